// Round 2
// 843.677 us; speedup vs baseline: 1.0859x; 1.0859x over previous
//
#include <hip/hip_runtime.h>
#include <hip/hip_bf16.h>
#include <cstdint>

#define HIDDEN   2048
#define HV       32
#define HK       16
#define DK       128
#define DV       128
#define KEY_DIM  2048
#define VAL_DIM  4096
#define CONV_DIM 8192
#define NTOK     2048   // B*S
#define SEQ      1024
#define N1       12288  // 2*KEY_DIM + VAL_DIM (qkv ++ z fused GEMM)
#define C_CH     64     // delta-rule chunk length
#define NCHK     (SEQ / C_CH)

typedef __attribute__((ext_vector_type(4))) float f4_t;
typedef __attribute__((ext_vector_type(2))) float f2_t;
typedef __attribute__((ext_vector_type(8))) short bf8_t;
typedef __attribute__((ext_vector_type(16))) float f16acc;
typedef __attribute__((ext_vector_type(4))) unsigned short u16x4;
typedef __attribute__((ext_vector_type(8))) unsigned short u16x8;
typedef __attribute__((ext_vector_type(2))) uint32_t u32x2;
typedef __attribute__((ext_vector_type(4))) uint32_t u32x4;

__device__ __forceinline__ unsigned short f2bf(float f) {
    union { float f; uint32_t u; } a; a.f = f;
    uint32_t u = a.u;
    return (unsigned short)((u + 0x7fff + ((u >> 16) & 1)) >> 16);
}
__device__ __forceinline__ float bf2f(unsigned short h) {
    uint32_t u = ((uint32_t)h) << 16;
    union { uint32_t u; float f; } a; a.u = u;
    return a.f;
}
// 16B LDS fragment via two 8B loads (rows are 8B-aligned, strides chosen 2-way-max banks)
__device__ __forceinline__ bf8_t lds_frag(const unsigned short* p) {
    u32x2 a = *(const u32x2*)p;
    u32x2 b = *(const u32x2*)(p + 4);
    u32x4 w = {a[0], a[1], b[0], b[1]};
    return __builtin_bit_cast(bf8_t, w);
}

// ---------------- cast hs -> bf16 ----------------
__global__ __launch_bounds__(256) void k_cast_hs(const float* __restrict__ hs,
                                                 unsigned short* __restrict__ out) {
    int i = blockIdx.x * 256 + threadIdx.x;
    f4_t v = ((const f4_t*)hs)[i];
    u16x4 o;
    o[0] = f2bf(v[0]); o[1] = f2bf(v[1]); o[2] = f2bf(v[2]); o[3] = f2bf(v[3]);
    ((u16x4*)out)[i] = o;
}

// ---------------- transpose+cast: W1t[n][k] = {w_qkv|w_z}[k][n] ----------------
__global__ __launch_bounds__(256) void k_trans_w1(const float* __restrict__ w_qkv,
                                                  const float* __restrict__ w_z,
                                                  unsigned short* __restrict__ w1t) {
    __shared__ float tile[32][33];
    int tx = threadIdx.x & 31, ty = threadIdx.x >> 5;
    int n0 = blockIdx.x * 32, k0 = blockIdx.y * 32;
    int n = n0 + tx;
#pragma unroll
    for (int i = 0; i < 4; i++) {
        int k = k0 + ty + i * 8;
        float v = (n < CONV_DIM) ? w_qkv[(size_t)k * CONV_DIM + n]
                                 : w_z[(size_t)k * VAL_DIM + (n - CONV_DIM)];
        tile[ty + i * 8][tx] = v;
    }
    __syncthreads();
#pragma unroll
    for (int i = 0; i < 4; i++)
        w1t[(size_t)(n0 + ty + i * 8) * HIDDEN + k0 + tx] = f2bf(tile[tx][ty + i * 8]);
}

__global__ __launch_bounds__(256) void k_trans(const float* __restrict__ src,
                                               unsigned short* __restrict__ dst,
                                               int K, int N) {
    __shared__ float tile[32][33];
    int tx = threadIdx.x & 31, ty = threadIdx.x >> 5;
    int n0 = blockIdx.x * 32, k0 = blockIdx.y * 32;
#pragma unroll
    for (int i = 0; i < 4; i++)
        tile[ty + i * 8][tx] = src[(size_t)(k0 + ty + i * 8) * N + n0 + tx];
    __syncthreads();
#pragma unroll
    for (int i = 0; i < 4; i++)
        dst[(size_t)(n0 + ty + i * 8) * K + k0 + tx] = f2bf(tile[tx][ty + i * 8]);
}

// ---------------- bf16 MFMA GEMM:  C[M,N] = A[M,K] * B[N,K]^T ----------------
__global__ __launch_bounds__(256, 2) void k_gemm_bt(const unsigned short* __restrict__ A,
                                                    const unsigned short* __restrict__ B,
                                                    float* __restrict__ C, int K, int N) {
    __shared__ unsigned short lA[128 * 32];
    __shared__ unsigned short lB[128 * 32];
    int tid = threadIdx.x;
    int wave = tid >> 6, lane = tid & 63;
    int m0 = blockIdx.x * 128, n0 = blockIdx.y * 128;
    int wm = wave & 1, wn = wave >> 1;
    f4_t acc[4][4];
#pragma unroll
    for (int i = 0; i < 4; i++)
#pragma unroll
        for (int j = 0; j < 4; j++) acc[i][j] = (f4_t){0.f, 0.f, 0.f, 0.f};
    int srow = wave * 16 + (lane >> 2);
    int scol = (lane & 3) * 8;
    int quad = lane >> 4, lrow = lane & 15;

    for (int k0 = 0; k0 < K; k0 += 32) {
        const unsigned short* gA0 = A + (size_t)(m0 + srow) * K + k0 + scol;
        const unsigned short* gA1 = A + (size_t)(m0 + 64 + srow) * K + k0 + scol;
        const unsigned short* gB0 = B + (size_t)(n0 + srow) * K + k0 + scol;
        const unsigned short* gB1 = B + (size_t)(n0 + 64 + srow) * K + k0 + scol;
        __syncthreads();
        __builtin_amdgcn_global_load_lds((const __attribute__((address_space(1))) void*)gA0,
            (__attribute__((address_space(3))) void*)(&lA[wave * 512]), 16, 0, 0);
        __builtin_amdgcn_global_load_lds((const __attribute__((address_space(1))) void*)gA1,
            (__attribute__((address_space(3))) void*)(&lA[2048 + wave * 512]), 16, 0, 0);
        __builtin_amdgcn_global_load_lds((const __attribute__((address_space(1))) void*)gB0,
            (__attribute__((address_space(3))) void*)(&lB[wave * 512]), 16, 0, 0);
        __builtin_amdgcn_global_load_lds((const __attribute__((address_space(1))) void*)gB1,
            (__attribute__((address_space(3))) void*)(&lB[2048 + wave * 512]), 16, 0, 0);
        __syncthreads();
        bf8_t af[4], bfv[4];
#pragma unroll
        for (int i = 0; i < 4; i++) {
            af[i]  = *(const bf8_t*)&lA[(wm * 64 + i * 16 + lrow) * 32 + quad * 8];
            bfv[i] = *(const bf8_t*)&lB[(wn * 64 + i * 16 + lrow) * 32 + quad * 8];
        }
#pragma unroll
        for (int i = 0; i < 4; i++)
#pragma unroll
            for (int j = 0; j < 4; j++)
                acc[i][j] = __builtin_amdgcn_mfma_f32_16x16x32_bf16(af[i], bfv[j], acc[i][j], 0, 0, 0);
    }
#pragma unroll
    for (int i = 0; i < 4; i++) {
        int row_b = m0 + wm * 64 + i * 16 + quad * 4;
#pragma unroll
        for (int j = 0; j < 4; j++) {
            int col = n0 + wn * 64 + j * 16 + lrow;
#pragma unroll
            for (int r = 0; r < 4; r++)
                C[(size_t)(row_b + r) * N + col] = acc[i][j][r];
        }
    }
}

// ---------------- beta / raw log-decay g ----------------
__global__ __launch_bounds__(256) void k_beta_g(const float* __restrict__ hs,
                                                const float* __restrict__ w_b,
                                                const float* __restrict__ w_a,
                                                const float* __restrict__ dt_bias,
                                                const float* __restrict__ A_log,
                                                float* __restrict__ beta,
                                                float* __restrict__ gval) {
    __shared__ float row[HIDDEN];
    __shared__ float part[256];
    int tok = blockIdx.x, t = threadIdx.x;
    for (int i = t; i < HIDDEN; i += 256) row[i] = hs[(size_t)tok * HIDDEN + i];
    __syncthreads();
    int out = t & 63, qtr = t >> 6;
    const float* w = (out < 32) ? w_b : w_a;
    int h = out & 31;
    float acc = 0.f;
    for (int k = qtr * 512; k < qtr * 512 + 512; k++) acc += row[k] * w[k * 32 + h];
    part[t] = acc;
    __syncthreads();
    if (t < 64) {
        float s = part[t] + part[t + 64] + part[t + 128] + part[t + 192];
        if (t < 32) {
            beta[tok * 32 + t] = 1.f / (1.f + expf(-s));
        } else {
            int hh = t - 32;
            float x = s + dt_bias[hh];
            float sp = (x > 20.f) ? x : log1pf(expf(x));
            gval[tok * 32 + hh] = -expf(A_log[hh]) * sp;   // log-decay (<= 0)
        }
    }
}

// ---------------- conv halo + chunked in-place conv ----------------
#define CCH 32
#define NCHC (SEQ / CCH)
__global__ __launch_bounds__(256) void k_halo(const float* __restrict__ mixed,
                                              float* __restrict__ halo) {
    int id = blockIdx.x * 256 + threadIdx.x;
    int c = id & 8191;
    int r = id >> 13;
    int tap = r % 3;
    int ck = (r / 3) % (NCHC - 1);
    int b = r / (3 * (NCHC - 1));
    int s = (ck + 1) * CCH - 1 - tap;
    halo[id] = mixed[(size_t)(b * SEQ + s) * N1 + c];
}

__global__ __launch_bounds__(256) void k_conv(float* __restrict__ mixed,
                                              const float* __restrict__ cw,
                                              const float* __restrict__ halo) {
    int id = blockIdx.x * 256 + threadIdx.x;
    int c = id & 8191;
    int r = id >> 13;
    int chunk = r & (NCHC - 1), b = r >> 5;
    int s0 = chunk * CCH;
    float w0 = cw[c * 4 + 0], w1 = cw[c * 4 + 1], w2 = cw[c * 4 + 2], w3 = cw[c * 4 + 3];
    float xm1, xm2, xm3;
    if (chunk == 0) {
        xm1 = xm2 = xm3 = 0.f;
    } else {
        const float* hp = halo + (size_t)(b * (NCHC - 1) + chunk - 1) * 3 * 8192;
        xm1 = hp[0 * 8192 + c]; xm2 = hp[1 * 8192 + c]; xm3 = hp[2 * 8192 + c];
    }
    float* col = mixed + (size_t)(b * SEQ + s0) * N1 + c;
#pragma unroll
    for (int s = 0; s < CCH; s++) {
        float x = col[(size_t)s * N1];
        float y = w3 * x + w2 * xm1 + w1 * xm2 + w0 * xm3;
        y = y / (1.f + expf(-y));
        col[(size_t)s * N1] = y;
        xm3 = xm2; xm2 = xm1; xm1 = x;
    }
}

// ---------------- l2norm of q (with 1/sqrt(DK)) and k, in-place ----------------
__global__ __launch_bounds__(256) void k_l2norm(float* __restrict__ mixed) {
    int tok = blockIdx.x, t = threadIdx.x;
    int vec = t >> 3, ln = t & 7;
    int off = (vec < 16) ? vec * 128 : 2048 + (vec - 16) * 128;
    float* p = mixed + (size_t)tok * N1 + off + ln * 16;
    f4_t x0 = ((f4_t*)p)[0], x1 = ((f4_t*)p)[1], x2 = ((f4_t*)p)[2], x3 = ((f4_t*)p)[3];
    float ss = 0.f;
#pragma unroll
    for (int i = 0; i < 4; i++) ss += x0[i]*x0[i] + x1[i]*x1[i] + x2[i]*x2[i] + x3[i]*x3[i];
    ss += __shfl_xor(ss, 1); ss += __shfl_xor(ss, 2); ss += __shfl_xor(ss, 4);
    float sc = 1.f / sqrtf(ss + 1e-6f);
    if (vec < 16) sc *= 0.08838834764831845f;
#pragma unroll
    for (int i = 0; i < 4; i++) { x0[i]*=sc; x1[i]*=sc; x2[i]*=sc; x3[i]*=sc; }
    ((f4_t*)p)[0] = x0; ((f4_t*)p)[1] = x1; ((f4_t*)p)[2] = x2; ((f4_t*)p)[3] = x3;
}

// ---------------- chunk-local precompute (fully parallel over b,h,c) ----------------
// Per (b,h,chunk): stage K,Q (bf16), scan g/beta; compute
//   M  = beta_i*(K K^T)*exp(Gi-Gj) (strict lower, fp32)
//   P  = (Q K^T)*exp(Gi-Gj) masked j<=i (bf16)
//   KbarT[dk][i] = exp(G_C - G_i)*k_i[dk] (bf16)
//   Kb/Qb row-major bf16 dumps (per b,hk,c; written by even-h blocks)
//   Lam[i]=exp(G_i), Beta[i]  (fp32)
// All expressions match the round-0 fused kernel bit-for-bit.
__global__ __launch_bounds__(256, 3) void k_prep(const float* __restrict__ mixed,
                                                 const float* __restrict__ beta,
                                                 const float* __restrict__ gval,
                                                 float* __restrict__ Mg,
                                                 unsigned short* __restrict__ Pg,
                                                 unsigned short* __restrict__ KbTg,
                                                 unsigned short* __restrict__ Qbg,
                                                 unsigned short* __restrict__ Kbg,
                                                 float* __restrict__ Lamg,
                                                 float* __restrict__ Betag) {
    __shared__ unsigned short lK[64 * 132];
    __shared__ unsigned short lQ[64 * 132];
    __shared__ float lG[64], lLam[64], lBeta[64], lKsc[64];

    int blk = blockIdx.x;
    int c = blk & 15, h = (blk >> 4) & 31, b = blk >> 9;
    int hk = h >> 1;
    int t = threadIdx.x;
    int wave = t >> 6, lane = t & 63, half = lane >> 5, lm = lane & 31;
    int s0 = c * C_CH;

    const float* qptr = mixed + (size_t)(b * SEQ) * N1 + hk * 128;
    const float* kptr = qptr + 2048;

    // ---- stage K,Q + g/beta scan ----
    {
        int i = t >> 2, c0 = (t & 3) * 32;
        const float* kr = kptr + (size_t)(s0 + i) * N1 + c0;
        const float* qr = qptr + (size_t)(s0 + i) * N1 + c0;
        unsigned short* dK = &lK[i * 132 + c0];
        unsigned short* dQ = &lQ[i * 132 + c0];
#pragma unroll
        for (int u = 0; u < 8; u++) {
            f4_t kv = ((const f4_t*)kr)[u];
            f4_t qv = ((const f4_t*)qr)[u];
            u16x4 ks, qs;
#pragma unroll
            for (int e = 0; e < 4; e++) { ks[e] = f2bf(kv[e]); qs[e] = f2bf(qv[e]); }
            *(u16x4*)(dK + u * 4) = ks;
            *(u16x4*)(dQ + u * 4) = qs;
        }
        if (t < 64) {
            float gv = gval[(size_t)(b * SEQ + s0 + t) * 32 + h];
            float bv = beta[(size_t)(b * SEQ + s0 + t) * 32 + h];
            float x = gv;
#pragma unroll
            for (int d = 1; d < 64; d <<= 1) {
                float y = __shfl_up(x, d);
                if (t >= d) x += y;
            }
            float Gc = __shfl(x, 63);
            lG[t] = x; lLam[t] = expf(x); lBeta[t] = bv; lKsc[t] = expf(Gc - x);
        }
    }
    __syncthreads();

    size_t bhc = (size_t)(b * 32 + h) * 16 + c;
    size_t bkc = (size_t)(b * 16 + hk) * 16 + c;

    // ---- MFMA: M (3 tiles) + P (3 tiles) ----
    for (int job = wave; job < 6; job += 4) {
        int isP = job >= 3 ? 1 : 0;
        int jj = job - (isP ? 3 : 0);
        int ib = (jj == 0) ? 0 : 1;
        int jb = (jj == 2) ? 1 : 0;
        const unsigned short* Ab = isP ? lQ : lK;
        f16acc acc;
#pragma unroll
        for (int r = 0; r < 16; r++) acc[r] = 0.f;
        int arow = ib * 32 + lm, brow = jb * 32 + lm;
#pragma unroll
        for (int k0 = 0; k0 < 128; k0 += 16) {
            bf8_t a = lds_frag(&Ab[arow * 132 + k0 + half * 8]);
            bf8_t bb = lds_frag(&lK[brow * 132 + k0 + half * 8]);
            acc = __builtin_amdgcn_mfma_f32_32x32x16_bf16(a, bb, acc, 0, 0, 0);
        }
        int j = jb * 32 + lm;
        float Gj = lG[j];
#pragma unroll
        for (int r = 0; r < 16; r++) {
            int ml = (r & 3) + 8 * (r >> 2) + 4 * half;
            int i = ib * 32 + ml;
            float f = expf(lG[i] - Gj);
            if (isP) {
                Pg[bhc * 4096 + i * 64 + j] = f2bf((j <= i) ? acc[r] * f : 0.f);
            } else {
                if (j < i) Mg[bhc * 4096 + i * 64 + j] = acc[r] * lBeta[i] * f;
            }
        }
    }
    // zero P upper-right tile (rows 0..31, cols 32..63)
#pragma unroll
    for (int u = 0; u < 4; u++) {
        int e = t * 4 + u;
        Pg[bhc * 4096 + (e >> 5) * 64 + 32 + (e & 31)] = 0;
    }

    // ---- Kb / Qb dumps (shared per hk, only even-h blocks write) ----
    if ((h & 1) == 0) {
        int i = t >> 2, c0 = (t & 3) * 32;
#pragma unroll
        for (int u = 0; u < 8; u++) {
            *(u16x4*)&Kbg[bkc * 8192 + i * 128 + c0 + u * 4] = *(const u16x4*)&lK[i * 132 + c0 + u * 4];
            *(u16x4*)&Qbg[bkc * 8192 + i * 128 + c0 + u * 4] = *(const u16x4*)&lQ[i * 132 + c0 + u * 4];
        }
    }

    // ---- KbarT[dk][i] ----
    {
        int dk = t >> 1, i0 = (t & 1) * 32;
        unsigned short tmp[32];
#pragma unroll
        for (int ii = 0; ii < 32; ii++) {
            int i = i0 + ii;
            tmp[ii] = f2bf(bf2f(lK[i * 132 + dk]) * lKsc[i]);
        }
#pragma unroll
        for (int u = 0; u < 4; u++) {
            u16x8 w;
#pragma unroll
            for (int j = 0; j < 8; j++) w[j] = tmp[u * 8 + j];
            *(u16x8*)&KbTg[bhc * 8192 + dk * 64 + i0 + u * 8] = w;
        }
    }
    if (t < 64) {
        Lamg[bhc * 64 + t] = lLam[t];
        Betag[bhc * 64 + t] = lBeta[t];
    }
}

// ---------------- sequential state recurrence ----------------
// grid 256 = (b, h, vs): 4 waves, state slice S[128dk, 32dv] in MFMA accumulators.
// Per chunk: waves 0,1: Wraw=K*S0; waves 2,3: Qacc=Q*S0 (fragments from global);
// R = beta*(V - Lam*Wraw); fp32 blocked substitution (I+M)Delta = R (unchanged math);
// O = diag(Lam)*Qacc + P*Delta;  S <- LamC*S + KbarT*Delta.
__global__ __launch_bounds__(256, 1) void k_state(const float* __restrict__ mixed,
                                                  const float* __restrict__ Mg,
                                                  const unsigned short* __restrict__ Pg,
                                                  const unsigned short* __restrict__ KbTg,
                                                  const unsigned short* __restrict__ Qbg,
                                                  const unsigned short* __restrict__ Kbg,
                                                  const float* __restrict__ Lamg,
                                                  const float* __restrict__ Betag,
                                                  float* __restrict__ o) {
    __shared__ unsigned short lSt[32 * 132];  // S^T bf16 [v][dk]
    __shared__ unsigned short lDt[32 * 68];   // Delta^T bf16 [v][i]
    __shared__ float lM[64 * 64];             // M fp32 (strict lower used), linear for global_load_lds
    __shared__ float lV[64 * 32];             // V chunk fp32 (vs slice)
    __shared__ float lR[64 * 34];             // R -> solved rows
    __shared__ float lDf[64 * 34];            // Delta fp32 [i][v]

    int blk = blockIdx.x;
    int vs = blk & 3, h = (blk >> 2) & 31, b = blk >> 7;
    int hk = h >> 1;
    int t = threadIdx.x;
    int wave = t >> 6, lane = t & 63, half = lane >> 5, lm = lane & 31;
    int ib = wave & 1;

    for (int i = t; i < 32 * 132; i += 256) lSt[i] = 0;
    f16acc sacc;
#pragma unroll
    for (int r = 0; r < 16; r++) sacc[r] = 0.f;
    __syncthreads();

    const float* vptr = mixed + (size_t)(b * SEQ) * N1 + 4096 + h * 128 + vs * 32;

    for (int c = 0; c < NCHK; c++) {
        int s0 = c * C_CH;
        size_t bhc = (size_t)(b * 32 + h) * 16 + c;
        size_t bkc = (size_t)(b * 16 + hk) * 16 + c;
        const float* Mp = Mg + bhc * 4096;

        // ---- async stage: M (16KB) and V slice (8KB) into LDS ----
#pragma unroll
        for (int u = 0; u < 4; u++) {
            int seg = wave * 4 + u;                       // 0..15, 256 f32 each
            const float* src = Mp + seg * 256 + lane * 4;
            __builtin_amdgcn_global_load_lds((const __attribute__((address_space(1))) void*)src,
                (__attribute__((address_space(3))) void*)(&lM[seg * 256]), 16, 0, 0);
        }
#pragma unroll
        for (int u = 0; u < 2; u++) {
            int seg = wave * 2 + u;                       // 0..7, 256 f32 each (8 rows x 32)
            int e = seg * 256 + lane * 4;
            int i = e >> 5, cc = e & 31;
            const float* src = vptr + (size_t)(s0 + i) * N1 + cc;
            __builtin_amdgcn_global_load_lds((const __attribute__((address_space(1))) void*)src,
                (__attribute__((address_space(3))) void*)(&lV[seg * 256]), 16, 0, 0);
        }

        // ---- fragment loads (registers, L2-resident from k_prep) ----
        const unsigned short* Ag = (wave < 2) ? (Kbg + bkc * 8192) : (Qbg + bkc * 8192);
        bf8_t afr[8];
#pragma unroll
        for (int kk = 0; kk < 8; kk++)
            afr[kk] = *(const bf8_t*)&Ag[(ib * 32 + lm) * 128 + kk * 16 + half * 8];
        bf8_t ktfr[4];
#pragma unroll
        for (int u = 0; u < 4; u++)
            ktfr[u] = *(const bf8_t*)&KbTg[bhc * 8192 + (wave * 32 + lm) * 64 + u * 16 + half * 8];
        bf8_t pfr[4];
        if (wave >= 2) {
#pragma unroll
            for (int u = 0; u < 4; u++)
                pfr[u] = *(const bf8_t*)&Pg[bhc * 4096 + (ib * 32 + lm) * 64 + u * 16 + half * 8];
        }
        f4_t lamv[4], betv[4];
#pragma unroll
        for (int q = 0; q < 4; q++) {
            lamv[q] = *(const f4_t*)&Lamg[bhc * 64 + ib * 32 + q * 8 + half * 4];
            betv[q] = *(const f4_t*)&Betag[bhc * 64 + ib * 32 + q * 8 + half * 4];
        }
        float lamC = Lamg[bhc * 64 + 63];

        // ---- phase 1: Wraw (waves 0,1) / Qacc (waves 2,3) = A * S0 ----
        f16acc wacc;
#pragma unroll
        for (int r = 0; r < 16; r++) wacc[r] = 0.f;
#pragma unroll
        for (int kk = 0; kk < 8; kk++) {
            bf8_t bb = lds_frag(&lSt[lm * 132 + kk * 16 + half * 8]);
            wacc = __builtin_amdgcn_mfma_f32_32x32x16_bf16(afr[kk], bb, wacc, 0, 0, 0);
        }
        __syncthreads();   // lM/lV landed (vmcnt drained at barrier); lSt consumed

        // ---- R = beta*(V - Lam*Wraw) (waves 0,1) ----
        if (wave < 2) {
#pragma unroll
            for (int r = 0; r < 16; r++) {
                int ml = (r & 3) + 8 * (r >> 2) + 4 * half;
                int i = ib * 32 + ml;
                lR[i * 34 + lm] = betv[r >> 2][r & 3] * (lV[i * 32 + lm] - lamv[r >> 2][r & 3] * wacc[r]);
            }
        }
        __syncthreads();

        // ---- blocked forward substitution: (I+M) Delta = R ----
        for (int sb = 0; sb < 4; sb++) {
            if (sb > 0) {
                int i = 16 * sb + (t >> 4), v = t & 15;
                float a0 = lR[i * 34 + v], a1 = lR[i * 34 + v + 16];
                for (int j = 0; j < 16 * sb; j++) {
                    float m = lM[i * 64 + j];
                    a0 -= m * lDf[j * 34 + v];
                    a1 -= m * lDf[j * 34 + v + 16];
                }
                lR[i * 34 + v] = a0; lR[i * 34 + v + 16] = a1;
                __syncthreads();
            }
            if (t < 32) {
                int v = t;
                float dd[16];
                dd[0] = lR[(16 * sb) * 34 + v];
#pragma unroll
                for (int il = 1; il < 16; il++) {
                    float acc = lR[(16 * sb + il) * 34 + v];
#pragma unroll
                    for (int jl = 0; jl < il; jl++)
                        acc -= lM[(16 * sb + il) * 64 + 16 * sb + jl] * dd[jl];
                    dd[il] = acc;
                }
#pragma unroll
                for (int il = 0; il < 16; il++) {
                    lDf[(16 * sb + il) * 34 + v] = dd[il];
                    lDt[v * 68 + 16 * sb + il] = f2bf(dd[il]);
                }
            }
            __syncthreads();
        }

        // ---- tail: O = diag(Lam)*Qacc + P*Delta (waves 2,3); S update (all) ----
        if (wave >= 2) {
#pragma unroll
            for (int r = 0; r < 16; r++) wacc[r] *= lamv[r >> 2][r & 3];
#pragma unroll
            for (int u = 0; u < 4; u++) {
                bf8_t bb = lds_frag(&lDt[lm * 68 + u * 16 + half * 8]);
                wacc = __builtin_amdgcn_mfma_f32_32x32x16_bf16(pfr[u], bb, wacc, 0, 0, 0);
            }
#pragma unroll
            for (int r = 0; r < 16; r++) {
                int ml = (r & 3) + 8 * (r >> 2) + 4 * half;
                o[(size_t)(b * SEQ + s0 + ib * 32 + ml) * 4096 + h * 128 + vs * 32 + lm] = wacc[r];
            }
        }
#pragma unroll
        for (int r = 0; r < 16; r++) sacc[r] *= lamC;
#pragma unroll
        for (int u = 0; u < 4; u++) {
            bf8_t bb = lds_frag(&lDt[lm * 68 + u * 16 + half * 8]);
            sacc = __builtin_amdgcn_mfma_f32_32x32x16_bf16(ktfr[u], bb, sacc, 0, 0, 0);
        }
#pragma unroll
        for (int r = 0; r < 16; r++) {
            int ml = (r & 3) + 8 * (r >> 2) + 4 * half;
            lSt[lm * 132 + 32 * wave + ml] = f2bf(sacc[r]);
        }
        __syncthreads();
    }
}

// ---------------- gated RMSNorm -> bf16 ----------------
__global__ __launch_bounds__(256) void k_gnorm(const float* __restrict__ o,
                                               const float* __restrict__ mixed,
                                               const float* __restrict__ norm_w,
                                               unsigned short* __restrict__ on) {
    int tok = blockIdx.x, t = threadIdx.x;
    int hh = t >> 3, ln = t & 7;
    const f4_t* op = (const f4_t*)(o + (size_t)tok * 4096 + hh * 128 + ln * 16);
    const f4_t* zp = (const f4_t*)(mixed + (size_t)tok * N1 + 8192 + hh * 128 + ln * 16);
    float og[16];
    float ss = 0.f;
#pragma unroll
    for (int i = 0; i < 4; i++) {
        f4_t ov = op[i], zv = zp[i];
#pragma unroll
        for (int j = 0; j < 4; j++) {
            float z = zv[j];
            float g = ov[j] * (z / (1.f + expf(-z)));
            og[i * 4 + j] = g;
            ss += g * g;
        }
    }
    ss += __shfl_xor(ss, 1); ss += __shfl_xor(ss, 2); ss += __shfl_xor(ss, 4);
    float r = 1.f / sqrtf(ss * (1.f / 128.f) + 1e-6f);
    unsigned short* onp = on + (size_t)tok * 4096 + hh * 128 + ln * 16;
    u16x8 a, bb;
#pragma unroll
    for (int j = 0; j < 8; j++) a[j] = f2bf(og[j] * r * norm_w[ln * 16 + j]);
#pragma unroll
    for (int j = 0; j < 8; j++) bb[j] = f2bf(og[8 + j] * r * norm_w[ln * 16 + 8 + j]);
    ((u16x8*)onp)[0] = a;
    ((u16x8*)onp)[1] = bb;
}

extern "C" void kernel_launch(void* const* d_in, const int* in_sizes, int n_in,
                              void* d_out, int out_size, void* d_ws, size_t ws_size,
                              hipStream_t stream) {
    const float* hs      = (const float*)d_in[0];
    const float* conv_w  = (const float*)d_in[1];
    const float* w_qkv   = (const float*)d_in[2];
    const float* w_z     = (const float*)d_in[3];
    const float* w_b     = (const float*)d_in[4];
    const float* w_a     = (const float*)d_in[5];
    const float* w_out   = (const float*)d_in[6];
    const float* dt_bias = (const float*)d_in[7];
    const float* A_log   = (const float*)d_in[8];
    const float* norm_w  = (const float*)d_in[9];
    float* out = (float*)d_out;

    // Workspace layout is byte-identical to the 916 µs baseline (~222 MiB).
    char* ws = (char*)d_ws;
    unsigned short* hs_bf = (unsigned short*)ws; ws += (size_t)NTOK * HIDDEN * 2;     // 8 MiB
    unsigned short* w1t   = (unsigned short*)ws; ws += (size_t)N1 * HIDDEN * 2;       // 48 MiB
    unsigned short* wot   = (unsigned short*)ws; ws += (size_t)HIDDEN * VAL_DIM * 2;  // 16 MiB (live to end)
    float* mixed          = (float*)ws;          ws += (size_t)NTOK * N1 * 4;         // 96 MiB
    float* beta           = (float*)ws;          ws += (size_t)NTOK * 32 * 4;
    float* gval           = (float*)ws;          ws += (size_t)NTOK * 32 * 4;
    float* halo           = (float*)ws;          ws += (size_t)2 * (NCHC - 1) * 3 * 8192 * 4; // 5.8 MiB
    float* o_buf          = (float*)ws;          ws += (size_t)NTOK * VAL_DIM * 4;
    unsigned short* on_bf = (unsigned short*)ws; ws += (size_t)NTOK * VAL_DIM * 2;

    // k_prep/k_state scratch ALIASED over buffers dead by that point:
    //   hs_bf + w1t (56 MiB, dead after first GEMM) holds Mg|Pg|KbTg|Qbg|Kbg (56 MiB exactly);
    //   halo (dead after k_conv) holds Lamg|Betag (0.5 MiB).
    char* al = (char*)hs_bf;
    float* Mg             = (float*)al;          al += (size_t)1024 * 4096 * 4;  // 16 MiB
    unsigned short* Pg    = (unsigned short*)al; al += (size_t)1024 * 4096 * 2;  //  8 MiB
    unsigned short* KbTg  = (unsigned short*)al; al += (size_t)1024 * 8192 * 2;  // 16 MiB
    unsigned short* Qbg   = (unsigned short*)al; al += (size_t)512 * 8192 * 2;   //  8 MiB
    unsigned short* Kbg   = (unsigned short*)al; al += (size_t)512 * 8192 * 2;   //  8 MiB (ends at wot)
    char* al2 = (char*)halo;
    float* Lamg           = (float*)al2;         al2 += (size_t)1024 * 64 * 4;
    float* Betag          = (float*)al2;

    k_cast_hs<<<dim3(NTOK * HIDDEN / 4 / 256), 256, 0, stream>>>(hs, hs_bf);
    k_trans_w1<<<dim3(N1 / 32, HIDDEN / 32), 256, 0, stream>>>(w_qkv, w_z, w1t);
    k_trans<<<dim3(HIDDEN / 32, VAL_DIM / 32), 256, 0, stream>>>(w_out, wot, VAL_DIM, HIDDEN);
    k_gemm_bt<<<dim3(NTOK / 128, N1 / 128), 256, 0, stream>>>(hs_bf, w1t, mixed, HIDDEN, N1);
    k_beta_g<<<dim3(NTOK), 256, 0, stream>>>(hs, w_b, w_a, dt_bias, A_log, beta, gval);
    k_halo<<<dim3(2 * (NCHC - 1) * 3 * 8192 / 256), 256, 0, stream>>>(mixed, halo);
    k_conv<<<dim3(2 * NCHC * 8192 / 256), 256, 0, stream>>>(mixed, conv_w, halo);
    k_l2norm<<<dim3(NTOK), 256, 0, stream>>>(mixed);
    k_prep<<<dim3(1024), 256, 0, stream>>>(mixed, beta, gval, Mg, Pg, KbTg, Qbg, Kbg, Lamg, Betag);
    k_state<<<dim3(256), 256, 0, stream>>>(mixed, Mg, Pg, KbTg, Qbg, Kbg, Lamg, Betag, o_buf);
    k_gnorm<<<dim3(NTOK), 256, 0, stream>>>(o_buf, mixed, norm_w, on_bf);
    k_gemm_bt<<<dim3(NTOK / 128, HIDDEN / 128), 256, 0, stream>>>(on_bf, wot, out, VAL_DIM, HIDDEN);
}

// Round 4
// 741.871 us; speedup vs baseline: 1.2349x; 1.1372x over previous
//
#include <hip/hip_runtime.h>
#include <hip/hip_bf16.h>
#include <cstdint>

#define HIDDEN   2048
#define HV       32
#define HK       16
#define DK       128
#define DV       128
#define KEY_DIM  2048
#define VAL_DIM  4096
#define CONV_DIM 8192
#define NTOK     2048   // B*S
#define SEQ      1024
#define N1       12288  // 2*KEY_DIM + VAL_DIM (qkv ++ z fused GEMM)
#define C_CH     64     // delta-rule chunk length
#define NCHK     (SEQ / C_CH)

typedef __attribute__((ext_vector_type(4))) float f4_t;
typedef __attribute__((ext_vector_type(2))) float f2_t;
typedef __attribute__((ext_vector_type(8))) short bf8_t;
typedef __attribute__((ext_vector_type(16))) float f16acc;
typedef __attribute__((ext_vector_type(4))) unsigned short u16x4;
typedef __attribute__((ext_vector_type(8))) unsigned short u16x8;
typedef __attribute__((ext_vector_type(2))) uint32_t u32x2;
typedef __attribute__((ext_vector_type(4))) uint32_t u32x4;

__device__ __forceinline__ unsigned short f2bf(float f) {
    union { float f; uint32_t u; } a; a.f = f;
    uint32_t u = a.u;
    return (unsigned short)((u + 0x7fff + ((u >> 16) & 1)) >> 16);
}
__device__ __forceinline__ float bf2f(unsigned short h) {
    uint32_t u = ((uint32_t)h) << 16;
    union { uint32_t u; float f; } a; a.u = u;
    return a.f;
}
// 16B LDS fragment via two 8B loads (rows are 8B-aligned, strides chosen 2-way-max banks)
__device__ __forceinline__ bf8_t lds_frag(const unsigned short* p) {
    u32x2 a = *(const u32x2*)p;
    u32x2 b = *(const u32x2*)(p + 4);
    u32x4 w = {a[0], a[1], b[0], b[1]};
    return __builtin_bit_cast(bf8_t, w);
}

// ---------------- cast hs -> bf16 ----------------
__global__ __launch_bounds__(256) void k_cast_hs(const float* __restrict__ hs,
                                                 unsigned short* __restrict__ out) {
    int i = blockIdx.x * 256 + threadIdx.x;
    f4_t v = ((const f4_t*)hs)[i];
    u16x4 o;
    o[0] = f2bf(v[0]); o[1] = f2bf(v[1]); o[2] = f2bf(v[2]); o[3] = f2bf(v[3]);
    ((u16x4*)out)[i] = o;
}

// ---------------- transpose+cast: W1t[n][k] = {w_qkv|w_z}[k][n] ----------------
__global__ __launch_bounds__(256) void k_trans_w1(const float* __restrict__ w_qkv,
                                                  const float* __restrict__ w_z,
                                                  unsigned short* __restrict__ w1t) {
    __shared__ float tile[32][33];
    int tx = threadIdx.x & 31, ty = threadIdx.x >> 5;
    int n0 = blockIdx.x * 32, k0 = blockIdx.y * 32;
    int n = n0 + tx;
#pragma unroll
    for (int i = 0; i < 4; i++) {
        int k = k0 + ty + i * 8;
        float v = (n < CONV_DIM) ? w_qkv[(size_t)k * CONV_DIM + n]
                                 : w_z[(size_t)k * VAL_DIM + (n - CONV_DIM)];
        tile[ty + i * 8][tx] = v;
    }
    __syncthreads();
#pragma unroll
    for (int i = 0; i < 4; i++)
        w1t[(size_t)(n0 + ty + i * 8) * HIDDEN + k0 + tx] = f2bf(tile[tx][ty + i * 8]);
}

__global__ __launch_bounds__(256) void k_trans(const float* __restrict__ src,
                                               unsigned short* __restrict__ dst,
                                               int K, int N) {
    __shared__ float tile[32][33];
    int tx = threadIdx.x & 31, ty = threadIdx.x >> 5;
    int n0 = blockIdx.x * 32, k0 = blockIdx.y * 32;
#pragma unroll
    for (int i = 0; i < 4; i++)
        tile[ty + i * 8][tx] = src[(size_t)(k0 + ty + i * 8) * N + n0 + tx];
    __syncthreads();
#pragma unroll
    for (int i = 0; i < 4; i++)
        dst[(size_t)(n0 + ty + i * 8) * K + k0 + tx] = f2bf(tile[tx][ty + i * 8]);
}

// ---------------- bf16 MFMA GEMM:  C[M,N] = A[M,K] * B[N,K]^T ----------------
__global__ __launch_bounds__(256, 2) void k_gemm_bt(const unsigned short* __restrict__ A,
                                                    const unsigned short* __restrict__ B,
                                                    float* __restrict__ C, int K, int N) {
    __shared__ unsigned short lA[128 * 32];
    __shared__ unsigned short lB[128 * 32];
    int tid = threadIdx.x;
    int wave = tid >> 6, lane = tid & 63;
    int m0 = blockIdx.x * 128, n0 = blockIdx.y * 128;
    int wm = wave & 1, wn = wave >> 1;
    f4_t acc[4][4];
#pragma unroll
    for (int i = 0; i < 4; i++)
#pragma unroll
        for (int j = 0; j < 4; j++) acc[i][j] = (f4_t){0.f, 0.f, 0.f, 0.f};
    int srow = wave * 16 + (lane >> 2);
    int scol = (lane & 3) * 8;
    int quad = lane >> 4, lrow = lane & 15;

    for (int k0 = 0; k0 < K; k0 += 32) {
        const unsigned short* gA0 = A + (size_t)(m0 + srow) * K + k0 + scol;
        const unsigned short* gA1 = A + (size_t)(m0 + 64 + srow) * K + k0 + scol;
        const unsigned short* gB0 = B + (size_t)(n0 + srow) * K + k0 + scol;
        const unsigned short* gB1 = B + (size_t)(n0 + 64 + srow) * K + k0 + scol;
        __syncthreads();
        __builtin_amdgcn_global_load_lds((const __attribute__((address_space(1))) void*)gA0,
            (__attribute__((address_space(3))) void*)(&lA[wave * 512]), 16, 0, 0);
        __builtin_amdgcn_global_load_lds((const __attribute__((address_space(1))) void*)gA1,
            (__attribute__((address_space(3))) void*)(&lA[2048 + wave * 512]), 16, 0, 0);
        __builtin_amdgcn_global_load_lds((const __attribute__((address_space(1))) void*)gB0,
            (__attribute__((address_space(3))) void*)(&lB[wave * 512]), 16, 0, 0);
        __builtin_amdgcn_global_load_lds((const __attribute__((address_space(1))) void*)gB1,
            (__attribute__((address_space(3))) void*)(&lB[2048 + wave * 512]), 16, 0, 0);
        __syncthreads();
        bf8_t af[4], bfv[4];
#pragma unroll
        for (int i = 0; i < 4; i++) {
            af[i]  = *(const bf8_t*)&lA[(wm * 64 + i * 16 + lrow) * 32 + quad * 8];
            bfv[i] = *(const bf8_t*)&lB[(wn * 64 + i * 16 + lrow) * 32 + quad * 8];
        }
#pragma unroll
        for (int i = 0; i < 4; i++)
#pragma unroll
            for (int j = 0; j < 4; j++)
                acc[i][j] = __builtin_amdgcn_mfma_f32_16x16x32_bf16(af[i], bfv[j], acc[i][j], 0, 0, 0);
    }
#pragma unroll
    for (int i = 0; i < 4; i++) {
        int row_b = m0 + wm * 64 + i * 16 + quad * 4;
#pragma unroll
        for (int j = 0; j < 4; j++) {
            int col = n0 + wn * 64 + j * 16 + lrow;
#pragma unroll
            for (int r = 0; r < 4; r++)
                C[(size_t)(row_b + r) * N + col] = acc[i][j][r];
        }
    }
}

// ---------------- beta / raw log-decay g ----------------
__global__ __launch_bounds__(256) void k_beta_g(const float* __restrict__ hs,
                                                const float* __restrict__ w_b,
                                                const float* __restrict__ w_a,
                                                const float* __restrict__ dt_bias,
                                                const float* __restrict__ A_log,
                                                float* __restrict__ beta,
                                                float* __restrict__ gval) {
    __shared__ float row[HIDDEN];
    __shared__ float part[256];
    int tok = blockIdx.x, t = threadIdx.x;
    for (int i = t; i < HIDDEN; i += 256) row[i] = hs[(size_t)tok * HIDDEN + i];
    __syncthreads();
    int out = t & 63, qtr = t >> 6;
    const float* w = (out < 32) ? w_b : w_a;
    int h = out & 31;
    float acc = 0.f;
    for (int k = qtr * 512; k < qtr * 512 + 512; k++) acc += row[k] * w[k * 32 + h];
    part[t] = acc;
    __syncthreads();
    if (t < 64) {
        float s = part[t] + part[t + 64] + part[t + 128] + part[t + 192];
        if (t < 32) {
            beta[tok * 32 + t] = 1.f / (1.f + expf(-s));
        } else {
            int hh = t - 32;
            float x = s + dt_bias[hh];
            float sp = (x > 20.f) ? x : log1pf(expf(x));
            gval[tok * 32 + hh] = -expf(A_log[hh]) * sp;   // log-decay (<= 0)
        }
    }
}

// ---------------- conv halo + chunked in-place conv ----------------
#define CCH 32
#define NCHC (SEQ / CCH)
__global__ __launch_bounds__(256) void k_halo(const float* __restrict__ mixed,
                                              float* __restrict__ halo) {
    int id = blockIdx.x * 256 + threadIdx.x;
    int c = id & 8191;
    int r = id >> 13;
    int tap = r % 3;
    int ck = (r / 3) % (NCHC - 1);
    int b = r / (3 * (NCHC - 1));
    int s = (ck + 1) * CCH - 1 - tap;
    halo[id] = mixed[(size_t)(b * SEQ + s) * N1 + c];
}

__global__ __launch_bounds__(256) void k_conv(float* __restrict__ mixed,
                                              const float* __restrict__ cw,
                                              const float* __restrict__ halo) {
    int id = blockIdx.x * 256 + threadIdx.x;
    int c = id & 8191;
    int r = id >> 13;
    int chunk = r & (NCHC - 1), b = r >> 5;
    int s0 = chunk * CCH;
    float w0 = cw[c * 4 + 0], w1 = cw[c * 4 + 1], w2 = cw[c * 4 + 2], w3 = cw[c * 4 + 3];
    float xm1, xm2, xm3;
    if (chunk == 0) {
        xm1 = xm2 = xm3 = 0.f;
    } else {
        const float* hp = halo + (size_t)(b * (NCHC - 1) + chunk - 1) * 3 * 8192;
        xm1 = hp[0 * 8192 + c]; xm2 = hp[1 * 8192 + c]; xm3 = hp[2 * 8192 + c];
    }
    float* col = mixed + (size_t)(b * SEQ + s0) * N1 + c;
#pragma unroll
    for (int s = 0; s < CCH; s++) {
        float x = col[(size_t)s * N1];
        float y = w3 * x + w2 * xm1 + w1 * xm2 + w0 * xm3;
        y = y / (1.f + expf(-y));
        col[(size_t)s * N1] = y;
        xm3 = xm2; xm2 = xm1; xm1 = x;
    }
}

// ---------------- l2norm of q (with 1/sqrt(DK)) and k, in-place ----------------
__global__ __launch_bounds__(256) void k_l2norm(float* __restrict__ mixed) {
    int tok = blockIdx.x, t = threadIdx.x;
    int vec = t >> 3, ln = t & 7;
    int off = (vec < 16) ? vec * 128 : 2048 + (vec - 16) * 128;
    float* p = mixed + (size_t)tok * N1 + off + ln * 16;
    f4_t x0 = ((f4_t*)p)[0], x1 = ((f4_t*)p)[1], x2 = ((f4_t*)p)[2], x3 = ((f4_t*)p)[3];
    float ss = 0.f;
#pragma unroll
    for (int i = 0; i < 4; i++) ss += x0[i]*x0[i] + x1[i]*x1[i] + x2[i]*x2[i] + x3[i]*x3[i];
    ss += __shfl_xor(ss, 1); ss += __shfl_xor(ss, 2); ss += __shfl_xor(ss, 4);
    float sc = 1.f / sqrtf(ss + 1e-6f);
    if (vec < 16) sc *= 0.08838834764831845f;
#pragma unroll
    for (int i = 0; i < 4; i++) { x0[i]*=sc; x1[i]*=sc; x2[i]*=sc; x3[i]*=sc; }
    ((f4_t*)p)[0] = x0; ((f4_t*)p)[1] = x1; ((f4_t*)p)[2] = x2; ((f4_t*)p)[3] = x3;
}

// ---------------- chunk-local precompute + UT transform (parallel over b,h,c) ----------------
// Per (b,h,chunk): stage K,Q (bf16), scan g/beta; compute
//   M  = beta_i*(K K^T)*exp(Gi-Gj)   (strict lower, fp32, kept in LDS)
//   P  = (Q K^T)*exp(Gi-Gj) masked j<=i               -> Pg   (bf16)
//   KbarT[dk][i] = exp(G_C - G_i)*k_i[dk]             -> KbTg (bf16)
//   Q row dump (per b,hk,c; even-h blocks)            -> Qbg  (bf16)
//   Lam[i]=exp(G_i)                                   -> Lamg (fp32)
// UT transform: solve (I+M) X = [beta.*V | beta.*Lam.*K] by exact fp32 forward
// substitution (one column per thread, ascending-j order == old k_state solve):
//   U = X[:, 0:128]    -> stored fp32 INTO o_buf slots this chunk's O will overwrite
//   Wneg = -X[:,128:]  -> Wg (bf16)
// Then Delta = U + Wneg*S0 is a pure MFMA in the sequential kernel.
__global__ __launch_bounds__(256, 2) void k_prep(const float* __restrict__ mixed,
                                                 const float* __restrict__ beta,
                                                 const float* __restrict__ gval,
                                                 unsigned short* __restrict__ Pg,
                                                 unsigned short* __restrict__ KbTg,
                                                 unsigned short* __restrict__ Qbg,
                                                 unsigned short* __restrict__ Wg,
                                                 float* __restrict__ Ug,
                                                 float* __restrict__ Lamg) {
    __shared__ unsigned short lK[64 * 132];
    __shared__ unsigned short lQ[64 * 132];
    __shared__ float lM[64 * 66];
    __shared__ float lG[64], lLam[64], lBeta[64], lKsc[64];

    int blk = blockIdx.x;
    int c = blk & 15, h = (blk >> 4) & 31, b = blk >> 9;
    int hk = h >> 1;
    int t = threadIdx.x;
    int wave = t >> 6, lane = t & 63, half = lane >> 5, lm = lane & 31;
    int s0 = c * C_CH;

    const float* qptr = mixed + (size_t)(b * SEQ) * N1 + hk * 128;
    const float* kptr = qptr + 2048;

    // ---- stage K,Q + g/beta scan ----
    {
        int i = t >> 2, c0 = (t & 3) * 32;
        const float* kr = kptr + (size_t)(s0 + i) * N1 + c0;
        const float* qr = qptr + (size_t)(s0 + i) * N1 + c0;
        unsigned short* dK = &lK[i * 132 + c0];
        unsigned short* dQ = &lQ[i * 132 + c0];
#pragma unroll
        for (int u = 0; u < 8; u++) {
            f4_t kv = ((const f4_t*)kr)[u];
            f4_t qv = ((const f4_t*)qr)[u];
            u16x4 ks, qs;
#pragma unroll
            for (int e = 0; e < 4; e++) { ks[e] = f2bf(kv[e]); qs[e] = f2bf(qv[e]); }
            *(u16x4*)(dK + u * 4) = ks;
            *(u16x4*)(dQ + u * 4) = qs;
        }
        if (t < 64) {
            float gv = gval[(size_t)(b * SEQ + s0 + t) * 32 + h];
            float bv = beta[(size_t)(b * SEQ + s0 + t) * 32 + h];
            float x = gv;
#pragma unroll
            for (int d = 1; d < 64; d <<= 1) {
                float y = __shfl_up(x, d);
                if (t >= d) x += y;
            }
            float Gc = __shfl(x, 63);
            lG[t] = x; lLam[t] = expf(x); lBeta[t] = bv; lKsc[t] = expf(Gc - x);
        }
    }
    __syncthreads();

    size_t bhc = (size_t)(b * 32 + h) * 16 + c;
    size_t bkc = (size_t)(b * 16 + hk) * 16 + c;

    // ---- MFMA: M (3 tiles, ->LDS) + P (3 tiles, ->global) ----
    for (int job = wave; job < 6; job += 4) {
        int isP = job >= 3 ? 1 : 0;
        int jj = job - (isP ? 3 : 0);
        int ib = (jj == 0) ? 0 : 1;
        int jb = (jj == 2) ? 1 : 0;
        const unsigned short* Ab = isP ? lQ : lK;
        f16acc acc;
#pragma unroll
        for (int r = 0; r < 16; r++) acc[r] = 0.f;
        int arow = ib * 32 + lm, brow = jb * 32 + lm;
#pragma unroll
        for (int k0 = 0; k0 < 128; k0 += 16) {
            bf8_t a = lds_frag(&Ab[arow * 132 + k0 + half * 8]);
            bf8_t bb = lds_frag(&lK[brow * 132 + k0 + half * 8]);
            acc = __builtin_amdgcn_mfma_f32_32x32x16_bf16(a, bb, acc, 0, 0, 0);
        }
        int j = jb * 32 + lm;
        float Gj = lG[j];
#pragma unroll
        for (int r = 0; r < 16; r++) {
            int ml = (r & 3) + 8 * (r >> 2) + 4 * half;
            int i = ib * 32 + ml;
            float f = expf(lG[i] - Gj);
            if (isP) {
                Pg[bhc * 4096 + i * 64 + j] = f2bf((j <= i) ? acc[r] * f : 0.f);
            } else {
                if (j < i) lM[i * 66 + j] = acc[r] * lBeta[i] * f;
            }
        }
    }
    // zero P upper-right tile (rows 0..31, cols 32..63)
#pragma unroll
    for (int u = 0; u < 4; u++) {
        int e = t * 4 + u;
        Pg[bhc * 4096 + (e >> 5) * 64 + 32 + (e & 31)] = 0;
    }

    // ---- Q dump (shared per hk, only even-h blocks write) ----
    if ((h & 1) == 0) {
        int i = t >> 2, c0 = (t & 3) * 32;
#pragma unroll
        for (int u = 0; u < 8; u++)
            *(u16x4*)&Qbg[bkc * 8192 + i * 128 + c0 + u * 4] = *(const u16x4*)&lQ[i * 132 + c0 + u * 4];
    }

    // ---- KbarT[dk][i] ----
    {
        int dk = t >> 1, i0 = (t & 1) * 32;
        unsigned short tmp[32];
#pragma unroll
        for (int ii = 0; ii < 32; ii++) {
            int i = i0 + ii;
            tmp[ii] = f2bf(bf2f(lK[i * 132 + dk]) * lKsc[i]);
        }
#pragma unroll
        for (int u = 0; u < 4; u++) {
            u16x8 w;
#pragma unroll
            for (int j = 0; j < 8; j++) w[j] = tmp[u * 8 + j];
            *(u16x8*)&KbTg[bhc * 8192 + dk * 64 + i0 + u * 8] = w;
        }
    }
    if (t < 64) Lamg[bhc * 64 + t] = lLam[t];

    __syncthreads();   // lM fully populated

    // ---- UT transform: (I+M) X = [beta.*V | beta.*Lam.*K], one column/thread ----
    {
        float x[64];
        if (t < 128) {
            const float* vcol = mixed + (size_t)(b * SEQ + s0) * N1 + 4096 + h * 128 + t;
#pragma unroll
            for (int il = 0; il < 64; il++) x[il] = lBeta[il] * vcol[(size_t)il * N1];
        } else {
            int dk = t - 128;
#pragma unroll
            for (int il = 0; il < 64; il++) x[il] = lBeta[il] * lLam[il] * bf2f(lK[il * 132 + dk]);
        }
#pragma unroll
        for (int il = 1; il < 64; il++)
#pragma unroll
            for (int j = 0; j < il; j++)
                x[il] -= lM[il * 66 + j] * x[j];
        if (t < 128) {
            float* up = Ug + (size_t)(b * SEQ + s0) * 4096 + h * 128 + t;
#pragma unroll
            for (int il = 0; il < 64; il++) up[(size_t)il * 4096] = x[il];
        } else {
            unsigned short* wp = Wg + bhc * 8192 + (t - 128);
#pragma unroll
            for (int il = 0; il < 64; il++) wp[il * 128] = f2bf(-x[il]);
        }
    }
}

// ---------------- sequential state recurrence (pure MFMA) ----------------
// grid 256 = (b, h, vs): 4 waves, state slice S[128dk, 32dv] in MFMA accumulators.
// Per chunk (2 barriers):
//   waves 0,1: Delta = U + Wneg*S0 (U as C-init); waves 2,3: Qacc = Q*S0
//   -> Delta^T bf16 to LDS -> barrier
//   waves 2,3: O = diag(Lam)*Qacc + P*Delta (overwrites U slots in o)
//   all waves: S <- LamC*S + KbarT*Delta -> lSt -> barrier
__global__ __launch_bounds__(256, 1) void k_state(const unsigned short* __restrict__ Wg,
                                                  const unsigned short* __restrict__ Pg,
                                                  const unsigned short* __restrict__ KbTg,
                                                  const unsigned short* __restrict__ Qbg,
                                                  const float* __restrict__ Lamg,
                                                  float* __restrict__ o) {
    __shared__ unsigned short lSt[32 * 132];  // S^T bf16 [v][dk]
    __shared__ unsigned short lDt[32 * 68];   // Delta^T bf16 [v][i]

    int blk = blockIdx.x;
    int vs = blk & 3, h = (blk >> 2) & 31, b = blk >> 7;
    int hk = h >> 1;
    int t = threadIdx.x;
    int wave = t >> 6, lane = t & 63, half = lane >> 5, lm = lane & 31;
    int ib = wave & 1;

    for (int i = t; i < 32 * 132; i += 256) lSt[i] = 0;
    f16acc sacc;
#pragma unroll
    for (int r = 0; r < 16; r++) sacc[r] = 0.f;
    __syncthreads();

    for (int c = 0; c < NCHK; c++) {
        int s0 = c * C_CH;
        size_t bhc = (size_t)(b * 32 + h) * 16 + c;
        size_t bkc = (size_t)(b * 16 + hk) * 16 + c;

        // ---- fragment loads (L2-resident from k_prep) ----
        const unsigned short* Ag = (wave < 2) ? (Wg + bhc * 8192) : (Qbg + bkc * 8192);
        bf8_t afr[8];
#pragma unroll
        for (int kk = 0; kk < 8; kk++)
            afr[kk] = *(const bf8_t*)&Ag[(ib * 32 + lm) * 128 + kk * 16 + half * 8];
        bf8_t ktfr[4];
#pragma unroll
        for (int u = 0; u < 4; u++)
            ktfr[u] = *(const bf8_t*)&KbTg[bhc * 8192 + (wave * 32 + lm) * 64 + u * 16 + half * 8];
        bf8_t pfr[4];
        f4_t lamv[4];
        if (wave >= 2) {
#pragma unroll
            for (int u = 0; u < 4; u++)
                pfr[u] = *(const bf8_t*)&Pg[bhc * 4096 + (ib * 32 + lm) * 64 + u * 16 + half * 8];
#pragma unroll
            for (int q = 0; q < 4; q++)
                lamv[q] = *(const f4_t*)&Lamg[bhc * 64 + ib * 32 + q * 8 + half * 4];
        }
        float lamC = Lamg[bhc * 64 + 63];

        // ---- phase 1: Delta (waves 0,1, C-init = U) / Qacc (waves 2,3) ----
        f16acc wacc;
        if (wave < 2) {
            const float* up = o + (size_t)(b * SEQ + s0 + ib * 32) * 4096 + h * 128 + vs * 32 + lm;
#pragma unroll
            for (int r = 0; r < 16; r++) {
                int ml = (r & 3) + 8 * (r >> 2) + 4 * half;
                wacc[r] = up[(size_t)ml * 4096];
            }
        } else {
#pragma unroll
            for (int r = 0; r < 16; r++) wacc[r] = 0.f;
        }
#pragma unroll
        for (int kk = 0; kk < 8; kk++) {
            bf8_t bb = lds_frag(&lSt[lm * 132 + kk * 16 + half * 8]);
            wacc = __builtin_amdgcn_mfma_f32_32x32x16_bf16(afr[kk], bb, wacc, 0, 0, 0);
        }
        if (wave < 2) {
#pragma unroll
            for (int r = 0; r < 16; r++) {
                int ml = (r & 3) + 8 * (r >> 2) + 4 * half;
                lDt[lm * 68 + ib * 32 + ml] = f2bf(wacc[r]);
            }
        }
        __syncthreads();   // lDt ready; U reads + lSt reads done

        // ---- tail: O (waves 2,3); S update (all) ----
        if (wave >= 2) {
#pragma unroll
            for (int r = 0; r < 16; r++) wacc[r] *= lamv[r >> 2][r & 3];
#pragma unroll
            for (int u = 0; u < 4; u++) {
                bf8_t bb = lds_frag(&lDt[lm * 68 + u * 16 + half * 8]);
                wacc = __builtin_amdgcn_mfma_f32_32x32x16_bf16(pfr[u], bb, wacc, 0, 0, 0);
            }
#pragma unroll
            for (int r = 0; r < 16; r++) {
                int ml = (r & 3) + 8 * (r >> 2) + 4 * half;
                o[(size_t)(b * SEQ + s0 + ib * 32 + ml) * 4096 + h * 128 + vs * 32 + lm] = wacc[r];
            }
        }
#pragma unroll
        for (int r = 0; r < 16; r++) sacc[r] *= lamC;
#pragma unroll
        for (int u = 0; u < 4; u++) {
            bf8_t bb = lds_frag(&lDt[lm * 68 + u * 16 + half * 8]);
            sacc = __builtin_amdgcn_mfma_f32_32x32x16_bf16(ktfr[u], bb, sacc, 0, 0, 0);
        }
#pragma unroll
        for (int r = 0; r < 16; r++) {
            int ml = (r & 3) + 8 * (r >> 2) + 4 * half;
            lSt[lm * 132 + 32 * wave + ml] = f2bf(sacc[r]);
        }
        __syncthreads();
    }
}

// ---------------- gated RMSNorm -> bf16 ----------------
__global__ __launch_bounds__(256) void k_gnorm(const float* __restrict__ o,
                                               const float* __restrict__ mixed,
                                               const float* __restrict__ norm_w,
                                               unsigned short* __restrict__ on) {
    int tok = blockIdx.x, t = threadIdx.x;
    int hh = t >> 3, ln = t & 7;
    const f4_t* op = (const f4_t*)(o + (size_t)tok * 4096 + hh * 128 + ln * 16);
    const f4_t* zp = (const f4_t*)(mixed + (size_t)tok * N1 + 8192 + hh * 128 + ln * 16);
    float og[16];
    float ss = 0.f;
#pragma unroll
    for (int i = 0; i < 4; i++) {
        f4_t ov = op[i], zv = zp[i];
#pragma unroll
        for (int j = 0; j < 4; j++) {
            float z = zv[j];
            float g = ov[j] * (z / (1.f + expf(-z)));
            og[i * 4 + j] = g;
            ss += g * g;
        }
    }
    ss += __shfl_xor(ss, 1); ss += __shfl_xor(ss, 2); ss += __shfl_xor(ss, 4);
    float r = 1.f / sqrtf(ss * (1.f / 128.f) + 1e-6f);
    unsigned short* onp = on + (size_t)tok * 4096 + hh * 128 + ln * 16;
    u16x8 a, bb;
#pragma unroll
    for (int j = 0; j < 8; j++) a[j] = f2bf(og[j] * r * norm_w[ln * 16 + j]);
#pragma unroll
    for (int j = 0; j < 8; j++) bb[j] = f2bf(og[8 + j] * r * norm_w[ln * 16 + 8 + j]);
    ((u16x8*)onp)[0] = a;
    ((u16x8*)onp)[1] = bb;
}

extern "C" void kernel_launch(void* const* d_in, const int* in_sizes, int n_in,
                              void* d_out, int out_size, void* d_ws, size_t ws_size,
                              hipStream_t stream) {
    const float* hs      = (const float*)d_in[0];
    const float* conv_w  = (const float*)d_in[1];
    const float* w_qkv   = (const float*)d_in[2];
    const float* w_z     = (const float*)d_in[3];
    const float* w_b     = (const float*)d_in[4];
    const float* w_a     = (const float*)d_in[5];
    const float* w_out   = (const float*)d_in[6];
    const float* dt_bias = (const float*)d_in[7];
    const float* A_log   = (const float*)d_in[8];
    const float* norm_w  = (const float*)d_in[9];
    float* out = (float*)d_out;

    // Workspace layout is byte-identical to the 843 µs round-2 kernel (~222 MiB).
    char* ws = (char*)d_ws;
    unsigned short* hs_bf = (unsigned short*)ws; ws += (size_t)NTOK * HIDDEN * 2;     // 8 MiB
    unsigned short* w1t   = (unsigned short*)ws; ws += (size_t)N1 * HIDDEN * 2;       // 48 MiB
    unsigned short* wot   = (unsigned short*)ws; ws += (size_t)HIDDEN * VAL_DIM * 2;  // 16 MiB (live to end)
    float* mixed          = (float*)ws;          ws += (size_t)NTOK * N1 * 4;         // 96 MiB
    float* beta           = (float*)ws;          ws += (size_t)NTOK * 32 * 4;
    float* gval           = (float*)ws;          ws += (size_t)NTOK * 32 * 4;
    float* halo           = (float*)ws;          ws += (size_t)2 * (NCHC - 1) * 3 * 8192 * 4; // 5.8 MiB
    float* o_buf          = (float*)ws;          ws += (size_t)NTOK * VAL_DIM * 4;    // 32 MiB (U then O)
    unsigned short* on_bf = (unsigned short*)ws; ws += (size_t)NTOK * VAL_DIM * 2;

    // k_prep/k_state scratch ALIASED over buffers dead by that point:
    //   hs_bf + w1t (56 MiB, dead after first GEMM) holds Wg|Pg|KbTg|Qbg (48 MiB);
    //   halo (dead after k_conv) holds Lamg; U lives pre-O inside o_buf.
    char* al = (char*)hs_bf;
    unsigned short* Wg    = (unsigned short*)al; al += (size_t)1024 * 8192 * 2;  // 16 MiB
    unsigned short* Pg    = (unsigned short*)al; al += (size_t)1024 * 4096 * 2;  //  8 MiB
    unsigned short* KbTg  = (unsigned short*)al; al += (size_t)1024 * 8192 * 2;  // 16 MiB
    unsigned short* Qbg   = (unsigned short*)al; al += (size_t)512 * 8192 * 2;   //  8 MiB
    float* Lamg           = (float*)halo;

    k_cast_hs<<<dim3(NTOK * HIDDEN / 4 / 256), 256, 0, stream>>>(hs, hs_bf);
    k_trans_w1<<<dim3(N1 / 32, HIDDEN / 32), 256, 0, stream>>>(w_qkv, w_z, w1t);
    k_trans<<<dim3(HIDDEN / 32, VAL_DIM / 32), 256, 0, stream>>>(w_out, wot, VAL_DIM, HIDDEN);
    k_gemm_bt<<<dim3(NTOK / 128, N1 / 128), 256, 0, stream>>>(hs_bf, w1t, mixed, HIDDEN, N1);
    k_beta_g<<<dim3(NTOK), 256, 0, stream>>>(hs, w_b, w_a, dt_bias, A_log, beta, gval);
    k_halo<<<dim3(2 * (NCHC - 1) * 3 * 8192 / 256), 256, 0, stream>>>(mixed, halo);
    k_conv<<<dim3(2 * NCHC * 8192 / 256), 256, 0, stream>>>(mixed, conv_w, halo);
    k_l2norm<<<dim3(NTOK), 256, 0, stream>>>(mixed);
    k_prep<<<dim3(1024), 256, 0, stream>>>(mixed, beta, gval, Pg, KbTg, Qbg, Wg, o_buf, Lamg);
    k_state<<<dim3(256), 256, 0, stream>>>(Wg, Pg, KbTg, Qbg, Lamg, o_buf);
    k_gnorm<<<dim3(NTOK), 256, 0, stream>>>(o_buf, mixed, norm_w, on_bf);
    k_gemm_bt<<<dim3(NTOK / 128, HIDDEN / 128), 256, 0, stream>>>(on_bf, wot, out, VAL_DIM, HIDDEN);
}

// Round 5
// 602.436 us; speedup vs baseline: 1.5207x; 1.2315x over previous
//
#include <hip/hip_runtime.h>
#include <hip/hip_bf16.h>
#include <cstdint>

#define HIDDEN   2048
#define HV       32
#define HK       16
#define DK       128
#define DV       128
#define KEY_DIM  2048
#define VAL_DIM  4096
#define CONV_DIM 8192
#define NTOK     2048   // B*S
#define SEQ      1024
#define N1       12288  // 2*KEY_DIM + VAL_DIM (qkv ++ z fused GEMM)
#define C_CH     64     // delta-rule chunk length
#define NCHK     (SEQ / C_CH)

typedef __attribute__((ext_vector_type(4))) float f4_t;
typedef __attribute__((ext_vector_type(2))) float f2_t;
typedef __attribute__((ext_vector_type(8))) short bf8_t;
typedef __attribute__((ext_vector_type(16))) float f16acc;
typedef __attribute__((ext_vector_type(4))) unsigned short u16x4;
typedef __attribute__((ext_vector_type(8))) unsigned short u16x8;
typedef __attribute__((ext_vector_type(2))) uint32_t u32x2;
typedef __attribute__((ext_vector_type(4))) uint32_t u32x4;

__device__ __forceinline__ unsigned short f2bf(float f) {
    union { float f; uint32_t u; } a; a.f = f;
    uint32_t u = a.u;
    return (unsigned short)((u + 0x7fff + ((u >> 16) & 1)) >> 16);
}
__device__ __forceinline__ float bf2f(unsigned short h) {
    uint32_t u = ((uint32_t)h) << 16;
    union { uint32_t u; float f; } a; a.u = u;
    return a.f;
}
// 16B LDS fragment via two 8B loads (rows are 8B-aligned, strides chosen 2-way-max banks)
__device__ __forceinline__ bf8_t lds_frag(const unsigned short* p) {
    u32x2 a = *(const u32x2*)p;
    u32x2 b = *(const u32x2*)(p + 4);
    u32x4 w = {a[0], a[1], b[0], b[1]};
    return __builtin_bit_cast(bf8_t, w);
}

// ---------------- cast hs -> bf16 ----------------
__global__ __launch_bounds__(256) void k_cast_hs(const float* __restrict__ hs,
                                                 unsigned short* __restrict__ out) {
    int i = blockIdx.x * 256 + threadIdx.x;
    f4_t v = ((const f4_t*)hs)[i];
    u16x4 o;
    o[0] = f2bf(v[0]); o[1] = f2bf(v[1]); o[2] = f2bf(v[2]); o[3] = f2bf(v[3]);
    ((u16x4*)out)[i] = o;
}

// ---------------- transpose+cast: W1t[n][k] = {w_qkv|w_z}[k][n] ----------------
__global__ __launch_bounds__(256) void k_trans_w1(const float* __restrict__ w_qkv,
                                                  const float* __restrict__ w_z,
                                                  unsigned short* __restrict__ w1t) {
    __shared__ float tile[32][33];
    int tx = threadIdx.x & 31, ty = threadIdx.x >> 5;
    int n0 = blockIdx.x * 32, k0 = blockIdx.y * 32;
    int n = n0 + tx;
#pragma unroll
    for (int i = 0; i < 4; i++) {
        int k = k0 + ty + i * 8;
        float v = (n < CONV_DIM) ? w_qkv[(size_t)k * CONV_DIM + n]
                                 : w_z[(size_t)k * VAL_DIM + (n - CONV_DIM)];
        tile[ty + i * 8][tx] = v;
    }
    __syncthreads();
#pragma unroll
    for (int i = 0; i < 4; i++)
        w1t[(size_t)(n0 + ty + i * 8) * HIDDEN + k0 + tx] = f2bf(tile[tx][ty + i * 8]);
}

__global__ __launch_bounds__(256) void k_trans(const float* __restrict__ src,
                                               unsigned short* __restrict__ dst,
                                               int K, int N) {
    __shared__ float tile[32][33];
    int tx = threadIdx.x & 31, ty = threadIdx.x >> 5;
    int n0 = blockIdx.x * 32, k0 = blockIdx.y * 32;
#pragma unroll
    for (int i = 0; i < 4; i++)
        tile[ty + i * 8][tx] = src[(size_t)(k0 + ty + i * 8) * N + n0 + tx];
    __syncthreads();
#pragma unroll
    for (int i = 0; i < 4; i++)
        dst[(size_t)(n0 + ty + i * 8) * K + k0 + tx] = f2bf(tile[tx][ty + i * 8]);
}

// ---------------- bf16 MFMA GEMM:  C[M,N] = A[M,K] * B[N,K]^T ----------------
__global__ __launch_bounds__(256, 2) void k_gemm_bt(const unsigned short* __restrict__ A,
                                                    const unsigned short* __restrict__ B,
                                                    float* __restrict__ C, int K, int N) {
    __shared__ unsigned short lA[128 * 32];
    __shared__ unsigned short lB[128 * 32];
    int tid = threadIdx.x;
    int wave = tid >> 6, lane = tid & 63;
    int m0 = blockIdx.x * 128, n0 = blockIdx.y * 128;
    int wm = wave & 1, wn = wave >> 1;
    f4_t acc[4][4];
#pragma unroll
    for (int i = 0; i < 4; i++)
#pragma unroll
        for (int j = 0; j < 4; j++) acc[i][j] = (f4_t){0.f, 0.f, 0.f, 0.f};
    int srow = wave * 16 + (lane >> 2);
    int scol = (lane & 3) * 8;
    int quad = lane >> 4, lrow = lane & 15;

    for (int k0 = 0; k0 < K; k0 += 32) {
        const unsigned short* gA0 = A + (size_t)(m0 + srow) * K + k0 + scol;
        const unsigned short* gA1 = A + (size_t)(m0 + 64 + srow) * K + k0 + scol;
        const unsigned short* gB0 = B + (size_t)(n0 + srow) * K + k0 + scol;
        const unsigned short* gB1 = B + (size_t)(n0 + 64 + srow) * K + k0 + scol;
        __syncthreads();
        __builtin_amdgcn_global_load_lds((const __attribute__((address_space(1))) void*)gA0,
            (__attribute__((address_space(3))) void*)(&lA[wave * 512]), 16, 0, 0);
        __builtin_amdgcn_global_load_lds((const __attribute__((address_space(1))) void*)gA1,
            (__attribute__((address_space(3))) void*)(&lA[2048 + wave * 512]), 16, 0, 0);
        __builtin_amdgcn_global_load_lds((const __attribute__((address_space(1))) void*)gB0,
            (__attribute__((address_space(3))) void*)(&lB[wave * 512]), 16, 0, 0);
        __builtin_amdgcn_global_load_lds((const __attribute__((address_space(1))) void*)gB1,
            (__attribute__((address_space(3))) void*)(&lB[2048 + wave * 512]), 16, 0, 0);
        __syncthreads();
        bf8_t af[4], bfv[4];
#pragma unroll
        for (int i = 0; i < 4; i++) {
            af[i]  = *(const bf8_t*)&lA[(wm * 64 + i * 16 + lrow) * 32 + quad * 8];
            bfv[i] = *(const bf8_t*)&lB[(wn * 64 + i * 16 + lrow) * 32 + quad * 8];
        }
#pragma unroll
        for (int i = 0; i < 4; i++)
#pragma unroll
            for (int j = 0; j < 4; j++)
                acc[i][j] = __builtin_amdgcn_mfma_f32_16x16x32_bf16(af[i], bfv[j], acc[i][j], 0, 0, 0);
    }
#pragma unroll
    for (int i = 0; i < 4; i++) {
        int row_b = m0 + wm * 64 + i * 16 + quad * 4;
#pragma unroll
        for (int j = 0; j < 4; j++) {
            int col = n0 + wn * 64 + j * 16 + lrow;
#pragma unroll
            for (int r = 0; r < 4; r++)
                C[(size_t)(row_b + r) * N + col] = acc[i][j][r];
        }
    }
}

// ---------------- beta / raw log-decay g ----------------
// Skinny GEMM C[2048 tok][64] = hs @ [w_b|w_a], fp32 exact.
// 4 tokens/block (512 blocks). Thread = (h-quad hq, k-partition kp):
// float4 weight loads (16B/lane, full L2 request rate), 16 independent
// FMA streams/thread. Weight L2 traffic = 512 blocks x 512KB = 256MB.
#define BG_TOK 4
__global__ __launch_bounds__(256) void k_beta_g(const float* __restrict__ hs,
                                                const float* __restrict__ w_b,
                                                const float* __restrict__ w_a,
                                                const float* __restrict__ dt_bias,
                                                const float* __restrict__ A_log,
                                                float* __restrict__ beta,
                                                float* __restrict__ gval) {
    __shared__ float rows[BG_TOK * HIDDEN];   // 32 KB
    __shared__ float part[BG_TOK][64][17];    // 17.4 KB, padded stride
    int t = threadIdx.x;
    int tok0 = blockIdx.x * BG_TOK;
    // stage 4 token rows (coalesced f4)
    {
        const f4_t* src = (const f4_t*)(hs + (size_t)tok0 * HIDDEN);
        f4_t* dst = (f4_t*)rows;
#pragma unroll
        for (int u = 0; u < BG_TOK * HIDDEN / 4 / 256; u++)
            dst[t + u * 256] = src[t + u * 256];
    }
    __syncthreads();
    int hq = t & 15, kp = t >> 4;          // 16 h-quads x 16 k-partitions
    int h0 = hq * 4;
    const float* wsrc = (h0 < 32) ? (w_b + h0) : (w_a + (h0 - 32));
    f4_t acc[BG_TOK];
#pragma unroll
    for (int x = 0; x < BG_TOK; x++) acc[x] = (f4_t){0.f, 0.f, 0.f, 0.f};
    int kbase = kp * 128;
#pragma unroll 4
    for (int i = 0; i < 128; i++) {
        int k = kbase + i;
        f4_t wv = *(const f4_t*)(wsrc + (size_t)k * 32);
#pragma unroll
        for (int x = 0; x < BG_TOK; x++) {
            float r = rows[x * HIDDEN + k];
            acc[x][0] += wv[0] * r;
            acc[x][1] += wv[1] * r;
            acc[x][2] += wv[2] * r;
            acc[x][3] += wv[3] * r;
        }
    }
#pragma unroll
    for (int x = 0; x < BG_TOK; x++)
#pragma unroll
        for (int e = 0; e < 4; e++)
            part[x][h0 + e][kp] = acc[x][e];
    __syncthreads();
    // reduce 16 partials and apply nonlinearity: thread = (token x, output h)
    int x = t >> 6, h = t & 63;
    float s = 0.f;
#pragma unroll
    for (int k2 = 0; k2 < 16; k2++) s += part[x][h][k2];
    int tok = tok0 + x;
    if (h < 32) {
        beta[tok * 32 + h] = 1.f / (1.f + expf(-s));
    } else {
        int hh = h - 32;
        float xx = s + dt_bias[hh];
        float sp = (xx > 20.f) ? xx : log1pf(expf(xx));
        gval[tok * 32 + hh] = -expf(A_log[hh]) * sp;   // log-decay (<= 0)
    }
}

// ---------------- conv halo + chunked in-place conv ----------------
#define CCH 32
#define NCHC (SEQ / CCH)
__global__ __launch_bounds__(256) void k_halo(const float* __restrict__ mixed,
                                              float* __restrict__ halo) {
    int id = blockIdx.x * 256 + threadIdx.x;
    int c = id & 8191;
    int r = id >> 13;
    int tap = r % 3;
    int ck = (r / 3) % (NCHC - 1);
    int b = r / (3 * (NCHC - 1));
    int s = (ck + 1) * CCH - 1 - tap;
    halo[id] = mixed[(size_t)(b * SEQ + s) * N1 + c];
}

__global__ __launch_bounds__(256) void k_conv(float* __restrict__ mixed,
                                              const float* __restrict__ cw,
                                              const float* __restrict__ halo) {
    int id = blockIdx.x * 256 + threadIdx.x;
    int c = id & 8191;
    int r = id >> 13;
    int chunk = r & (NCHC - 1), b = r >> 5;
    int s0 = chunk * CCH;
    float w0 = cw[c * 4 + 0], w1 = cw[c * 4 + 1], w2 = cw[c * 4 + 2], w3 = cw[c * 4 + 3];
    float xm1, xm2, xm3;
    if (chunk == 0) {
        xm1 = xm2 = xm3 = 0.f;
    } else {
        const float* hp = halo + (size_t)(b * (NCHC - 1) + chunk - 1) * 3 * 8192;
        xm1 = hp[0 * 8192 + c]; xm2 = hp[1 * 8192 + c]; xm3 = hp[2 * 8192 + c];
    }
    float* col = mixed + (size_t)(b * SEQ + s0) * N1 + c;
#pragma unroll
    for (int s = 0; s < CCH; s++) {
        float x = col[(size_t)s * N1];
        float y = w3 * x + w2 * xm1 + w1 * xm2 + w0 * xm3;
        y = y / (1.f + expf(-y));
        col[(size_t)s * N1] = y;
        xm3 = xm2; xm2 = xm1; xm1 = x;
    }
}

// ---------------- l2norm of q (with 1/sqrt(DK)) and k, in-place ----------------
__global__ __launch_bounds__(256) void k_l2norm(float* __restrict__ mixed) {
    int tok = blockIdx.x, t = threadIdx.x;
    int vec = t >> 3, ln = t & 7;
    int off = (vec < 16) ? vec * 128 : 2048 + (vec - 16) * 128;
    float* p = mixed + (size_t)tok * N1 + off + ln * 16;
    f4_t x0 = ((f4_t*)p)[0], x1 = ((f4_t*)p)[1], x2 = ((f4_t*)p)[2], x3 = ((f4_t*)p)[3];
    float ss = 0.f;
#pragma unroll
    for (int i = 0; i < 4; i++) ss += x0[i]*x0[i] + x1[i]*x1[i] + x2[i]*x2[i] + x3[i]*x3[i];
    ss += __shfl_xor(ss, 1); ss += __shfl_xor(ss, 2); ss += __shfl_xor(ss, 4);
    float sc = 1.f / sqrtf(ss + 1e-6f);
    if (vec < 16) sc *= 0.08838834764831845f;
#pragma unroll
    for (int i = 0; i < 4; i++) { x0[i]*=sc; x1[i]*=sc; x2[i]*=sc; x3[i]*=sc; }
    ((f4_t*)p)[0] = x0; ((f4_t*)p)[1] = x1; ((f4_t*)p)[2] = x2; ((f4_t*)p)[3] = x3;
}

// ---------------- chunk-local precompute + UT transform (parallel over b,h,c) ----------------
// Per (b,h,chunk): stage K,Q (bf16), scan g/beta; compute
//   M  = beta_i*(K K^T)*exp(Gi-Gj)   (strict lower, fp32, kept in LDS)
//   P  = (Q K^T)*exp(Gi-Gj) masked j<=i               -> Pg   (bf16)
//   KbarT[dk][i] = exp(G_C - G_i)*k_i[dk]             -> KbTg (bf16)
//   Q row dump (per b,hk,c; even-h blocks)            -> Qbg  (bf16)
//   Lam[i]=exp(G_i)                                   -> Lamg (fp32)
// UT transform: solve (I+M) X = [beta.*V | beta.*Lam.*K] by exact fp32 forward
// substitution (one column per thread, ascending-j order == old k_state solve):
//   U = X[:, 0:128]    -> stored fp32 INTO o_buf slots this chunk's O will overwrite
//   Wneg = -X[:,128:]  -> Wg (bf16)
// Then Delta = U + Wneg*S0 is a pure MFMA in the sequential kernel.
__global__ __launch_bounds__(256, 2) void k_prep(const float* __restrict__ mixed,
                                                 const float* __restrict__ beta,
                                                 const float* __restrict__ gval,
                                                 unsigned short* __restrict__ Pg,
                                                 unsigned short* __restrict__ KbTg,
                                                 unsigned short* __restrict__ Qbg,
                                                 unsigned short* __restrict__ Wg,
                                                 float* __restrict__ Ug,
                                                 float* __restrict__ Lamg) {
    __shared__ unsigned short lK[64 * 132];
    __shared__ unsigned short lQ[64 * 132];
    __shared__ float lM[64 * 66];
    __shared__ float lG[64], lLam[64], lBeta[64], lKsc[64];

    int blk = blockIdx.x;
    int c = blk & 15, h = (blk >> 4) & 31, b = blk >> 9;
    int hk = h >> 1;
    int t = threadIdx.x;
    int wave = t >> 6, lane = t & 63, half = lane >> 5, lm = lane & 31;
    int s0 = c * C_CH;

    const float* qptr = mixed + (size_t)(b * SEQ) * N1 + hk * 128;
    const float* kptr = qptr + 2048;

    // ---- stage K,Q + g/beta scan ----
    {
        int i = t >> 2, c0 = (t & 3) * 32;
        const float* kr = kptr + (size_t)(s0 + i) * N1 + c0;
        const float* qr = qptr + (size_t)(s0 + i) * N1 + c0;
        unsigned short* dK = &lK[i * 132 + c0];
        unsigned short* dQ = &lQ[i * 132 + c0];
#pragma unroll
        for (int u = 0; u < 8; u++) {
            f4_t kv = ((const f4_t*)kr)[u];
            f4_t qv = ((const f4_t*)qr)[u];
            u16x4 ks, qs;
#pragma unroll
            for (int e = 0; e < 4; e++) { ks[e] = f2bf(kv[e]); qs[e] = f2bf(qv[e]); }
            *(u16x4*)(dK + u * 4) = ks;
            *(u16x4*)(dQ + u * 4) = qs;
        }
        if (t < 64) {
            float gv = gval[(size_t)(b * SEQ + s0 + t) * 32 + h];
            float bv = beta[(size_t)(b * SEQ + s0 + t) * 32 + h];
            float x = gv;
#pragma unroll
            for (int d = 1; d < 64; d <<= 1) {
                float y = __shfl_up(x, d);
                if (t >= d) x += y;
            }
            float Gc = __shfl(x, 63);
            lG[t] = x; lLam[t] = expf(x); lBeta[t] = bv; lKsc[t] = expf(Gc - x);
        }
    }
    __syncthreads();

    size_t bhc = (size_t)(b * 32 + h) * 16 + c;
    size_t bkc = (size_t)(b * 16 + hk) * 16 + c;

    // ---- MFMA: M (3 tiles, ->LDS) + P (3 tiles, ->global) ----
    for (int job = wave; job < 6; job += 4) {
        int isP = job >= 3 ? 1 : 0;
        int jj = job - (isP ? 3 : 0);
        int ib = (jj == 0) ? 0 : 1;
        int jb = (jj == 2) ? 1 : 0;
        const unsigned short* Ab = isP ? lQ : lK;
        f16acc acc;
#pragma unroll
        for (int r = 0; r < 16; r++) acc[r] = 0.f;
        int arow = ib * 32 + lm, brow = jb * 32 + lm;
#pragma unroll
        for (int k0 = 0; k0 < 128; k0 += 16) {
            bf8_t a = lds_frag(&Ab[arow * 132 + k0 + half * 8]);
            bf8_t bb = lds_frag(&lK[brow * 132 + k0 + half * 8]);
            acc = __builtin_amdgcn_mfma_f32_32x32x16_bf16(a, bb, acc, 0, 0, 0);
        }
        int j = jb * 32 + lm;
        float Gj = lG[j];
#pragma unroll
        for (int r = 0; r < 16; r++) {
            int ml = (r & 3) + 8 * (r >> 2) + 4 * half;
            int i = ib * 32 + ml;
            float f = expf(lG[i] - Gj);
            if (isP) {
                Pg[bhc * 4096 + i * 64 + j] = f2bf((j <= i) ? acc[r] * f : 0.f);
            } else {
                if (j < i) lM[i * 66 + j] = acc[r] * lBeta[i] * f;
            }
        }
    }
    // zero P upper-right tile (rows 0..31, cols 32..63)
#pragma unroll
    for (int u = 0; u < 4; u++) {
        int e = t * 4 + u;
        Pg[bhc * 4096 + (e >> 5) * 64 + 32 + (e & 31)] = 0;
    }

    // ---- Q dump (shared per hk, only even-h blocks write) ----
    if ((h & 1) == 0) {
        int i = t >> 2, c0 = (t & 3) * 32;
#pragma unroll
        for (int u = 0; u < 8; u++)
            *(u16x4*)&Qbg[bkc * 8192 + i * 128 + c0 + u * 4] = *(const u16x4*)&lQ[i * 132 + c0 + u * 4];
    }

    // ---- KbarT[dk][i] ----
    {
        int dk = t >> 1, i0 = (t & 1) * 32;
        unsigned short tmp[32];
#pragma unroll
        for (int ii = 0; ii < 32; ii++) {
            int i = i0 + ii;
            tmp[ii] = f2bf(bf2f(lK[i * 132 + dk]) * lKsc[i]);
        }
#pragma unroll
        for (int u = 0; u < 4; u++) {
            u16x8 w;
#pragma unroll
            for (int j = 0; j < 8; j++) w[j] = tmp[u * 8 + j];
            *(u16x8*)&KbTg[bhc * 8192 + dk * 64 + i0 + u * 8] = w;
        }
    }
    if (t < 64) Lamg[bhc * 64 + t] = lLam[t];

    __syncthreads();   // lM fully populated

    // ---- UT transform: (I+M) X = [beta.*V | beta.*Lam.*K], one column/thread ----
    {
        float x[64];
        if (t < 128) {
            const float* vcol = mixed + (size_t)(b * SEQ + s0) * N1 + 4096 + h * 128 + t;
#pragma unroll
            for (int il = 0; il < 64; il++) x[il] = lBeta[il] * vcol[(size_t)il * N1];
        } else {
            int dk = t - 128;
#pragma unroll
            for (int il = 0; il < 64; il++) x[il] = lBeta[il] * lLam[il] * bf2f(lK[il * 132 + dk]);
        }
#pragma unroll
        for (int il = 1; il < 64; il++)
#pragma unroll
            for (int j = 0; j < il; j++)
                x[il] -= lM[il * 66 + j] * x[j];
        if (t < 128) {
            float* up = Ug + (size_t)(b * SEQ + s0) * 4096 + h * 128 + t;
#pragma unroll
            for (int il = 0; il < 64; il++) up[(size_t)il * 4096] = x[il];
        } else {
            unsigned short* wp = Wg + bhc * 8192 + (t - 128);
#pragma unroll
            for (int il = 0; il < 64; il++) wp[il * 128] = f2bf(-x[il]);
        }
    }
}

// ---------------- sequential state recurrence (pure MFMA) ----------------
// grid 256 = (b, h, vs): 4 waves, state slice S[128dk, 32dv] in MFMA accumulators.
// Per chunk (2 barriers):
//   waves 0,1: Delta = U + Wneg*S0 (U as C-init); waves 2,3: Qacc = Q*S0
//   -> Delta^T bf16 to LDS -> barrier
//   waves 2,3: O = diag(Lam)*Qacc + P*Delta (overwrites U slots in o)
//   all waves: S <- LamC*S + KbarT*Delta -> lSt -> barrier
__global__ __launch_bounds__(256, 1) void k_state(const unsigned short* __restrict__ Wg,
                                                  const unsigned short* __restrict__ Pg,
                                                  const unsigned short* __restrict__ KbTg,
                                                  const unsigned short* __restrict__ Qbg,
                                                  const float* __restrict__ Lamg,
                                                  float* __restrict__ o) {
    __shared__ unsigned short lSt[32 * 132];  // S^T bf16 [v][dk]
    __shared__ unsigned short lDt[32 * 68];   // Delta^T bf16 [v][i]

    int blk = blockIdx.x;
    int vs = blk & 3, h = (blk >> 2) & 31, b = blk >> 7;
    int hk = h >> 1;
    int t = threadIdx.x;
    int wave = t >> 6, lane = t & 63, half = lane >> 5, lm = lane & 31;
    int ib = wave & 1;

    for (int i = t; i < 32 * 132; i += 256) lSt[i] = 0;
    f16acc sacc;
#pragma unroll
    for (int r = 0; r < 16; r++) sacc[r] = 0.f;
    __syncthreads();

    for (int c = 0; c < NCHK; c++) {
        int s0 = c * C_CH;
        size_t bhc = (size_t)(b * 32 + h) * 16 + c;
        size_t bkc = (size_t)(b * 16 + hk) * 16 + c;

        // ---- fragment loads (L2-resident from k_prep) ----
        const unsigned short* Ag = (wave < 2) ? (Wg + bhc * 8192) : (Qbg + bkc * 8192);
        bf8_t afr[8];
#pragma unroll
        for (int kk = 0; kk < 8; kk++)
            afr[kk] = *(const bf8_t*)&Ag[(ib * 32 + lm) * 128 + kk * 16 + half * 8];
        bf8_t ktfr[4];
#pragma unroll
        for (int u = 0; u < 4; u++)
            ktfr[u] = *(const bf8_t*)&KbTg[bhc * 8192 + (wave * 32 + lm) * 64 + u * 16 + half * 8];
        bf8_t pfr[4];
        f4_t lamv[4];
        if (wave >= 2) {
#pragma unroll
            for (int u = 0; u < 4; u++)
                pfr[u] = *(const bf8_t*)&Pg[bhc * 4096 + (ib * 32 + lm) * 64 + u * 16 + half * 8];
#pragma unroll
            for (int q = 0; q < 4; q++)
                lamv[q] = *(const f4_t*)&Lamg[bhc * 64 + ib * 32 + q * 8 + half * 4];
        }
        float lamC = Lamg[bhc * 64 + 63];

        // ---- phase 1: Delta (waves 0,1, C-init = U) / Qacc (waves 2,3) ----
        f16acc wacc;
        if (wave < 2) {
            const float* up = o + (size_t)(b * SEQ + s0 + ib * 32) * 4096 + h * 128 + vs * 32 + lm;
#pragma unroll
            for (int r = 0; r < 16; r++) {
                int ml = (r & 3) + 8 * (r >> 2) + 4 * half;
                wacc[r] = up[(size_t)ml * 4096];
            }
        } else {
#pragma unroll
            for (int r = 0; r < 16; r++) wacc[r] = 0.f;
        }
#pragma unroll
        for (int kk = 0; kk < 8; kk++) {
            bf8_t bb = lds_frag(&lSt[lm * 132 + kk * 16 + half * 8]);
            wacc = __builtin_amdgcn_mfma_f32_32x32x16_bf16(afr[kk], bb, wacc, 0, 0, 0);
        }
        if (wave < 2) {
#pragma unroll
            for (int r = 0; r < 16; r++) {
                int ml = (r & 3) + 8 * (r >> 2) + 4 * half;
                lDt[lm * 68 + ib * 32 + ml] = f2bf(wacc[r]);
            }
        }
        __syncthreads();   // lDt ready; U reads + lSt reads done

        // ---- tail: O (waves 2,3); S update (all) ----
        if (wave >= 2) {
#pragma unroll
            for (int r = 0; r < 16; r++) wacc[r] *= lamv[r >> 2][r & 3];
#pragma unroll
            for (int u = 0; u < 4; u++) {
                bf8_t bb = lds_frag(&lDt[lm * 68 + u * 16 + half * 8]);
                wacc = __builtin_amdgcn_mfma_f32_32x32x16_bf16(pfr[u], bb, wacc, 0, 0, 0);
            }
#pragma unroll
            for (int r = 0; r < 16; r++) {
                int ml = (r & 3) + 8 * (r >> 2) + 4 * half;
                o[(size_t)(b * SEQ + s0 + ib * 32 + ml) * 4096 + h * 128 + vs * 32 + lm] = wacc[r];
            }
        }
#pragma unroll
        for (int r = 0; r < 16; r++) sacc[r] *= lamC;
#pragma unroll
        for (int u = 0; u < 4; u++) {
            bf8_t bb = lds_frag(&lDt[lm * 68 + u * 16 + half * 8]);
            sacc = __builtin_amdgcn_mfma_f32_32x32x16_bf16(ktfr[u], bb, sacc, 0, 0, 0);
        }
#pragma unroll
        for (int r = 0; r < 16; r++) {
            int ml = (r & 3) + 8 * (r >> 2) + 4 * half;
            lSt[lm * 132 + 32 * wave + ml] = f2bf(sacc[r]);
        }
        __syncthreads();
    }
}

// ---------------- gated RMSNorm -> bf16 ----------------
__global__ __launch_bounds__(256) void k_gnorm(const float* __restrict__ o,
                                               const float* __restrict__ mixed,
                                               const float* __restrict__ norm_w,
                                               unsigned short* __restrict__ on) {
    int tok = blockIdx.x, t = threadIdx.x;
    int hh = t >> 3, ln = t & 7;
    const f4_t* op = (const f4_t*)(o + (size_t)tok * 4096 + hh * 128 + ln * 16);
    const f4_t* zp = (const f4_t*)(mixed + (size_t)tok * N1 + 8192 + hh * 128 + ln * 16);
    float og[16];
    float ss = 0.f;
#pragma unroll
    for (int i = 0; i < 4; i++) {
        f4_t ov = op[i], zv = zp[i];
#pragma unroll
        for (int j = 0; j < 4; j++) {
            float z = zv[j];
            float g = ov[j] * (z / (1.f + expf(-z)));
            og[i * 4 + j] = g;
            ss += g * g;
        }
    }
    ss += __shfl_xor(ss, 1); ss += __shfl_xor(ss, 2); ss += __shfl_xor(ss, 4);
    float r = 1.f / sqrtf(ss * (1.f / 128.f) + 1e-6f);
    unsigned short* onp = on + (size_t)tok * 4096 + hh * 128 + ln * 16;
    u16x8 a, bb;
#pragma unroll
    for (int j = 0; j < 8; j++) a[j] = f2bf(og[j] * r * norm_w[ln * 16 + j]);
#pragma unroll
    for (int j = 0; j < 8; j++) bb[j] = f2bf(og[8 + j] * r * norm_w[ln * 16 + 8 + j]);
    ((u16x8*)onp)[0] = a;
    ((u16x8*)onp)[1] = bb;
}

extern "C" void kernel_launch(void* const* d_in, const int* in_sizes, int n_in,
                              void* d_out, int out_size, void* d_ws, size_t ws_size,
                              hipStream_t stream) {
    const float* hs      = (const float*)d_in[0];
    const float* conv_w  = (const float*)d_in[1];
    const float* w_qkv   = (const float*)d_in[2];
    const float* w_z     = (const float*)d_in[3];
    const float* w_b     = (const float*)d_in[4];
    const float* w_a     = (const float*)d_in[5];
    const float* w_out   = (const float*)d_in[6];
    const float* dt_bias = (const float*)d_in[7];
    const float* A_log   = (const float*)d_in[8];
    const float* norm_w  = (const float*)d_in[9];
    float* out = (float*)d_out;

    // Workspace layout is byte-identical to the 742 µs round-4 kernel (~222 MiB).
    char* ws = (char*)d_ws;
    unsigned short* hs_bf = (unsigned short*)ws; ws += (size_t)NTOK * HIDDEN * 2;     // 8 MiB
    unsigned short* w1t   = (unsigned short*)ws; ws += (size_t)N1 * HIDDEN * 2;       // 48 MiB
    unsigned short* wot   = (unsigned short*)ws; ws += (size_t)HIDDEN * VAL_DIM * 2;  // 16 MiB (live to end)
    float* mixed          = (float*)ws;          ws += (size_t)NTOK * N1 * 4;         // 96 MiB
    float* beta           = (float*)ws;          ws += (size_t)NTOK * 32 * 4;
    float* gval           = (float*)ws;          ws += (size_t)NTOK * 32 * 4;
    float* halo           = (float*)ws;          ws += (size_t)2 * (NCHC - 1) * 3 * 8192 * 4; // 5.8 MiB
    float* o_buf          = (float*)ws;          ws += (size_t)NTOK * VAL_DIM * 4;    // 32 MiB (U then O)
    unsigned short* on_bf = (unsigned short*)ws; ws += (size_t)NTOK * VAL_DIM * 2;

    // k_prep/k_state scratch ALIASED over buffers dead by that point:
    //   hs_bf + w1t (56 MiB, dead after first GEMM) holds Wg|Pg|KbTg|Qbg (48 MiB);
    //   halo (dead after k_conv) holds Lamg; U lives pre-O inside o_buf.
    char* al = (char*)hs_bf;
    unsigned short* Wg    = (unsigned short*)al; al += (size_t)1024 * 8192 * 2;  // 16 MiB
    unsigned short* Pg    = (unsigned short*)al; al += (size_t)1024 * 4096 * 2;  //  8 MiB
    unsigned short* KbTg  = (unsigned short*)al; al += (size_t)1024 * 8192 * 2;  // 16 MiB
    unsigned short* Qbg   = (unsigned short*)al; al += (size_t)512 * 8192 * 2;   //  8 MiB
    float* Lamg           = (float*)halo;

    k_cast_hs<<<dim3(NTOK * HIDDEN / 4 / 256), 256, 0, stream>>>(hs, hs_bf);
    k_trans_w1<<<dim3(N1 / 32, HIDDEN / 32), 256, 0, stream>>>(w_qkv, w_z, w1t);
    k_trans<<<dim3(HIDDEN / 32, VAL_DIM / 32), 256, 0, stream>>>(w_out, wot, VAL_DIM, HIDDEN);
    k_gemm_bt<<<dim3(NTOK / 128, N1 / 128), 256, 0, stream>>>(hs_bf, w1t, mixed, HIDDEN, N1);
    k_beta_g<<<dim3(NTOK / BG_TOK), 256, 0, stream>>>(hs, w_b, w_a, dt_bias, A_log, beta, gval);
    k_halo<<<dim3(2 * (NCHC - 1) * 3 * 8192 / 256), 256, 0, stream>>>(mixed, halo);
    k_conv<<<dim3(2 * NCHC * 8192 / 256), 256, 0, stream>>>(mixed, conv_w, halo);
    k_l2norm<<<dim3(NTOK), 256, 0, stream>>>(mixed);
    k_prep<<<dim3(1024), 256, 0, stream>>>(mixed, beta, gval, Pg, KbTg, Qbg, Wg, o_buf, Lamg);
    k_state<<<dim3(256), 256, 0, stream>>>(Wg, Pg, KbTg, Qbg, Lamg, o_buf);
    k_gnorm<<<dim3(NTOK), 256, 0, stream>>>(o_buf, mixed, norm_w, on_bf);
    k_gemm_bt<<<dim3(NTOK / 128, HIDDEN / 128), 256, 0, stream>>>(on_bf, wot, out, VAL_DIM, HIDDEN);
}

// Round 7
// 574.767 us; speedup vs baseline: 1.5939x; 1.0481x over previous
//
#include <hip/hip_runtime.h>
#include <hip/hip_bf16.h>
#include <cstdint>

#define HIDDEN   2048
#define HV       32
#define HK       16
#define DK       128
#define DV       128
#define KEY_DIM  2048
#define VAL_DIM  4096
#define CONV_DIM 8192
#define NTOK     2048   // B*S
#define SEQ      1024
#define N1       12288  // 2*KEY_DIM + VAL_DIM (qkv ++ z fused GEMM)
#define C_CH     64     // delta-rule chunk length
#define NCHK     (SEQ / C_CH)

typedef __attribute__((ext_vector_type(4))) float f4_t;
typedef __attribute__((ext_vector_type(2))) float f2_t;
typedef __attribute__((ext_vector_type(8))) short bf8_t;
typedef __attribute__((ext_vector_type(16))) float f16acc;
typedef __attribute__((ext_vector_type(4))) unsigned short u16x4;
typedef __attribute__((ext_vector_type(8))) unsigned short u16x8;
typedef __attribute__((ext_vector_type(2))) uint32_t u32x2;
typedef __attribute__((ext_vector_type(4))) uint32_t u32x4;

__device__ __forceinline__ unsigned short f2bf(float f) {
    union { float f; uint32_t u; } a; a.f = f;
    uint32_t u = a.u;
    return (unsigned short)((u + 0x7fff + ((u >> 16) & 1)) >> 16);
}
__device__ __forceinline__ float bf2f(unsigned short h) {
    uint32_t u = ((uint32_t)h) << 16;
    union { uint32_t u; float f; } a; a.u = u;
    return a.f;
}
// 16B LDS fragment via two 8B loads (rows are 8B-aligned, strides chosen 2-way-max banks)
__device__ __forceinline__ bf8_t lds_frag(const unsigned short* p) {
    u32x2 a = *(const u32x2*)p;
    u32x2 b = *(const u32x2*)(p + 4);
    u32x4 w = {a[0], a[1], b[0], b[1]};
    return __builtin_bit_cast(bf8_t, w);
}

// ---------------- cast hs -> bf16 ----------------
__global__ __launch_bounds__(256) void k_cast_hs(const float* __restrict__ hs,
                                                 unsigned short* __restrict__ out) {
    int i = blockIdx.x * 256 + threadIdx.x;
    f4_t v = ((const f4_t*)hs)[i];
    u16x4 o;
    o[0] = f2bf(v[0]); o[1] = f2bf(v[1]); o[2] = f2bf(v[2]); o[3] = f2bf(v[3]);
    ((u16x4*)out)[i] = o;
}

// ---------------- transpose+cast: W1t[n][k] = {w_qkv|w_z}[k][n] ----------------
__global__ __launch_bounds__(256) void k_trans_w1(const float* __restrict__ w_qkv,
                                                  const float* __restrict__ w_z,
                                                  unsigned short* __restrict__ w1t) {
    __shared__ float tile[32][33];
    int tx = threadIdx.x & 31, ty = threadIdx.x >> 5;
    int n0 = blockIdx.x * 32, k0 = blockIdx.y * 32;
    int n = n0 + tx;
#pragma unroll
    for (int i = 0; i < 4; i++) {
        int k = k0 + ty + i * 8;
        float v = (n < CONV_DIM) ? w_qkv[(size_t)k * CONV_DIM + n]
                                 : w_z[(size_t)k * VAL_DIM + (n - CONV_DIM)];
        tile[ty + i * 8][tx] = v;
    }
    __syncthreads();
#pragma unroll
    for (int i = 0; i < 4; i++)
        w1t[(size_t)(n0 + ty + i * 8) * HIDDEN + k0 + tx] = f2bf(tile[tx][ty + i * 8]);
}

__global__ __launch_bounds__(256) void k_trans(const float* __restrict__ src,
                                               unsigned short* __restrict__ dst,
                                               int K, int N) {
    __shared__ float tile[32][33];
    int tx = threadIdx.x & 31, ty = threadIdx.x >> 5;
    int n0 = blockIdx.x * 32, k0 = blockIdx.y * 32;
#pragma unroll
    for (int i = 0; i < 4; i++)
        tile[ty + i * 8][tx] = src[(size_t)(k0 + ty + i * 8) * N + n0 + tx];
    __syncthreads();
#pragma unroll
    for (int i = 0; i < 4; i++)
        dst[(size_t)(n0 + ty + i * 8) * K + k0 + tx] = f2bf(tile[tx][ty + i * 8]);
}

// ---------------- bf16 MFMA GEMM:  C[M,N] = A[M,K] * B[N,K]^T ----------------
// 128x128 tile, double-buffered LDS, stage-early single-barrier loop (T3-minimum):
//   STAGE(next) -> ds_read(cur) -> MFMA -> __syncthreads (drains vmcnt+lgkm) -> flip.
// Next-tile load latency hides under current-tile ds_read+MFMA. Bitwise-identical C.
// Block index XCD-chunk swizzled (T1, bijective; both grids have gridDim.x==16, nwg%8==0).
__global__ __launch_bounds__(256, 2) void k_gemm_bt(const unsigned short* __restrict__ A,
                                                    const unsigned short* __restrict__ B,
                                                    float* __restrict__ C, int K, int N) {
    __shared__ unsigned short lA[2][128 * 32];
    __shared__ unsigned short lB[2][128 * 32];
    int tid = threadIdx.x;
    int wave = tid >> 6, lane = tid & 63;
    // T1: chunked bijective XCD swizzle (gridDim.x == 16 for both launches)
    int nwg = gridDim.x * gridDim.y;
    int lid = blockIdx.y * gridDim.x + blockIdx.x;
    int swz = (lid & 7) * (nwg >> 3) + (lid >> 3);
    int m0 = (swz & 15) * 128, n0 = (swz >> 4) * 128;
    int wm = wave & 1, wn = wave >> 1;
    f4_t acc[4][4];
#pragma unroll
    for (int i = 0; i < 4; i++)
#pragma unroll
        for (int j = 0; j < 4; j++) acc[i][j] = (f4_t){0.f, 0.f, 0.f, 0.f};
    int srow = wave * 16 + (lane >> 2);
    int scol = (lane & 3) * 8;
    int quad = lane >> 4, lrow = lane & 15;

    const unsigned short* gA0 = A + (size_t)(m0 + srow) * K + scol;
    const unsigned short* gA1 = A + (size_t)(m0 + 64 + srow) * K + scol;
    const unsigned short* gB0 = B + (size_t)(n0 + srow) * K + scol;
    const unsigned short* gB1 = B + (size_t)(n0 + 64 + srow) * K + scol;

#define GEMM_STAGE(buf, k0)                                                                        \
    do {                                                                                           \
        __builtin_amdgcn_global_load_lds((const __attribute__((address_space(1))) void*)(gA0 + (k0)), \
            (__attribute__((address_space(3))) void*)(&lA[buf][wave * 512]), 16, 0, 0);            \
        __builtin_amdgcn_global_load_lds((const __attribute__((address_space(1))) void*)(gA1 + (k0)), \
            (__attribute__((address_space(3))) void*)(&lA[buf][2048 + wave * 512]), 16, 0, 0);     \
        __builtin_amdgcn_global_load_lds((const __attribute__((address_space(1))) void*)(gB0 + (k0)), \
            (__attribute__((address_space(3))) void*)(&lB[buf][wave * 512]), 16, 0, 0);            \
        __builtin_amdgcn_global_load_lds((const __attribute__((address_space(1))) void*)(gB1 + (k0)), \
            (__attribute__((address_space(3))) void*)(&lB[buf][2048 + wave * 512]), 16, 0, 0);     \
    } while (0)

    // prologue: stage tile 0, drain, barrier
    GEMM_STAGE(0, 0);
    __syncthreads();

    int cur = 0;
    for (int k0 = 0; k0 < K; k0 += 32) {
        if (k0 + 32 < K) GEMM_STAGE(cur ^ 1, k0 + 32);   // issue next-tile loads FIRST
        bf8_t af[4], bfv[4];
#pragma unroll
        for (int i = 0; i < 4; i++) {
            af[i]  = *(const bf8_t*)&lA[cur][(wm * 64 + i * 16 + lrow) * 32 + quad * 8];
            bfv[i] = *(const bf8_t*)&lB[cur][(wn * 64 + i * 16 + lrow) * 32 + quad * 8];
        }
#pragma unroll
        for (int i = 0; i < 4; i++)
#pragma unroll
            for (int j = 0; j < 4; j++)
                acc[i][j] = __builtin_amdgcn_mfma_f32_16x16x32_bf16(af[i], bfv[j], acc[i][j], 0, 0, 0);
        __syncthreads();   // drains vmcnt(0)+lgkmcnt(0): next buffer landed, cur fully read
        cur ^= 1;
    }
#undef GEMM_STAGE
#pragma unroll
    for (int i = 0; i < 4; i++) {
        int row_b = m0 + wm * 64 + i * 16 + quad * 4;
#pragma unroll
        for (int j = 0; j < 4; j++) {
            int col = n0 + wn * 64 + j * 16 + lrow;
#pragma unroll
            for (int r = 0; r < 4; r++)
                C[(size_t)(row_b + r) * N + col] = acc[i][j][r];
        }
    }
}

// ---------------- beta / raw log-decay g ----------------
// Skinny GEMM C[2048 tok][64] = hs @ [w_b|w_a], fp32 exact.
#define BG_TOK 4
__global__ __launch_bounds__(256) void k_beta_g(const float* __restrict__ hs,
                                                const float* __restrict__ w_b,
                                                const float* __restrict__ w_a,
                                                const float* __restrict__ dt_bias,
                                                const float* __restrict__ A_log,
                                                float* __restrict__ beta,
                                                float* __restrict__ gval) {
    __shared__ float rows[BG_TOK * HIDDEN];   // 32 KB
    __shared__ float part[BG_TOK][64][17];    // 17.4 KB, padded stride
    int t = threadIdx.x;
    int tok0 = blockIdx.x * BG_TOK;
    {
        const f4_t* src = (const f4_t*)(hs + (size_t)tok0 * HIDDEN);
        f4_t* dst = (f4_t*)rows;
#pragma unroll
        for (int u = 0; u < BG_TOK * HIDDEN / 4 / 256; u++)
            dst[t + u * 256] = src[t + u * 256];
    }
    __syncthreads();
    int hq = t & 15, kp = t >> 4;          // 16 h-quads x 16 k-partitions
    int h0 = hq * 4;
    const float* wsrc = (h0 < 32) ? (w_b + h0) : (w_a + (h0 - 32));
    f4_t acc[BG_TOK];
#pragma unroll
    for (int x = 0; x < BG_TOK; x++) acc[x] = (f4_t){0.f, 0.f, 0.f, 0.f};
    int kbase = kp * 128;
#pragma unroll 4
    for (int i = 0; i < 128; i++) {
        int k = kbase + i;
        f4_t wv = *(const f4_t*)(wsrc + (size_t)k * 32);
#pragma unroll
        for (int x = 0; x < BG_TOK; x++) {
            float r = rows[x * HIDDEN + k];
            acc[x][0] += wv[0] * r;
            acc[x][1] += wv[1] * r;
            acc[x][2] += wv[2] * r;
            acc[x][3] += wv[3] * r;
        }
    }
#pragma unroll
    for (int x = 0; x < BG_TOK; x++)
#pragma unroll
        for (int e = 0; e < 4; e++)
            part[x][h0 + e][kp] = acc[x][e];
    __syncthreads();
    int x = t >> 6, h = t & 63;
    float s = 0.f;
#pragma unroll
    for (int k2 = 0; k2 < 16; k2++) s += part[x][h][k2];
    int tok = tok0 + x;
    if (h < 32) {
        beta[tok * 32 + h] = 1.f / (1.f + expf(-s));
    } else {
        int hh = h - 32;
        float xx = s + dt_bias[hh];
        float sp = (xx > 20.f) ? xx : log1pf(expf(xx));
        gval[tok * 32 + hh] = -expf(A_log[hh]) * sp;   // log-decay (<= 0)
    }
}

// ---------------- conv halo + chunked in-place conv ----------------
#define CCH 32
#define NCHC (SEQ / CCH)
__global__ __launch_bounds__(256) void k_halo(const float* __restrict__ mixed,
                                              float* __restrict__ halo) {
    int id = blockIdx.x * 256 + threadIdx.x;
    int c = id & 8191;
    int r = id >> 13;
    int tap = r % 3;
    int ck = (r / 3) % (NCHC - 1);
    int b = r / (3 * (NCHC - 1));
    int s = (ck + 1) * CCH - 1 - tap;
    halo[id] = mixed[(size_t)(b * SEQ + s) * N1 + c];
}

__global__ __launch_bounds__(256) void k_conv(float* __restrict__ mixed,
                                              const float* __restrict__ cw,
                                              const float* __restrict__ halo) {
    int id = blockIdx.x * 256 + threadIdx.x;
    int c = id & 8191;
    int r = id >> 13;
    int chunk = r & (NCHC - 1), b = r >> 5;
    int s0 = chunk * CCH;
    float w0 = cw[c * 4 + 0], w1 = cw[c * 4 + 1], w2 = cw[c * 4 + 2], w3 = cw[c * 4 + 3];
    float xm1, xm2, xm3;
    if (chunk == 0) {
        xm1 = xm2 = xm3 = 0.f;
    } else {
        const float* hp = halo + (size_t)(b * (NCHC - 1) + chunk - 1) * 3 * 8192;
        xm1 = hp[0 * 8192 + c]; xm2 = hp[1 * 8192 + c]; xm3 = hp[2 * 8192 + c];
    }
    float* col = mixed + (size_t)(b * SEQ + s0) * N1 + c;
#pragma unroll
    for (int s = 0; s < CCH; s++) {
        float x = col[(size_t)s * N1];
        float y = w3 * x + w2 * xm1 + w1 * xm2 + w0 * xm3;
        y = y / (1.f + expf(-y));
        col[(size_t)s * N1] = y;
        xm3 = xm2; xm2 = xm1; xm1 = x;
    }
}

// ---------------- l2norm of q (with 1/sqrt(DK)) and k, in-place ----------------
__global__ __launch_bounds__(256) void k_l2norm(float* __restrict__ mixed) {
    int tok = blockIdx.x, t = threadIdx.x;
    int vec = t >> 3, ln = t & 7;
    int off = (vec < 16) ? vec * 128 : 2048 + (vec - 16) * 128;
    float* p = mixed + (size_t)tok * N1 + off + ln * 16;
    f4_t x0 = ((f4_t*)p)[0], x1 = ((f4_t*)p)[1], x2 = ((f4_t*)p)[2], x3 = ((f4_t*)p)[3];
    float ss = 0.f;
#pragma unroll
    for (int i = 0; i < 4; i++) ss += x0[i]*x0[i] + x1[i]*x1[i] + x2[i]*x2[i] + x3[i]*x3[i];
    ss += __shfl_xor(ss, 1); ss += __shfl_xor(ss, 2); ss += __shfl_xor(ss, 4);
    float sc = 1.f / sqrtf(ss + 1e-6f);
    if (vec < 16) sc *= 0.08838834764831845f;
#pragma unroll
    for (int i = 0; i < 4; i++) { x0[i]*=sc; x1[i]*=sc; x2[i]*=sc; x3[i]*=sc; }
    ((f4_t*)p)[0] = x0; ((f4_t*)p)[1] = x1; ((f4_t*)p)[2] = x2; ((f4_t*)p)[3] = x3;
}

// ---------------- chunk-local precompute + UT transform (parallel over b,h,c) ----------------
__global__ __launch_bounds__(256, 2) void k_prep(const float* __restrict__ mixed,
                                                 const float* __restrict__ beta,
                                                 const float* __restrict__ gval,
                                                 unsigned short* __restrict__ Pg,
                                                 unsigned short* __restrict__ KbTg,
                                                 unsigned short* __restrict__ Qbg,
                                                 unsigned short* __restrict__ Wg,
                                                 float* __restrict__ Ug,
                                                 float* __restrict__ Lamg) {
    __shared__ unsigned short lK[64 * 132];
    __shared__ unsigned short lQ[64 * 132];
    __shared__ float lM[64 * 66];
    __shared__ float lG[64], lLam[64], lBeta[64], lKsc[64];

    int blk = blockIdx.x;
    int c = blk & 15, h = (blk >> 4) & 31, b = blk >> 9;
    int hk = h >> 1;
    int t = threadIdx.x;
    int wave = t >> 6, lane = t & 63, half = lane >> 5, lm = lane & 31;
    int s0 = c * C_CH;

    const float* qptr = mixed + (size_t)(b * SEQ) * N1 + hk * 128;
    const float* kptr = qptr + 2048;

    // ---- stage K,Q + g/beta scan ----
    {
        int i = t >> 2, c0 = (t & 3) * 32;
        const float* kr = kptr + (size_t)(s0 + i) * N1 + c0;
        const float* qr = qptr + (size_t)(s0 + i) * N1 + c0;
        unsigned short* dK = &lK[i * 132 + c0];
        unsigned short* dQ = &lQ[i * 132 + c0];
#pragma unroll
        for (int u = 0; u < 8; u++) {
            f4_t kv = ((const f4_t*)kr)[u];
            f4_t qv = ((const f4_t*)qr)[u];
            u16x4 ks, qs;
#pragma unroll
            for (int e = 0; e < 4; e++) { ks[e] = f2bf(kv[e]); qs[e] = f2bf(qv[e]); }
            *(u16x4*)(dK + u * 4) = ks;
            *(u16x4*)(dQ + u * 4) = qs;
        }
        if (t < 64) {
            float gv = gval[(size_t)(b * SEQ + s0 + t) * 32 + h];
            float bv = beta[(size_t)(b * SEQ + s0 + t) * 32 + h];
            float x = gv;
#pragma unroll
            for (int d = 1; d < 64; d <<= 1) {
                float y = __shfl_up(x, d);
                if (t >= d) x += y;
            }
            float Gc = __shfl(x, 63);
            lG[t] = x; lLam[t] = expf(x); lBeta[t] = bv; lKsc[t] = expf(Gc - x);
        }
    }
    __syncthreads();

    size_t bhc = (size_t)(b * 32 + h) * 16 + c;
    size_t bkc = (size_t)(b * 16 + hk) * 16 + c;

    // ---- MFMA: M (3 tiles, ->LDS) + P (3 tiles, ->global) ----
    for (int job = wave; job < 6; job += 4) {
        int isP = job >= 3 ? 1 : 0;
        int jj = job - (isP ? 3 : 0);
        int ib = (jj == 0) ? 0 : 1;
        int jb = (jj == 2) ? 1 : 0;
        const unsigned short* Ab = isP ? lQ : lK;
        f16acc acc;
#pragma unroll
        for (int r = 0; r < 16; r++) acc[r] = 0.f;
        int arow = ib * 32 + lm, brow = jb * 32 + lm;
#pragma unroll
        for (int k0 = 0; k0 < 128; k0 += 16) {
            bf8_t a = lds_frag(&Ab[arow * 132 + k0 + half * 8]);
            bf8_t bb = lds_frag(&lK[brow * 132 + k0 + half * 8]);
            acc = __builtin_amdgcn_mfma_f32_32x32x16_bf16(a, bb, acc, 0, 0, 0);
        }
        int j = jb * 32 + lm;
        float Gj = lG[j];
#pragma unroll
        for (int r = 0; r < 16; r++) {
            int ml = (r & 3) + 8 * (r >> 2) + 4 * half;
            int i = ib * 32 + ml;
            float f = expf(lG[i] - Gj);
            if (isP) {
                Pg[bhc * 4096 + i * 64 + j] = f2bf((j <= i) ? acc[r] * f : 0.f);
            } else {
                if (j < i) lM[i * 66 + j] = acc[r] * lBeta[i] * f;
            }
        }
    }
    // zero P upper-right tile (rows 0..31, cols 32..63)
#pragma unroll
    for (int u = 0; u < 4; u++) {
        int e = t * 4 + u;
        Pg[bhc * 4096 + (e >> 5) * 64 + 32 + (e & 31)] = 0;
    }

    // ---- Q dump (shared per hk, only even-h blocks write) ----
    if ((h & 1) == 0) {
        int i = t >> 2, c0 = (t & 3) * 32;
#pragma unroll
        for (int u = 0; u < 8; u++)
            *(u16x4*)&Qbg[bkc * 8192 + i * 128 + c0 + u * 4] = *(const u16x4*)&lQ[i * 132 + c0 + u * 4];
    }

    // ---- KbarT[dk][i] ----
    {
        int dk = t >> 1, i0 = (t & 1) * 32;
        unsigned short tmp[32];
#pragma unroll
        for (int ii = 0; ii < 32; ii++) {
            int i = i0 + ii;
            tmp[ii] = f2bf(bf2f(lK[i * 132 + dk]) * lKsc[i]);
        }
#pragma unroll
        for (int u = 0; u < 4; u++) {
            u16x8 w;
#pragma unroll
            for (int j = 0; j < 8; j++) w[j] = tmp[u * 8 + j];
            *(u16x8*)&KbTg[bhc * 8192 + dk * 64 + i0 + u * 8] = w;
        }
    }
    if (t < 64) Lamg[bhc * 64 + t] = lLam[t];

    __syncthreads();   // lM fully populated

    // ---- UT transform: (I+M) X = [beta.*V | beta.*Lam.*K], one column/thread ----
    {
        float x[64];
        if (t < 128) {
            const float* vcol = mixed + (size_t)(b * SEQ + s0) * N1 + 4096 + h * 128 + t;
#pragma unroll
            for (int il = 0; il < 64; il++) x[il] = lBeta[il] * vcol[(size_t)il * N1];
        } else {
            int dk = t - 128;
#pragma unroll
            for (int il = 0; il < 64; il++) x[il] = lBeta[il] * lLam[il] * bf2f(lK[il * 132 + dk]);
        }
#pragma unroll
        for (int il = 1; il < 64; il++)
#pragma unroll
            for (int j = 0; j < il; j++)
                x[il] -= lM[il * 66 + j] * x[j];
        if (t < 128) {
            float* up = Ug + (size_t)(b * SEQ + s0) * 4096 + h * 128 + t;
#pragma unroll
            for (int il = 0; il < 64; il++) up[(size_t)il * 4096] = x[il];
        } else {
            unsigned short* wp = Wg + bhc * 8192 + (t - 128);
#pragma unroll
            for (int il = 0; il < 64; il++) wp[il * 128] = f2bf(-x[il]);
        }
    }
}

// ---------------- sequential state recurrence (pure MFMA) ----------------
__global__ __launch_bounds__(256, 1) void k_state(const unsigned short* __restrict__ Wg,
                                                  const unsigned short* __restrict__ Pg,
                                                  const unsigned short* __restrict__ KbTg,
                                                  const unsigned short* __restrict__ Qbg,
                                                  const float* __restrict__ Lamg,
                                                  float* __restrict__ o) {
    __shared__ unsigned short lSt[32 * 132];  // S^T bf16 [v][dk]
    __shared__ unsigned short lDt[32 * 68];   // Delta^T bf16 [v][i]

    int blk = blockIdx.x;
    int vs = blk & 3, h = (blk >> 2) & 31, b = blk >> 7;
    int hk = h >> 1;
    int t = threadIdx.x;
    int wave = t >> 6, lane = t & 63, half = lane >> 5, lm = lane & 31;
    int ib = wave & 1;

    for (int i = t; i < 32 * 132; i += 256) lSt[i] = 0;
    f16acc sacc;
#pragma unroll
    for (int r = 0; r < 16; r++) sacc[r] = 0.f;
    __syncthreads();

    for (int c = 0; c < NCHK; c++) {
        int s0 = c * C_CH;
        size_t bhc = (size_t)(b * 32 + h) * 16 + c;
        size_t bkc = (size_t)(b * 16 + hk) * 16 + c;

        // ---- fragment loads (L2-resident from k_prep) ----
        const unsigned short* Ag = (wave < 2) ? (Wg + bhc * 8192) : (Qbg + bkc * 8192);
        bf8_t afr[8];
#pragma unroll
        for (int kk = 0; kk < 8; kk++)
            afr[kk] = *(const bf8_t*)&Ag[(ib * 32 + lm) * 128 + kk * 16 + half * 8];
        bf8_t ktfr[4];
#pragma unroll
        for (int u = 0; u < 4; u++)
            ktfr[u] = *(const bf8_t*)&KbTg[bhc * 8192 + (wave * 32 + lm) * 64 + u * 16 + half * 8];
        bf8_t pfr[4];
        f4_t lamv[4];
        if (wave >= 2) {
#pragma unroll
            for (int u = 0; u < 4; u++)
                pfr[u] = *(const bf8_t*)&Pg[bhc * 4096 + (ib * 32 + lm) * 64 + u * 16 + half * 8];
#pragma unroll
            for (int q = 0; q < 4; q++)
                lamv[q] = *(const f4_t*)&Lamg[bhc * 64 + ib * 32 + q * 8 + half * 4];
        }
        float lamC = Lamg[bhc * 64 + 63];

        // ---- phase 1: Delta (waves 0,1, C-init = U) / Qacc (waves 2,3) ----
        f16acc wacc;
        if (wave < 2) {
            const float* up = o + (size_t)(b * SEQ + s0 + ib * 32) * 4096 + h * 128 + vs * 32 + lm;
#pragma unroll
            for (int r = 0; r < 16; r++) {
                int ml = (r & 3) + 8 * (r >> 2) + 4 * half;
                wacc[r] = up[(size_t)ml * 4096];
            }
        } else {
#pragma unroll
            for (int r = 0; r < 16; r++) wacc[r] = 0.f;
        }
#pragma unroll
        for (int kk = 0; kk < 8; kk++) {
            bf8_t bb = lds_frag(&lSt[lm * 132 + kk * 16 + half * 8]);
            wacc = __builtin_amdgcn_mfma_f32_32x32x16_bf16(afr[kk], bb, wacc, 0, 0, 0);
        }
        if (wave < 2) {
#pragma unroll
            for (int r = 0; r < 16; r++) {
                int ml = (r & 3) + 8 * (r >> 2) + 4 * half;
                lDt[lm * 68 + ib * 32 + ml] = f2bf(wacc[r]);
            }
        }
        __syncthreads();   // lDt ready; U reads + lSt reads done

        // ---- tail: O (waves 2,3); S update (all) ----
        if (wave >= 2) {
#pragma unroll
            for (int r = 0; r < 16; r++) wacc[r] *= lamv[r >> 2][r & 3];
#pragma unroll
            for (int u = 0; u < 4; u++) {
                bf8_t bb = lds_frag(&lDt[lm * 68 + u * 16 + half * 8]);
                wacc = __builtin_amdgcn_mfma_f32_32x32x16_bf16(pfr[u], bb, wacc, 0, 0, 0);
            }
#pragma unroll
            for (int r = 0; r < 16; r++) {
                int ml = (r & 3) + 8 * (r >> 2) + 4 * half;
                o[(size_t)(b * SEQ + s0 + ib * 32 + ml) * 4096 + h * 128 + vs * 32 + lm] = wacc[r];
            }
        }
#pragma unroll
        for (int r = 0; r < 16; r++) sacc[r] *= lamC;
#pragma unroll
        for (int u = 0; u < 4; u++) {
            bf8_t bb = lds_frag(&lDt[lm * 68 + u * 16 + half * 8]);
            sacc = __builtin_amdgcn_mfma_f32_32x32x16_bf16(ktfr[u], bb, sacc, 0, 0, 0);
        }
#pragma unroll
        for (int r = 0; r < 16; r++) {
            int ml = (r & 3) + 8 * (r >> 2) + 4 * half;
            lSt[lm * 132 + 32 * wave + ml] = f2bf(sacc[r]);
        }
        __syncthreads();
    }
}

// ---------------- gated RMSNorm -> bf16 ----------------
__global__ __launch_bounds__(256) void k_gnorm(const float* __restrict__ o,
                                               const float* __restrict__ mixed,
                                               const float* __restrict__ norm_w,
                                               unsigned short* __restrict__ on) {
    int tok = blockIdx.x, t = threadIdx.x;
    int hh = t >> 3, ln = t & 7;
    const f4_t* op = (const f4_t*)(o + (size_t)tok * 4096 + hh * 128 + ln * 16);
    const f4_t* zp = (const f4_t*)(mixed + (size_t)tok * N1 + 8192 + hh * 128 + ln * 16);
    float og[16];
    float ss = 0.f;
#pragma unroll
    for (int i = 0; i < 4; i++) {
        f4_t ov = op[i], zv = zp[i];
#pragma unroll
        for (int j = 0; j < 4; j++) {
            float z = zv[j];
            float g = ov[j] * (z / (1.f + expf(-z)));
            og[i * 4 + j] = g;
            ss += g * g;
        }
    }
    ss += __shfl_xor(ss, 1); ss += __shfl_xor(ss, 2); ss += __shfl_xor(ss, 4);
    float r = 1.f / sqrtf(ss * (1.f / 128.f) + 1e-6f);
    unsigned short* onp = on + (size_t)tok * 4096 + hh * 128 + ln * 16;
    u16x8 a, bb;
#pragma unroll
    for (int j = 0; j < 8; j++) a[j] = f2bf(og[j] * r * norm_w[ln * 16 + j]);
#pragma unroll
    for (int j = 0; j < 8; j++) bb[j] = f2bf(og[8 + j] * r * norm_w[ln * 16 + 8 + j]);
    ((u16x8*)onp)[0] = a;
    ((u16x8*)onp)[1] = bb;
}

extern "C" void kernel_launch(void* const* d_in, const int* in_sizes, int n_in,
                              void* d_out, int out_size, void* d_ws, size_t ws_size,
                              hipStream_t stream) {
    const float* hs      = (const float*)d_in[0];
    const float* conv_w  = (const float*)d_in[1];
    const float* w_qkv   = (const float*)d_in[2];
    const float* w_z     = (const float*)d_in[3];
    const float* w_b     = (const float*)d_in[4];
    const float* w_a     = (const float*)d_in[5];
    const float* w_out   = (const float*)d_in[6];
    const float* dt_bias = (const float*)d_in[7];
    const float* A_log   = (const float*)d_in[8];
    const float* norm_w  = (const float*)d_in[9];
    float* out = (float*)d_out;

    // Workspace layout is byte-identical to the 602 µs round-5 kernel (~222 MiB).
    char* ws = (char*)d_ws;
    unsigned short* hs_bf = (unsigned short*)ws; ws += (size_t)NTOK * HIDDEN * 2;     // 8 MiB
    unsigned short* w1t   = (unsigned short*)ws; ws += (size_t)N1 * HIDDEN * 2;       // 48 MiB
    unsigned short* wot   = (unsigned short*)ws; ws += (size_t)HIDDEN * VAL_DIM * 2;  // 16 MiB (live to end)
    float* mixed          = (float*)ws;          ws += (size_t)NTOK * N1 * 4;         // 96 MiB
    float* beta           = (float*)ws;          ws += (size_t)NTOK * 32 * 4;
    float* gval           = (float*)ws;          ws += (size_t)NTOK * 32 * 4;
    float* halo           = (float*)ws;          ws += (size_t)2 * (NCHC - 1) * 3 * 8192 * 4; // 5.8 MiB
    float* o_buf          = (float*)ws;          ws += (size_t)NTOK * VAL_DIM * 4;    // 32 MiB (U then O)
    unsigned short* on_bf = (unsigned short*)ws; ws += (size_t)NTOK * VAL_DIM * 2;

    // k_prep/k_state scratch ALIASED over buffers dead by that point:
    //   hs_bf + w1t (56 MiB, dead after first GEMM) holds Wg|Pg|KbTg|Qbg (48 MiB);
    //   halo (dead after k_conv) holds Lamg; U lives pre-O inside o_buf.
    char* al = (char*)hs_bf;
    unsigned short* Wg    = (unsigned short*)al; al += (size_t)1024 * 8192 * 2;  // 16 MiB
    unsigned short* Pg    = (unsigned short*)al; al += (size_t)1024 * 4096 * 2;  //  8 MiB
    unsigned short* KbTg  = (unsigned short*)al; al += (size_t)1024 * 8192 * 2;  // 16 MiB
    unsigned short* Qbg   = (unsigned short*)al; al += (size_t)512 * 8192 * 2;   //  8 MiB
    float* Lamg           = (float*)halo;

    k_cast_hs<<<dim3(NTOK * HIDDEN / 4 / 256), 256, 0, stream>>>(hs, hs_bf);
    k_trans_w1<<<dim3(N1 / 32, HIDDEN / 32), 256, 0, stream>>>(w_qkv, w_z, w1t);
    k_trans<<<dim3(HIDDEN / 32, VAL_DIM / 32), 256, 0, stream>>>(w_out, wot, VAL_DIM, HIDDEN);
    k_gemm_bt<<<dim3(NTOK / 128, N1 / 128), 256, 0, stream>>>(hs_bf, w1t, mixed, HIDDEN, N1);
    k_beta_g<<<dim3(NTOK / BG_TOK), 256, 0, stream>>>(hs, w_b, w_a, dt_bias, A_log, beta, gval);
    k_halo<<<dim3(2 * (NCHC - 1) * 3 * 8192 / 256), 256, 0, stream>>>(mixed, halo);
    k_conv<<<dim3(2 * NCHC * 8192 / 256), 256, 0, stream>>>(mixed, conv_w, halo);
    k_l2norm<<<dim3(NTOK), 256, 0, stream>>>(mixed);
    k_prep<<<dim3(1024), 256, 0, stream>>>(mixed, beta, gval, Pg, KbTg, Qbg, Wg, o_buf, Lamg);
    k_state<<<dim3(256), 256, 0, stream>>>(Wg, Pg, KbTg, Qbg, Lamg, o_buf);
    k_gnorm<<<dim3(NTOK), 256, 0, stream>>>(o_buf, mixed, norm_w, on_bf);
    k_gemm_bt<<<dim3(NTOK / 128, HIDDEN / 128), 256, 0, stream>>>(on_bf, wot, out, VAL_DIM, HIDDEN);
}

// Round 8
// 573.800 us; speedup vs baseline: 1.5966x; 1.0017x over previous
//
#include <hip/hip_runtime.h>
#include <hip/hip_bf16.h>
#include <cstdint>

#define HIDDEN   2048
#define HV       32
#define HK       16
#define DK       128
#define DV       128
#define KEY_DIM  2048
#define VAL_DIM  4096
#define CONV_DIM 8192
#define NTOK     2048   // B*S
#define SEQ      1024
#define N1       12288  // 2*KEY_DIM + VAL_DIM (qkv ++ z fused GEMM)
#define C_CH     64     // delta-rule chunk length
#define NCHK     (SEQ / C_CH)

typedef __attribute__((ext_vector_type(4))) float f4_t;
typedef __attribute__((ext_vector_type(2))) float f2_t;
typedef __attribute__((ext_vector_type(8))) short bf8_t;
typedef __attribute__((ext_vector_type(16))) float f16acc;
typedef __attribute__((ext_vector_type(4))) unsigned short u16x4;
typedef __attribute__((ext_vector_type(8))) unsigned short u16x8;
typedef __attribute__((ext_vector_type(2))) uint32_t u32x2;
typedef __attribute__((ext_vector_type(4))) uint32_t u32x4;

__device__ __forceinline__ unsigned short f2bf(float f) {
    union { float f; uint32_t u; } a; a.f = f;
    uint32_t u = a.u;
    return (unsigned short)((u + 0x7fff + ((u >> 16) & 1)) >> 16);
}
__device__ __forceinline__ float bf2f(unsigned short h) {
    uint32_t u = ((uint32_t)h) << 16;
    union { uint32_t u; float f; } a; a.u = u;
    return a.f;
}
// 16B LDS fragment via two 8B loads (rows are 8B-aligned, strides chosen 2-way-max banks)
__device__ __forceinline__ bf8_t lds_frag(const unsigned short* p) {
    u32x2 a = *(const u32x2*)p;
    u32x2 b = *(const u32x2*)(p + 4);
    u32x4 w = {a[0], a[1], b[0], b[1]};
    return __builtin_bit_cast(bf8_t, w);
}

// ---------------- cast hs -> bf16 ----------------
__global__ __launch_bounds__(256) void k_cast_hs(const float* __restrict__ hs,
                                                 unsigned short* __restrict__ out) {
    int i = blockIdx.x * 256 + threadIdx.x;
    f4_t v = ((const f4_t*)hs)[i];
    u16x4 o;
    o[0] = f2bf(v[0]); o[1] = f2bf(v[1]); o[2] = f2bf(v[2]); o[3] = f2bf(v[3]);
    ((u16x4*)out)[i] = o;
}

// ---------------- transpose+cast: W1t[n][k] = {w_qkv|w_z}[k][n] ----------------
__global__ __launch_bounds__(256) void k_trans_w1(const float* __restrict__ w_qkv,
                                                  const float* __restrict__ w_z,
                                                  unsigned short* __restrict__ w1t) {
    __shared__ float tile[32][33];
    int tx = threadIdx.x & 31, ty = threadIdx.x >> 5;
    int n0 = blockIdx.x * 32, k0 = blockIdx.y * 32;
    int n = n0 + tx;
#pragma unroll
    for (int i = 0; i < 4; i++) {
        int k = k0 + ty + i * 8;
        float v = (n < CONV_DIM) ? w_qkv[(size_t)k * CONV_DIM + n]
                                 : w_z[(size_t)k * VAL_DIM + (n - CONV_DIM)];
        tile[ty + i * 8][tx] = v;
    }
    __syncthreads();
#pragma unroll
    for (int i = 0; i < 4; i++)
        w1t[(size_t)(n0 + ty + i * 8) * HIDDEN + k0 + tx] = f2bf(tile[tx][ty + i * 8]);
}

__global__ __launch_bounds__(256) void k_trans(const float* __restrict__ src,
                                               unsigned short* __restrict__ dst,
                                               int K, int N) {
    __shared__ float tile[32][33];
    int tx = threadIdx.x & 31, ty = threadIdx.x >> 5;
    int n0 = blockIdx.x * 32, k0 = blockIdx.y * 32;
#pragma unroll
    for (int i = 0; i < 4; i++)
        tile[ty + i * 8][tx] = src[(size_t)(k0 + ty + i * 8) * N + n0 + tx];
    __syncthreads();
#pragma unroll
    for (int i = 0; i < 4; i++)
        dst[(size_t)(n0 + ty + i * 8) * K + k0 + tx] = f2bf(tile[tx][ty + i * 8]);
}

// ---------------- bf16 MFMA GEMM:  C[M,N] = A[M,K] * B[N,K]^T ----------------
// 128x128 tile, double-buffered LDS, stage-early single-barrier loop (T3-minimum).
// T2 bank-conflict fix under global_load_lds (rule #21: linear LDS dest + pre-swizzled
// global SOURCE + swizzled READ, same involution): 16B-slot index XORed with row bits 1-2.
//   stage: lane l loads global chunk (l&3)^((l>>3)&3) of row l>>2  -> LDS linear
//   read:  chunk q of row r lives at slot q^((r>>1)&3)
// Old pattern was 8-way bank conflict (rows stride 64B); now 2-way (free, m136).
// Bitwise-identical C. XCD-chunk swizzle on blockIdx (T1, bijective: nwg%8==0).
__global__ __launch_bounds__(256, 2) void k_gemm_bt(const unsigned short* __restrict__ A,
                                                    const unsigned short* __restrict__ B,
                                                    float* __restrict__ C, int K, int N) {
    __shared__ unsigned short lA[2][128 * 32];
    __shared__ unsigned short lB[2][128 * 32];
    int tid = threadIdx.x;
    int wave = tid >> 6, lane = tid & 63;
    // T1: chunked bijective XCD swizzle (gridDim.x == 16 for both launches)
    int nwg = gridDim.x * gridDim.y;
    int lid = blockIdx.y * gridDim.x + blockIdx.x;
    int swz = (lid & 7) * (nwg >> 3) + (lid >> 3);
    int m0 = (swz & 15) * 128, n0 = (swz >> 4) * 128;
    int wm = wave & 1, wn = wave >> 1;
    f4_t acc[4][4];
#pragma unroll
    for (int i = 0; i < 4; i++)
#pragma unroll
        for (int j = 0; j < 4; j++) acc[i][j] = (f4_t){0.f, 0.f, 0.f, 0.f};
    int srow = wave * 16 + (lane >> 2);
    int scol = ((lane & 3) ^ ((lane >> 3) & 3)) * 8;   // pre-swizzled source chunk
    int quad = lane >> 4, lrow = lane & 15;
    int rswz = (lrow >> 1) & 3;                        // read-side swizzle (row bits 1-2)

    const unsigned short* gA0 = A + (size_t)(m0 + srow) * K + scol;
    const unsigned short* gA1 = A + (size_t)(m0 + 64 + srow) * K + scol;
    const unsigned short* gB0 = B + (size_t)(n0 + srow) * K + scol;
    const unsigned short* gB1 = B + (size_t)(n0 + 64 + srow) * K + scol;

#define GEMM_STAGE(buf, k0)                                                                        \
    do {                                                                                           \
        __builtin_amdgcn_global_load_lds((const __attribute__((address_space(1))) void*)(gA0 + (k0)), \
            (__attribute__((address_space(3))) void*)(&lA[buf][wave * 512]), 16, 0, 0);            \
        __builtin_amdgcn_global_load_lds((const __attribute__((address_space(1))) void*)(gA1 + (k0)), \
            (__attribute__((address_space(3))) void*)(&lA[buf][2048 + wave * 512]), 16, 0, 0);     \
        __builtin_amdgcn_global_load_lds((const __attribute__((address_space(1))) void*)(gB0 + (k0)), \
            (__attribute__((address_space(3))) void*)(&lB[buf][wave * 512]), 16, 0, 0);            \
        __builtin_amdgcn_global_load_lds((const __attribute__((address_space(1))) void*)(gB1 + (k0)), \
            (__attribute__((address_space(3))) void*)(&lB[buf][2048 + wave * 512]), 16, 0, 0);     \
    } while (0)

    // prologue: stage tile 0, drain, barrier
    GEMM_STAGE(0, 0);
    __syncthreads();

    int cur = 0;
    for (int k0 = 0; k0 < K; k0 += 32) {
        if (k0 + 32 < K) GEMM_STAGE(cur ^ 1, k0 + 32);   // issue next-tile loads FIRST
        bf8_t af[4], bfv[4];
#pragma unroll
        for (int i = 0; i < 4; i++) {
            int sa = (quad ^ rswz) * 8;
            af[i]  = *(const bf8_t*)&lA[cur][(wm * 64 + i * 16 + lrow) * 32 + sa];
            bfv[i] = *(const bf8_t*)&lB[cur][(wn * 64 + i * 16 + lrow) * 32 + sa];
        }
#pragma unroll
        for (int i = 0; i < 4; i++)
#pragma unroll
            for (int j = 0; j < 4; j++)
                acc[i][j] = __builtin_amdgcn_mfma_f32_16x16x32_bf16(af[i], bfv[j], acc[i][j], 0, 0, 0);
        __syncthreads();   // drains vmcnt(0)+lgkmcnt(0): next buffer landed, cur fully read
        cur ^= 1;
    }
#undef GEMM_STAGE
#pragma unroll
    for (int i = 0; i < 4; i++) {
        int row_b = m0 + wm * 64 + i * 16 + quad * 4;
#pragma unroll
        for (int j = 0; j < 4; j++) {
            int col = n0 + wn * 64 + j * 16 + lrow;
#pragma unroll
            for (int r = 0; r < 4; r++)
                C[(size_t)(row_b + r) * N + col] = acc[i][j][r];
        }
    }
}

// ---------------- beta / raw log-decay g ----------------
// Skinny GEMM C[2048 tok][64] = hs @ [w_b|w_a], fp32 exact.
#define BG_TOK 4
__global__ __launch_bounds__(256) void k_beta_g(const float* __restrict__ hs,
                                                const float* __restrict__ w_b,
                                                const float* __restrict__ w_a,
                                                const float* __restrict__ dt_bias,
                                                const float* __restrict__ A_log,
                                                float* __restrict__ beta,
                                                float* __restrict__ gval) {
    __shared__ float rows[BG_TOK * HIDDEN];   // 32 KB
    __shared__ float part[BG_TOK][64][17];    // 17.4 KB, padded stride
    int t = threadIdx.x;
    int tok0 = blockIdx.x * BG_TOK;
    {
        const f4_t* src = (const f4_t*)(hs + (size_t)tok0 * HIDDEN);
        f4_t* dst = (f4_t*)rows;
#pragma unroll
        for (int u = 0; u < BG_TOK * HIDDEN / 4 / 256; u++)
            dst[t + u * 256] = src[t + u * 256];
    }
    __syncthreads();
    int hq = t & 15, kp = t >> 4;          // 16 h-quads x 16 k-partitions
    int h0 = hq * 4;
    const float* wsrc = (h0 < 32) ? (w_b + h0) : (w_a + (h0 - 32));
    f4_t acc[BG_TOK];
#pragma unroll
    for (int x = 0; x < BG_TOK; x++) acc[x] = (f4_t){0.f, 0.f, 0.f, 0.f};
    int kbase = kp * 128;
#pragma unroll 4
    for (int i = 0; i < 128; i++) {
        int k = kbase + i;
        f4_t wv = *(const f4_t*)(wsrc + (size_t)k * 32);
#pragma unroll
        for (int x = 0; x < BG_TOK; x++) {
            float r = rows[x * HIDDEN + k];
            acc[x][0] += wv[0] * r;
            acc[x][1] += wv[1] * r;
            acc[x][2] += wv[2] * r;
            acc[x][3] += wv[3] * r;
        }
    }
#pragma unroll
    for (int x = 0; x < BG_TOK; x++)
#pragma unroll
        for (int e = 0; e < 4; e++)
            part[x][h0 + e][kp] = acc[x][e];
    __syncthreads();
    int x = t >> 6, h = t & 63;
    float s = 0.f;
#pragma unroll
    for (int k2 = 0; k2 < 16; k2++) s += part[x][h][k2];
    int tok = tok0 + x;
    if (h < 32) {
        beta[tok * 32 + h] = 1.f / (1.f + expf(-s));
    } else {
        int hh = h - 32;
        float xx = s + dt_bias[hh];
        float sp = (xx > 20.f) ? xx : log1pf(expf(xx));
        gval[tok * 32 + hh] = -expf(A_log[hh]) * sp;   // log-decay (<= 0)
    }
}

// ---------------- conv halo + chunked in-place conv ----------------
#define CCH 32
#define NCHC (SEQ / CCH)
__global__ __launch_bounds__(256) void k_halo(const float* __restrict__ mixed,
                                              float* __restrict__ halo) {
    int id = blockIdx.x * 256 + threadIdx.x;
    int c = id & 8191;
    int r = id >> 13;
    int tap = r % 3;
    int ck = (r / 3) % (NCHC - 1);
    int b = r / (3 * (NCHC - 1));
    int s = (ck + 1) * CCH - 1 - tap;
    halo[id] = mixed[(size_t)(b * SEQ + s) * N1 + c];
}

__global__ __launch_bounds__(256) void k_conv(float* __restrict__ mixed,
                                              const float* __restrict__ cw,
                                              const float* __restrict__ halo) {
    int id = blockIdx.x * 256 + threadIdx.x;
    int c = id & 8191;
    int r = id >> 13;
    int chunk = r & (NCHC - 1), b = r >> 5;
    int s0 = chunk * CCH;
    float w0 = cw[c * 4 + 0], w1 = cw[c * 4 + 1], w2 = cw[c * 4 + 2], w3 = cw[c * 4 + 3];
    float xm1, xm2, xm3;
    if (chunk == 0) {
        xm1 = xm2 = xm3 = 0.f;
    } else {
        const float* hp = halo + (size_t)(b * (NCHC - 1) + chunk - 1) * 3 * 8192;
        xm1 = hp[0 * 8192 + c]; xm2 = hp[1 * 8192 + c]; xm3 = hp[2 * 8192 + c];
    }
    float* col = mixed + (size_t)(b * SEQ + s0) * N1 + c;
#pragma unroll
    for (int s = 0; s < CCH; s++) {
        float x = col[(size_t)s * N1];
        float y = w3 * x + w2 * xm1 + w1 * xm2 + w0 * xm3;
        y = y / (1.f + expf(-y));
        col[(size_t)s * N1] = y;
        xm3 = xm2; xm2 = xm1; xm1 = x;
    }
}

// ---------------- l2norm of q (with 1/sqrt(DK)) and k, in-place ----------------
__global__ __launch_bounds__(256) void k_l2norm(float* __restrict__ mixed) {
    int tok = blockIdx.x, t = threadIdx.x;
    int vec = t >> 3, ln = t & 7;
    int off = (vec < 16) ? vec * 128 : 2048 + (vec - 16) * 128;
    float* p = mixed + (size_t)tok * N1 + off + ln * 16;
    f4_t x0 = ((f4_t*)p)[0], x1 = ((f4_t*)p)[1], x2 = ((f4_t*)p)[2], x3 = ((f4_t*)p)[3];
    float ss = 0.f;
#pragma unroll
    for (int i = 0; i < 4; i++) ss += x0[i]*x0[i] + x1[i]*x1[i] + x2[i]*x2[i] + x3[i]*x3[i];
    ss += __shfl_xor(ss, 1); ss += __shfl_xor(ss, 2); ss += __shfl_xor(ss, 4);
    float sc = 1.f / sqrtf(ss + 1e-6f);
    if (vec < 16) sc *= 0.08838834764831845f;
#pragma unroll
    for (int i = 0; i < 4; i++) { x0[i]*=sc; x1[i]*=sc; x2[i]*=sc; x3[i]*=sc; }
    ((f4_t*)p)[0] = x0; ((f4_t*)p)[1] = x1; ((f4_t*)p)[2] = x2; ((f4_t*)p)[3] = x3;
}

// ---------------- chunk-local precompute + UT transform (parallel over b,h,c) ----------------
__global__ __launch_bounds__(256, 2) void k_prep(const float* __restrict__ mixed,
                                                 const float* __restrict__ beta,
                                                 const float* __restrict__ gval,
                                                 unsigned short* __restrict__ Pg,
                                                 unsigned short* __restrict__ KbTg,
                                                 unsigned short* __restrict__ Qbg,
                                                 unsigned short* __restrict__ Wg,
                                                 float* __restrict__ Ug,
                                                 float* __restrict__ Lamg) {
    __shared__ unsigned short lK[64 * 132];
    __shared__ unsigned short lQ[64 * 132];
    __shared__ float lM[64 * 66];
    __shared__ float lG[64], lLam[64], lBeta[64], lKsc[64];

    int blk = blockIdx.x;
    int c = blk & 15, h = (blk >> 4) & 31, b = blk >> 9;
    int hk = h >> 1;
    int t = threadIdx.x;
    int wave = t >> 6, lane = t & 63, half = lane >> 5, lm = lane & 31;
    int s0 = c * C_CH;

    const float* qptr = mixed + (size_t)(b * SEQ) * N1 + hk * 128;
    const float* kptr = qptr + 2048;

    // ---- stage K,Q + g/beta scan ----
    {
        int i = t >> 2, c0 = (t & 3) * 32;
        const float* kr = kptr + (size_t)(s0 + i) * N1 + c0;
        const float* qr = qptr + (size_t)(s0 + i) * N1 + c0;
        unsigned short* dK = &lK[i * 132 + c0];
        unsigned short* dQ = &lQ[i * 132 + c0];
#pragma unroll
        for (int u = 0; u < 8; u++) {
            f4_t kv = ((const f4_t*)kr)[u];
            f4_t qv = ((const f4_t*)qr)[u];
            u16x4 ks, qs;
#pragma unroll
            for (int e = 0; e < 4; e++) { ks[e] = f2bf(kv[e]); qs[e] = f2bf(qv[e]); }
            *(u16x4*)(dK + u * 4) = ks;
            *(u16x4*)(dQ + u * 4) = qs;
        }
        if (t < 64) {
            float gv = gval[(size_t)(b * SEQ + s0 + t) * 32 + h];
            float bv = beta[(size_t)(b * SEQ + s0 + t) * 32 + h];
            float x = gv;
#pragma unroll
            for (int d = 1; d < 64; d <<= 1) {
                float y = __shfl_up(x, d);
                if (t >= d) x += y;
            }
            float Gc = __shfl(x, 63);
            lG[t] = x; lLam[t] = expf(x); lBeta[t] = bv; lKsc[t] = expf(Gc - x);
        }
    }
    __syncthreads();

    size_t bhc = (size_t)(b * 32 + h) * 16 + c;
    size_t bkc = (size_t)(b * 16 + hk) * 16 + c;

    // ---- MFMA: M (3 tiles, ->LDS) + P (3 tiles, ->global) ----
    for (int job = wave; job < 6; job += 4) {
        int isP = job >= 3 ? 1 : 0;
        int jj = job - (isP ? 3 : 0);
        int ib = (jj == 0) ? 0 : 1;
        int jb = (jj == 2) ? 1 : 0;
        const unsigned short* Ab = isP ? lQ : lK;
        f16acc acc;
#pragma unroll
        for (int r = 0; r < 16; r++) acc[r] = 0.f;
        int arow = ib * 32 + lm, brow = jb * 32 + lm;
#pragma unroll
        for (int k0 = 0; k0 < 128; k0 += 16) {
            bf8_t a = lds_frag(&Ab[arow * 132 + k0 + half * 8]);
            bf8_t bb = lds_frag(&lK[brow * 132 + k0 + half * 8]);
            acc = __builtin_amdgcn_mfma_f32_32x32x16_bf16(a, bb, acc, 0, 0, 0);
        }
        int j = jb * 32 + lm;
        float Gj = lG[j];
#pragma unroll
        for (int r = 0; r < 16; r++) {
            int ml = (r & 3) + 8 * (r >> 2) + 4 * half;
            int i = ib * 32 + ml;
            float f = expf(lG[i] - Gj);
            if (isP) {
                Pg[bhc * 4096 + i * 64 + j] = f2bf((j <= i) ? acc[r] * f : 0.f);
            } else {
                if (j < i) lM[i * 66 + j] = acc[r] * lBeta[i] * f;
            }
        }
    }
    // zero P upper-right tile (rows 0..31, cols 32..63)
#pragma unroll
    for (int u = 0; u < 4; u++) {
        int e = t * 4 + u;
        Pg[bhc * 4096 + (e >> 5) * 64 + 32 + (e & 31)] = 0;
    }

    // ---- Q dump (shared per hk, only even-h blocks write) ----
    if ((h & 1) == 0) {
        int i = t >> 2, c0 = (t & 3) * 32;
#pragma unroll
        for (int u = 0; u < 8; u++)
            *(u16x4*)&Qbg[bkc * 8192 + i * 128 + c0 + u * 4] = *(const u16x4*)&lQ[i * 132 + c0 + u * 4];
    }

    // ---- KbarT[dk][i] ----
    {
        int dk = t >> 1, i0 = (t & 1) * 32;
        unsigned short tmp[32];
#pragma unroll
        for (int ii = 0; ii < 32; ii++) {
            int i = i0 + ii;
            tmp[ii] = f2bf(bf2f(lK[i * 132 + dk]) * lKsc[i]);
        }
#pragma unroll
        for (int u = 0; u < 4; u++) {
            u16x8 w;
#pragma unroll
            for (int j = 0; j < 8; j++) w[j] = tmp[u * 8 + j];
            *(u16x8*)&KbTg[bhc * 8192 + dk * 64 + i0 + u * 8] = w;
        }
    }
    if (t < 64) Lamg[bhc * 64 + t] = lLam[t];

    __syncthreads();   // lM fully populated

    // ---- UT transform: (I+M) X = [beta.*V | beta.*Lam.*K], one column/thread ----
    {
        float x[64];
        if (t < 128) {
            const float* vcol = mixed + (size_t)(b * SEQ + s0) * N1 + 4096 + h * 128 + t;
#pragma unroll
            for (int il = 0; il < 64; il++) x[il] = lBeta[il] * vcol[(size_t)il * N1];
        } else {
            int dk = t - 128;
#pragma unroll
            for (int il = 0; il < 64; il++) x[il] = lBeta[il] * lLam[il] * bf2f(lK[il * 132 + dk]);
        }
#pragma unroll
        for (int il = 1; il < 64; il++)
#pragma unroll
            for (int j = 0; j < il; j++)
                x[il] -= lM[il * 66 + j] * x[j];
        if (t < 128) {
            float* up = Ug + (size_t)(b * SEQ + s0) * 4096 + h * 128 + t;
#pragma unroll
            for (int il = 0; il < 64; il++) up[(size_t)il * 4096] = x[il];
        } else {
            unsigned short* wp = Wg + bhc * 8192 + (t - 128);
#pragma unroll
            for (int il = 0; il < 64; il++) wp[il * 128] = f2bf(-x[il]);
        }
    }
}

// ---------------- sequential state recurrence (pure MFMA) ----------------
__global__ __launch_bounds__(256, 1) void k_state(const unsigned short* __restrict__ Wg,
                                                  const unsigned short* __restrict__ Pg,
                                                  const unsigned short* __restrict__ KbTg,
                                                  const unsigned short* __restrict__ Qbg,
                                                  const float* __restrict__ Lamg,
                                                  float* __restrict__ o) {
    __shared__ unsigned short lSt[32 * 132];  // S^T bf16 [v][dk]
    __shared__ unsigned short lDt[32 * 68];   // Delta^T bf16 [v][i]

    int blk = blockIdx.x;
    int vs = blk & 3, h = (blk >> 2) & 31, b = blk >> 7;
    int hk = h >> 1;
    int t = threadIdx.x;
    int wave = t >> 6, lane = t & 63, half = lane >> 5, lm = lane & 31;
    int ib = wave & 1;

    for (int i = t; i < 32 * 132; i += 256) lSt[i] = 0;
    f16acc sacc;
#pragma unroll
    for (int r = 0; r < 16; r++) sacc[r] = 0.f;
    __syncthreads();

    for (int c = 0; c < NCHK; c++) {
        int s0 = c * C_CH;
        size_t bhc = (size_t)(b * 32 + h) * 16 + c;
        size_t bkc = (size_t)(b * 16 + hk) * 16 + c;

        // ---- fragment loads (L2-resident from k_prep) ----
        const unsigned short* Ag = (wave < 2) ? (Wg + bhc * 8192) : (Qbg + bkc * 8192);
        bf8_t afr[8];
#pragma unroll
        for (int kk = 0; kk < 8; kk++)
            afr[kk] = *(const bf8_t*)&Ag[(ib * 32 + lm) * 128 + kk * 16 + half * 8];
        bf8_t ktfr[4];
#pragma unroll
        for (int u = 0; u < 4; u++)
            ktfr[u] = *(const bf8_t*)&KbTg[bhc * 8192 + (wave * 32 + lm) * 64 + u * 16 + half * 8];
        bf8_t pfr[4];
        f4_t lamv[4];
        if (wave >= 2) {
#pragma unroll
            for (int u = 0; u < 4; u++)
                pfr[u] = *(const bf8_t*)&Pg[bhc * 4096 + (ib * 32 + lm) * 64 + u * 16 + half * 8];
#pragma unroll
            for (int q = 0; q < 4; q++)
                lamv[q] = *(const f4_t*)&Lamg[bhc * 64 + ib * 32 + q * 8 + half * 4];
        }
        float lamC = Lamg[bhc * 64 + 63];

        // ---- phase 1: Delta (waves 0,1, C-init = U) / Qacc (waves 2,3) ----
        f16acc wacc;
        if (wave < 2) {
            const float* up = o + (size_t)(b * SEQ + s0 + ib * 32) * 4096 + h * 128 + vs * 32 + lm;
#pragma unroll
            for (int r = 0; r < 16; r++) {
                int ml = (r & 3) + 8 * (r >> 2) + 4 * half;
                wacc[r] = up[(size_t)ml * 4096];
            }
        } else {
#pragma unroll
            for (int r = 0; r < 16; r++) wacc[r] = 0.f;
        }
#pragma unroll
        for (int kk = 0; kk < 8; kk++) {
            bf8_t bb = lds_frag(&lSt[lm * 132 + kk * 16 + half * 8]);
            wacc = __builtin_amdgcn_mfma_f32_32x32x16_bf16(afr[kk], bb, wacc, 0, 0, 0);
        }
        if (wave < 2) {
#pragma unroll
            for (int r = 0; r < 16; r++) {
                int ml = (r & 3) + 8 * (r >> 2) + 4 * half;
                lDt[lm * 68 + ib * 32 + ml] = f2bf(wacc[r]);
            }
        }
        __syncthreads();   // lDt ready; U reads + lSt reads done

        // ---- tail: O (waves 2,3); S update (all) ----
        if (wave >= 2) {
#pragma unroll
            for (int r = 0; r < 16; r++) wacc[r] *= lamv[r >> 2][r & 3];
#pragma unroll
            for (int u = 0; u < 4; u++) {
                bf8_t bb = lds_frag(&lDt[lm * 68 + u * 16 + half * 8]);
                wacc = __builtin_amdgcn_mfma_f32_32x32x16_bf16(pfr[u], bb, wacc, 0, 0, 0);
            }
#pragma unroll
            for (int r = 0; r < 16; r++) {
                int ml = (r & 3) + 8 * (r >> 2) + 4 * half;
                o[(size_t)(b * SEQ + s0 + ib * 32 + ml) * 4096 + h * 128 + vs * 32 + lm] = wacc[r];
            }
        }
#pragma unroll
        for (int r = 0; r < 16; r++) sacc[r] *= lamC;
#pragma unroll
        for (int u = 0; u < 4; u++) {
            bf8_t bb = lds_frag(&lDt[lm * 68 + u * 16 + half * 8]);
            sacc = __builtin_amdgcn_mfma_f32_32x32x16_bf16(ktfr[u], bb, sacc, 0, 0, 0);
        }
#pragma unroll
        for (int r = 0; r < 16; r++) {
            int ml = (r & 3) + 8 * (r >> 2) + 4 * half;
            lSt[lm * 132 + 32 * wave + ml] = f2bf(sacc[r]);
        }
        __syncthreads();
    }
}

// ---------------- gated RMSNorm -> bf16 ----------------
__global__ __launch_bounds__(256) void k_gnorm(const float* __restrict__ o,
                                               const float* __restrict__ mixed,
                                               const float* __restrict__ norm_w,
                                               unsigned short* __restrict__ on) {
    int tok = blockIdx.x, t = threadIdx.x;
    int hh = t >> 3, ln = t & 7;
    const f4_t* op = (const f4_t*)(o + (size_t)tok * 4096 + hh * 128 + ln * 16);
    const f4_t* zp = (const f4_t*)(mixed + (size_t)tok * N1 + 8192 + hh * 128 + ln * 16);
    float og[16];
    float ss = 0.f;
#pragma unroll
    for (int i = 0; i < 4; i++) {
        f4_t ov = op[i], zv = zp[i];
#pragma unroll
        for (int j = 0; j < 4; j++) {
            float z = zv[j];
            float g = ov[j] * (z / (1.f + expf(-z)));
            og[i * 4 + j] = g;
            ss += g * g;
        }
    }
    ss += __shfl_xor(ss, 1); ss += __shfl_xor(ss, 2); ss += __shfl_xor(ss, 4);
    float r = 1.f / sqrtf(ss * (1.f / 128.f) + 1e-6f);
    unsigned short* onp = on + (size_t)tok * 4096 + hh * 128 + ln * 16;
    u16x8 a, bb;
#pragma unroll
    for (int j = 0; j < 8; j++) a[j] = f2bf(og[j] * r * norm_w[ln * 16 + j]);
#pragma unroll
    for (int j = 0; j < 8; j++) bb[j] = f2bf(og[8 + j] * r * norm_w[ln * 16 + 8 + j]);
    ((u16x8*)onp)[0] = a;
    ((u16x8*)onp)[1] = bb;
}

extern "C" void kernel_launch(void* const* d_in, const int* in_sizes, int n_in,
                              void* d_out, int out_size, void* d_ws, size_t ws_size,
                              hipStream_t stream) {
    const float* hs      = (const float*)d_in[0];
    const float* conv_w  = (const float*)d_in[1];
    const float* w_qkv   = (const float*)d_in[2];
    const float* w_z     = (const float*)d_in[3];
    const float* w_b     = (const float*)d_in[4];
    const float* w_a     = (const float*)d_in[5];
    const float* w_out   = (const float*)d_in[6];
    const float* dt_bias = (const float*)d_in[7];
    const float* A_log   = (const float*)d_in[8];
    const float* norm_w  = (const float*)d_in[9];
    float* out = (float*)d_out;

    // Workspace layout is byte-identical to the 575 µs round-7 kernel (~222 MiB).
    char* ws = (char*)d_ws;
    unsigned short* hs_bf = (unsigned short*)ws; ws += (size_t)NTOK * HIDDEN * 2;     // 8 MiB
    unsigned short* w1t   = (unsigned short*)ws; ws += (size_t)N1 * HIDDEN * 2;       // 48 MiB
    unsigned short* wot   = (unsigned short*)ws; ws += (size_t)HIDDEN * VAL_DIM * 2;  // 16 MiB (live to end)
    float* mixed          = (float*)ws;          ws += (size_t)NTOK * N1 * 4;         // 96 MiB
    float* beta           = (float*)ws;          ws += (size_t)NTOK * 32 * 4;
    float* gval           = (float*)ws;          ws += (size_t)NTOK * 32 * 4;
    float* halo           = (float*)ws;          ws += (size_t)2 * (NCHC - 1) * 3 * 8192 * 4; // 5.8 MiB
    float* o_buf          = (float*)ws;          ws += (size_t)NTOK * VAL_DIM * 4;    // 32 MiB (U then O)
    unsigned short* on_bf = (unsigned short*)ws; ws += (size_t)NTOK * VAL_DIM * 2;

    // k_prep/k_state scratch ALIASED over buffers dead by that point:
    //   hs_bf + w1t (56 MiB, dead after first GEMM) holds Wg|Pg|KbTg|Qbg (48 MiB);
    //   halo (dead after k_conv) holds Lamg; U lives pre-O inside o_buf.
    char* al = (char*)hs_bf;
    unsigned short* Wg    = (unsigned short*)al; al += (size_t)1024 * 8192 * 2;  // 16 MiB
    unsigned short* Pg    = (unsigned short*)al; al += (size_t)1024 * 4096 * 2;  //  8 MiB
    unsigned short* KbTg  = (unsigned short*)al; al += (size_t)1024 * 8192 * 2;  // 16 MiB
    unsigned short* Qbg   = (unsigned short*)al; al += (size_t)512 * 8192 * 2;   //  8 MiB
    float* Lamg           = (float*)halo;

    k_cast_hs<<<dim3(NTOK * HIDDEN / 4 / 256), 256, 0, stream>>>(hs, hs_bf);
    k_trans_w1<<<dim3(N1 / 32, HIDDEN / 32), 256, 0, stream>>>(w_qkv, w_z, w1t);
    k_trans<<<dim3(HIDDEN / 32, VAL_DIM / 32), 256, 0, stream>>>(w_out, wot, VAL_DIM, HIDDEN);
    k_gemm_bt<<<dim3(NTOK / 128, N1 / 128), 256, 0, stream>>>(hs_bf, w1t, mixed, HIDDEN, N1);
    k_beta_g<<<dim3(NTOK / BG_TOK), 256, 0, stream>>>(hs, w_b, w_a, dt_bias, A_log, beta, gval);
    k_halo<<<dim3(2 * (NCHC - 1) * 3 * 8192 / 256), 256, 0, stream>>>(mixed, halo);
    k_conv<<<dim3(2 * NCHC * 8192 / 256), 256, 0, stream>>>(mixed, conv_w, halo);
    k_l2norm<<<dim3(NTOK), 256, 0, stream>>>(mixed);
    k_prep<<<dim3(1024), 256, 0, stream>>>(mixed, beta, gval, Pg, KbTg, Qbg, Wg, o_buf, Lamg);
    k_state<<<dim3(256), 256, 0, stream>>>(Wg, Pg, KbTg, Qbg, Lamg, o_buf);
    k_gnorm<<<dim3(NTOK), 256, 0, stream>>>(o_buf, mixed, norm_w, on_bf);
    k_gemm_bt<<<dim3(NTOK / 128, HIDDEN / 128), 256, 0, stream>>>(on_bf, wot, out, VAL_DIM, HIDDEN);
}

// Round 9
// 572.774 us; speedup vs baseline: 1.5995x; 1.0018x over previous
//
#include <hip/hip_runtime.h>
#include <hip/hip_bf16.h>
#include <cstdint>

#define HIDDEN   2048
#define HV       32
#define HK       16
#define DK       128
#define DV       128
#define KEY_DIM  2048
#define VAL_DIM  4096
#define CONV_DIM 8192
#define NTOK     2048   // B*S
#define SEQ      1024
#define N1       12288  // 2*KEY_DIM + VAL_DIM (qkv ++ z fused GEMM)
#define C_CH     64     // delta-rule chunk length
#define NCHK     (SEQ / C_CH)

typedef __attribute__((ext_vector_type(4))) float f4_t;
typedef __attribute__((ext_vector_type(2))) float f2_t;
typedef __attribute__((ext_vector_type(8))) short bf8_t;
typedef __attribute__((ext_vector_type(16))) float f16acc;
typedef __attribute__((ext_vector_type(4))) unsigned short u16x4;
typedef __attribute__((ext_vector_type(8))) unsigned short u16x8;
typedef __attribute__((ext_vector_type(2))) uint32_t u32x2;
typedef __attribute__((ext_vector_type(4))) uint32_t u32x4;

__device__ __forceinline__ unsigned short f2bf(float f) {
    union { float f; uint32_t u; } a; a.f = f;
    uint32_t u = a.u;
    return (unsigned short)((u + 0x7fff + ((u >> 16) & 1)) >> 16);
}
__device__ __forceinline__ float bf2f(unsigned short h) {
    uint32_t u = ((uint32_t)h) << 16;
    union { uint32_t u; float f; } a; a.u = u;
    return a.f;
}
// 16B LDS fragment via two 8B loads (rows are 8B-aligned, strides chosen 2-way-max banks)
__device__ __forceinline__ bf8_t lds_frag(const unsigned short* p) {
    u32x2 a = *(const u32x2*)p;
    u32x2 b = *(const u32x2*)(p + 4);
    u32x4 w = {a[0], a[1], b[0], b[1]};
    return __builtin_bit_cast(bf8_t, w);
}

// ---------------- cast hs -> bf16 ----------------
__global__ __launch_bounds__(256) void k_cast_hs(const float* __restrict__ hs,
                                                 unsigned short* __restrict__ out) {
    int i = blockIdx.x * 256 + threadIdx.x;
    f4_t v = ((const f4_t*)hs)[i];
    u16x4 o;
    o[0] = f2bf(v[0]); o[1] = f2bf(v[1]); o[2] = f2bf(v[2]); o[3] = f2bf(v[3]);
    ((u16x4*)out)[i] = o;
}

// ---------------- transpose+cast: W1t[n][k] = {w_qkv|w_z}[k][n] ----------------
__global__ __launch_bounds__(256) void k_trans_w1(const float* __restrict__ w_qkv,
                                                  const float* __restrict__ w_z,
                                                  unsigned short* __restrict__ w1t) {
    __shared__ float tile[32][33];
    int tx = threadIdx.x & 31, ty = threadIdx.x >> 5;
    int n0 = blockIdx.x * 32, k0 = blockIdx.y * 32;
    int n = n0 + tx;
#pragma unroll
    for (int i = 0; i < 4; i++) {
        int k = k0 + ty + i * 8;
        float v = (n < CONV_DIM) ? w_qkv[(size_t)k * CONV_DIM + n]
                                 : w_z[(size_t)k * VAL_DIM + (n - CONV_DIM)];
        tile[ty + i * 8][tx] = v;
    }
    __syncthreads();
#pragma unroll
    for (int i = 0; i < 4; i++)
        w1t[(size_t)(n0 + ty + i * 8) * HIDDEN + k0 + tx] = f2bf(tile[tx][ty + i * 8]);
}

__global__ __launch_bounds__(256) void k_trans(const float* __restrict__ src,
                                               unsigned short* __restrict__ dst,
                                               int K, int N) {
    __shared__ float tile[32][33];
    int tx = threadIdx.x & 31, ty = threadIdx.x >> 5;
    int n0 = blockIdx.x * 32, k0 = blockIdx.y * 32;
#pragma unroll
    for (int i = 0; i < 4; i++)
        tile[ty + i * 8][tx] = src[(size_t)(k0 + ty + i * 8) * N + n0 + tx];
    __syncthreads();
#pragma unroll
    for (int i = 0; i < 4; i++)
        dst[(size_t)(n0 + ty + i * 8) * K + k0 + tx] = f2bf(tile[tx][ty + i * 8]);
}

// ---------------- bf16 MFMA GEMM:  C[M,N] = A[M,K] * B[N,K]^T ----------------
// 128x128 tile, double-buffered LDS, stage-early single-barrier loop (T3-minimum).
// T2 swizzle (rule #21 both-sides involution) -> SQ_LDS_BANK_CONFLICT == 0 (r8).
// This round: __launch_bounds__(256, 4) -> 4 blocks/CU (LDS 4x32=128KB <= 160,
// VGPR cap 128 >> 56). m114 mechanism: co-resident blocks hide each other's
// barrier vmcnt-drain; m97's 874 TF ran ~3 blocks/CU with zero explicit pipelining.
// Bitwise-identical C. XCD-chunk swizzle on blockIdx (T1, bijective: nwg%8==0).
__global__ __launch_bounds__(256, 4) void k_gemm_bt(const unsigned short* __restrict__ A,
                                                    const unsigned short* __restrict__ B,
                                                    float* __restrict__ C, int K, int N) {
    __shared__ unsigned short lA[2][128 * 32];
    __shared__ unsigned short lB[2][128 * 32];
    int tid = threadIdx.x;
    int wave = tid >> 6, lane = tid & 63;
    // T1: chunked bijective XCD swizzle (gridDim.x == 16 for both launches)
    int nwg = gridDim.x * gridDim.y;
    int lid = blockIdx.y * gridDim.x + blockIdx.x;
    int swz = (lid & 7) * (nwg >> 3) + (lid >> 3);
    int m0 = (swz & 15) * 128, n0 = (swz >> 4) * 128;
    int wm = wave & 1, wn = wave >> 1;
    f4_t acc[4][4];
#pragma unroll
    for (int i = 0; i < 4; i++)
#pragma unroll
        for (int j = 0; j < 4; j++) acc[i][j] = (f4_t){0.f, 0.f, 0.f, 0.f};
    int srow = wave * 16 + (lane >> 2);
    int scol = ((lane & 3) ^ ((lane >> 3) & 3)) * 8;   // pre-swizzled source chunk
    int quad = lane >> 4, lrow = lane & 15;
    int rswz = (lrow >> 1) & 3;                        // read-side swizzle (row bits 1-2)

    const unsigned short* gA0 = A + (size_t)(m0 + srow) * K + scol;
    const unsigned short* gA1 = A + (size_t)(m0 + 64 + srow) * K + scol;
    const unsigned short* gB0 = B + (size_t)(n0 + srow) * K + scol;
    const unsigned short* gB1 = B + (size_t)(n0 + 64 + srow) * K + scol;

#define GEMM_STAGE(buf, k0)                                                                        \
    do {                                                                                           \
        __builtin_amdgcn_global_load_lds((const __attribute__((address_space(1))) void*)(gA0 + (k0)), \
            (__attribute__((address_space(3))) void*)(&lA[buf][wave * 512]), 16, 0, 0);            \
        __builtin_amdgcn_global_load_lds((const __attribute__((address_space(1))) void*)(gA1 + (k0)), \
            (__attribute__((address_space(3))) void*)(&lA[buf][2048 + wave * 512]), 16, 0, 0);     \
        __builtin_amdgcn_global_load_lds((const __attribute__((address_space(1))) void*)(gB0 + (k0)), \
            (__attribute__((address_space(3))) void*)(&lB[buf][wave * 512]), 16, 0, 0);            \
        __builtin_amdgcn_global_load_lds((const __attribute__((address_space(1))) void*)(gB1 + (k0)), \
            (__attribute__((address_space(3))) void*)(&lB[buf][2048 + wave * 512]), 16, 0, 0);     \
    } while (0)

    // prologue: stage tile 0, drain, barrier
    GEMM_STAGE(0, 0);
    __syncthreads();

    int cur = 0;
    for (int k0 = 0; k0 < K; k0 += 32) {
        if (k0 + 32 < K) GEMM_STAGE(cur ^ 1, k0 + 32);   // issue next-tile loads FIRST
        bf8_t af[4], bfv[4];
#pragma unroll
        for (int i = 0; i < 4; i++) {
            int sa = (quad ^ rswz) * 8;
            af[i]  = *(const bf8_t*)&lA[cur][(wm * 64 + i * 16 + lrow) * 32 + sa];
            bfv[i] = *(const bf8_t*)&lB[cur][(wn * 64 + i * 16 + lrow) * 32 + sa];
        }
#pragma unroll
        for (int i = 0; i < 4; i++)
#pragma unroll
            for (int j = 0; j < 4; j++)
                acc[i][j] = __builtin_amdgcn_mfma_f32_16x16x32_bf16(af[i], bfv[j], acc[i][j], 0, 0, 0);
        __syncthreads();   // drains vmcnt(0)+lgkmcnt(0): next buffer landed, cur fully read
        cur ^= 1;
    }
#undef GEMM_STAGE
#pragma unroll
    for (int i = 0; i < 4; i++) {
        int row_b = m0 + wm * 64 + i * 16 + quad * 4;
#pragma unroll
        for (int j = 0; j < 4; j++) {
            int col = n0 + wn * 64 + j * 16 + lrow;
#pragma unroll
            for (int r = 0; r < 4; r++)
                C[(size_t)(row_b + r) * N + col] = acc[i][j][r];
        }
    }
}

// ---------------- beta / raw log-decay g ----------------
// Skinny GEMM C[2048 tok][64] = hs @ [w_b|w_a], fp32 exact.
#define BG_TOK 4
__global__ __launch_bounds__(256) void k_beta_g(const float* __restrict__ hs,
                                                const float* __restrict__ w_b,
                                                const float* __restrict__ w_a,
                                                const float* __restrict__ dt_bias,
                                                const float* __restrict__ A_log,
                                                float* __restrict__ beta,
                                                float* __restrict__ gval) {
    __shared__ float rows[BG_TOK * HIDDEN];   // 32 KB
    __shared__ float part[BG_TOK][64][17];    // 17.4 KB, padded stride
    int t = threadIdx.x;
    int tok0 = blockIdx.x * BG_TOK;
    {
        const f4_t* src = (const f4_t*)(hs + (size_t)tok0 * HIDDEN);
        f4_t* dst = (f4_t*)rows;
#pragma unroll
        for (int u = 0; u < BG_TOK * HIDDEN / 4 / 256; u++)
            dst[t + u * 256] = src[t + u * 256];
    }
    __syncthreads();
    int hq = t & 15, kp = t >> 4;          // 16 h-quads x 16 k-partitions
    int h0 = hq * 4;
    const float* wsrc = (h0 < 32) ? (w_b + h0) : (w_a + (h0 - 32));
    f4_t acc[BG_TOK];
#pragma unroll
    for (int x = 0; x < BG_TOK; x++) acc[x] = (f4_t){0.f, 0.f, 0.f, 0.f};
    int kbase = kp * 128;
#pragma unroll 4
    for (int i = 0; i < 128; i++) {
        int k = kbase + i;
        f4_t wv = *(const f4_t*)(wsrc + (size_t)k * 32);
#pragma unroll
        for (int x = 0; x < BG_TOK; x++) {
            float r = rows[x * HIDDEN + k];
            acc[x][0] += wv[0] * r;
            acc[x][1] += wv[1] * r;
            acc[x][2] += wv[2] * r;
            acc[x][3] += wv[3] * r;
        }
    }
#pragma unroll
    for (int x = 0; x < BG_TOK; x++)
#pragma unroll
        for (int e = 0; e < 4; e++)
            part[x][h0 + e][kp] = acc[x][e];
    __syncthreads();
    int x = t >> 6, h = t & 63;
    float s = 0.f;
#pragma unroll
    for (int k2 = 0; k2 < 16; k2++) s += part[x][h][k2];
    int tok = tok0 + x;
    if (h < 32) {
        beta[tok * 32 + h] = 1.f / (1.f + expf(-s));
    } else {
        int hh = h - 32;
        float xx = s + dt_bias[hh];
        float sp = (xx > 20.f) ? xx : log1pf(expf(xx));
        gval[tok * 32 + hh] = -expf(A_log[hh]) * sp;   // log-decay (<= 0)
    }
}

// ---------------- conv halo + chunked in-place conv ----------------
#define CCH 32
#define NCHC (SEQ / CCH)
__global__ __launch_bounds__(256) void k_halo(const float* __restrict__ mixed,
                                              float* __restrict__ halo) {
    int id = blockIdx.x * 256 + threadIdx.x;
    int c = id & 8191;
    int r = id >> 13;
    int tap = r % 3;
    int ck = (r / 3) % (NCHC - 1);
    int b = r / (3 * (NCHC - 1));
    int s = (ck + 1) * CCH - 1 - tap;
    halo[id] = mixed[(size_t)(b * SEQ + s) * N1 + c];
}

__global__ __launch_bounds__(256) void k_conv(float* __restrict__ mixed,
                                              const float* __restrict__ cw,
                                              const float* __restrict__ halo) {
    int id = blockIdx.x * 256 + threadIdx.x;
    int c = id & 8191;
    int r = id >> 13;
    int chunk = r & (NCHC - 1), b = r >> 5;
    int s0 = chunk * CCH;
    float w0 = cw[c * 4 + 0], w1 = cw[c * 4 + 1], w2 = cw[c * 4 + 2], w3 = cw[c * 4 + 3];
    float xm1, xm2, xm3;
    if (chunk == 0) {
        xm1 = xm2 = xm3 = 0.f;
    } else {
        const float* hp = halo + (size_t)(b * (NCHC - 1) + chunk - 1) * 3 * 8192;
        xm1 = hp[0 * 8192 + c]; xm2 = hp[1 * 8192 + c]; xm3 = hp[2 * 8192 + c];
    }
    float* col = mixed + (size_t)(b * SEQ + s0) * N1 + c;
#pragma unroll
    for (int s = 0; s < CCH; s++) {
        float x = col[(size_t)s * N1];
        float y = w3 * x + w2 * xm1 + w1 * xm2 + w0 * xm3;
        y = y / (1.f + expf(-y));
        col[(size_t)s * N1] = y;
        xm3 = xm2; xm2 = xm1; xm1 = x;
    }
}

// ---------------- l2norm of q (with 1/sqrt(DK)) and k, in-place ----------------
__global__ __launch_bounds__(256) void k_l2norm(float* __restrict__ mixed) {
    int tok = blockIdx.x, t = threadIdx.x;
    int vec = t >> 3, ln = t & 7;
    int off = (vec < 16) ? vec * 128 : 2048 + (vec - 16) * 128;
    float* p = mixed + (size_t)tok * N1 + off + ln * 16;
    f4_t x0 = ((f4_t*)p)[0], x1 = ((f4_t*)p)[1], x2 = ((f4_t*)p)[2], x3 = ((f4_t*)p)[3];
    float ss = 0.f;
#pragma unroll
    for (int i = 0; i < 4; i++) ss += x0[i]*x0[i] + x1[i]*x1[i] + x2[i]*x2[i] + x3[i]*x3[i];
    ss += __shfl_xor(ss, 1); ss += __shfl_xor(ss, 2); ss += __shfl_xor(ss, 4);
    float sc = 1.f / sqrtf(ss + 1e-6f);
    if (vec < 16) sc *= 0.08838834764831845f;
#pragma unroll
    for (int i = 0; i < 4; i++) { x0[i]*=sc; x1[i]*=sc; x2[i]*=sc; x3[i]*=sc; }
    ((f4_t*)p)[0] = x0; ((f4_t*)p)[1] = x1; ((f4_t*)p)[2] = x2; ((f4_t*)p)[3] = x3;
}

// ---------------- chunk-local precompute + UT transform (parallel over b,h,c) ----------------
__global__ __launch_bounds__(256, 2) void k_prep(const float* __restrict__ mixed,
                                                 const float* __restrict__ beta,
                                                 const float* __restrict__ gval,
                                                 unsigned short* __restrict__ Pg,
                                                 unsigned short* __restrict__ KbTg,
                                                 unsigned short* __restrict__ Qbg,
                                                 unsigned short* __restrict__ Wg,
                                                 float* __restrict__ Ug,
                                                 float* __restrict__ Lamg) {
    __shared__ unsigned short lK[64 * 132];
    __shared__ unsigned short lQ[64 * 132];
    __shared__ float lM[64 * 66];
    __shared__ float lG[64], lLam[64], lBeta[64], lKsc[64];

    int blk = blockIdx.x;
    int c = blk & 15, h = (blk >> 4) & 31, b = blk >> 9;
    int hk = h >> 1;
    int t = threadIdx.x;
    int wave = t >> 6, lane = t & 63, half = lane >> 5, lm = lane & 31;
    int s0 = c * C_CH;

    const float* qptr = mixed + (size_t)(b * SEQ) * N1 + hk * 128;
    const float* kptr = qptr + 2048;

    // ---- stage K,Q + g/beta scan ----
    {
        int i = t >> 2, c0 = (t & 3) * 32;
        const float* kr = kptr + (size_t)(s0 + i) * N1 + c0;
        const float* qr = qptr + (size_t)(s0 + i) * N1 + c0;
        unsigned short* dK = &lK[i * 132 + c0];
        unsigned short* dQ = &lQ[i * 132 + c0];
#pragma unroll
        for (int u = 0; u < 8; u++) {
            f4_t kv = ((const f4_t*)kr)[u];
            f4_t qv = ((const f4_t*)qr)[u];
            u16x4 ks, qs;
#pragma unroll
            for (int e = 0; e < 4; e++) { ks[e] = f2bf(kv[e]); qs[e] = f2bf(qv[e]); }
            *(u16x4*)(dK + u * 4) = ks;
            *(u16x4*)(dQ + u * 4) = qs;
        }
        if (t < 64) {
            float gv = gval[(size_t)(b * SEQ + s0 + t) * 32 + h];
            float bv = beta[(size_t)(b * SEQ + s0 + t) * 32 + h];
            float x = gv;
#pragma unroll
            for (int d = 1; d < 64; d <<= 1) {
                float y = __shfl_up(x, d);
                if (t >= d) x += y;
            }
            float Gc = __shfl(x, 63);
            lG[t] = x; lLam[t] = expf(x); lBeta[t] = bv; lKsc[t] = expf(Gc - x);
        }
    }
    __syncthreads();

    size_t bhc = (size_t)(b * 32 + h) * 16 + c;
    size_t bkc = (size_t)(b * 16 + hk) * 16 + c;

    // ---- MFMA: M (3 tiles, ->LDS) + P (3 tiles, ->global) ----
    for (int job = wave; job < 6; job += 4) {
        int isP = job >= 3 ? 1 : 0;
        int jj = job - (isP ? 3 : 0);
        int ib = (jj == 0) ? 0 : 1;
        int jb = (jj == 2) ? 1 : 0;
        const unsigned short* Ab = isP ? lQ : lK;
        f16acc acc;
#pragma unroll
        for (int r = 0; r < 16; r++) acc[r] = 0.f;
        int arow = ib * 32 + lm, brow = jb * 32 + lm;
#pragma unroll
        for (int k0 = 0; k0 < 128; k0 += 16) {
            bf8_t a = lds_frag(&Ab[arow * 132 + k0 + half * 8]);
            bf8_t bb = lds_frag(&lK[brow * 132 + k0 + half * 8]);
            acc = __builtin_amdgcn_mfma_f32_32x32x16_bf16(a, bb, acc, 0, 0, 0);
        }
        int j = jb * 32 + lm;
        float Gj = lG[j];
#pragma unroll
        for (int r = 0; r < 16; r++) {
            int ml = (r & 3) + 8 * (r >> 2) + 4 * half;
            int i = ib * 32 + ml;
            float f = expf(lG[i] - Gj);
            if (isP) {
                Pg[bhc * 4096 + i * 64 + j] = f2bf((j <= i) ? acc[r] * f : 0.f);
            } else {
                if (j < i) lM[i * 66 + j] = acc[r] * lBeta[i] * f;
            }
        }
    }
    // zero P upper-right tile (rows 0..31, cols 32..63)
#pragma unroll
    for (int u = 0; u < 4; u++) {
        int e = t * 4 + u;
        Pg[bhc * 4096 + (e >> 5) * 64 + 32 + (e & 31)] = 0;
    }

    // ---- Q dump (shared per hk, only even-h blocks write) ----
    if ((h & 1) == 0) {
        int i = t >> 2, c0 = (t & 3) * 32;
#pragma unroll
        for (int u = 0; u < 8; u++)
            *(u16x4*)&Qbg[bkc * 8192 + i * 128 + c0 + u * 4] = *(const u16x4*)&lQ[i * 132 + c0 + u * 4];
    }

    // ---- KbarT[dk][i] ----
    {
        int dk = t >> 1, i0 = (t & 1) * 32;
        unsigned short tmp[32];
#pragma unroll
        for (int ii = 0; ii < 32; ii++) {
            int i = i0 + ii;
            tmp[ii] = f2bf(bf2f(lK[i * 132 + dk]) * lKsc[i]);
        }
#pragma unroll
        for (int u = 0; u < 4; u++) {
            u16x8 w;
#pragma unroll
            for (int j = 0; j < 8; j++) w[j] = tmp[u * 8 + j];
            *(u16x8*)&KbTg[bhc * 8192 + dk * 64 + i0 + u * 8] = w;
        }
    }
    if (t < 64) Lamg[bhc * 64 + t] = lLam[t];

    __syncthreads();   // lM fully populated

    // ---- UT transform: (I+M) X = [beta.*V | beta.*Lam.*K], one column/thread ----
    {
        float x[64];
        if (t < 128) {
            const float* vcol = mixed + (size_t)(b * SEQ + s0) * N1 + 4096 + h * 128 + t;
#pragma unroll
            for (int il = 0; il < 64; il++) x[il] = lBeta[il] * vcol[(size_t)il * N1];
        } else {
            int dk = t - 128;
#pragma unroll
            for (int il = 0; il < 64; il++) x[il] = lBeta[il] * lLam[il] * bf2f(lK[il * 132 + dk]);
        }
#pragma unroll
        for (int il = 1; il < 64; il++)
#pragma unroll
            for (int j = 0; j < il; j++)
                x[il] -= lM[il * 66 + j] * x[j];
        if (t < 128) {
            float* up = Ug + (size_t)(b * SEQ + s0) * 4096 + h * 128 + t;
#pragma unroll
            for (int il = 0; il < 64; il++) up[(size_t)il * 4096] = x[il];
        } else {
            unsigned short* wp = Wg + bhc * 8192 + (t - 128);
#pragma unroll
            for (int il = 0; il < 64; il++) wp[il * 128] = f2bf(-x[il]);
        }
    }
}

// ---------------- sequential state recurrence (pure MFMA) ----------------
__global__ __launch_bounds__(256, 1) void k_state(const unsigned short* __restrict__ Wg,
                                                  const unsigned short* __restrict__ Pg,
                                                  const unsigned short* __restrict__ KbTg,
                                                  const unsigned short* __restrict__ Qbg,
                                                  const float* __restrict__ Lamg,
                                                  float* __restrict__ o) {
    __shared__ unsigned short lSt[32 * 132];  // S^T bf16 [v][dk]
    __shared__ unsigned short lDt[32 * 68];   // Delta^T bf16 [v][i]

    int blk = blockIdx.x;
    int vs = blk & 3, h = (blk >> 2) & 31, b = blk >> 7;
    int hk = h >> 1;
    int t = threadIdx.x;
    int wave = t >> 6, lane = t & 63, half = lane >> 5, lm = lane & 31;
    int ib = wave & 1;

    for (int i = t; i < 32 * 132; i += 256) lSt[i] = 0;
    f16acc sacc;
#pragma unroll
    for (int r = 0; r < 16; r++) sacc[r] = 0.f;
    __syncthreads();

    for (int c = 0; c < NCHK; c++) {
        int s0 = c * C_CH;
        size_t bhc = (size_t)(b * 32 + h) * 16 + c;
        size_t bkc = (size_t)(b * 16 + hk) * 16 + c;

        // ---- fragment loads (L2-resident from k_prep) ----
        const unsigned short* Ag = (wave < 2) ? (Wg + bhc * 8192) : (Qbg + bkc * 8192);
        bf8_t afr[8];
#pragma unroll
        for (int kk = 0; kk < 8; kk++)
            afr[kk] = *(const bf8_t*)&Ag[(ib * 32 + lm) * 128 + kk * 16 + half * 8];
        bf8_t ktfr[4];
#pragma unroll
        for (int u = 0; u < 4; u++)
            ktfr[u] = *(const bf8_t*)&KbTg[bhc * 8192 + (wave * 32 + lm) * 64 + u * 16 + half * 8];
        bf8_t pfr[4];
        f4_t lamv[4];
        if (wave >= 2) {
#pragma unroll
            for (int u = 0; u < 4; u++)
                pfr[u] = *(const bf8_t*)&Pg[bhc * 4096 + (ib * 32 + lm) * 64 + u * 16 + half * 8];
#pragma unroll
            for (int q = 0; q < 4; q++)
                lamv[q] = *(const f4_t*)&Lamg[bhc * 64 + ib * 32 + q * 8 + half * 4];
        }
        float lamC = Lamg[bhc * 64 + 63];

        // ---- phase 1: Delta (waves 0,1, C-init = U) / Qacc (waves 2,3) ----
        f16acc wacc;
        if (wave < 2) {
            const float* up = o + (size_t)(b * SEQ + s0 + ib * 32) * 4096 + h * 128 + vs * 32 + lm;
#pragma unroll
            for (int r = 0; r < 16; r++) {
                int ml = (r & 3) + 8 * (r >> 2) + 4 * half;
                wacc[r] = up[(size_t)ml * 4096];
            }
        } else {
#pragma unroll
            for (int r = 0; r < 16; r++) wacc[r] = 0.f;
        }
#pragma unroll
        for (int kk = 0; kk < 8; kk++) {
            bf8_t bb = lds_frag(&lSt[lm * 132 + kk * 16 + half * 8]);
            wacc = __builtin_amdgcn_mfma_f32_32x32x16_bf16(afr[kk], bb, wacc, 0, 0, 0);
        }
        if (wave < 2) {
#pragma unroll
            for (int r = 0; r < 16; r++) {
                int ml = (r & 3) + 8 * (r >> 2) + 4 * half;
                lDt[lm * 68 + ib * 32 + ml] = f2bf(wacc[r]);
            }
        }
        __syncthreads();   // lDt ready; U reads + lSt reads done

        // ---- tail: O (waves 2,3); S update (all) ----
        if (wave >= 2) {
#pragma unroll
            for (int r = 0; r < 16; r++) wacc[r] *= lamv[r >> 2][r & 3];
#pragma unroll
            for (int u = 0; u < 4; u++) {
                bf8_t bb = lds_frag(&lDt[lm * 68 + u * 16 + half * 8]);
                wacc = __builtin_amdgcn_mfma_f32_32x32x16_bf16(pfr[u], bb, wacc, 0, 0, 0);
            }
#pragma unroll
            for (int r = 0; r < 16; r++) {
                int ml = (r & 3) + 8 * (r >> 2) + 4 * half;
                o[(size_t)(b * SEQ + s0 + ib * 32 + ml) * 4096 + h * 128 + vs * 32 + lm] = wacc[r];
            }
        }
#pragma unroll
        for (int r = 0; r < 16; r++) sacc[r] *= lamC;
#pragma unroll
        for (int u = 0; u < 4; u++) {
            bf8_t bb = lds_frag(&lDt[lm * 68 + u * 16 + half * 8]);
            sacc = __builtin_amdgcn_mfma_f32_32x32x16_bf16(ktfr[u], bb, sacc, 0, 0, 0);
        }
#pragma unroll
        for (int r = 0; r < 16; r++) {
            int ml = (r & 3) + 8 * (r >> 2) + 4 * half;
            lSt[lm * 132 + 32 * wave + ml] = f2bf(sacc[r]);
        }
        __syncthreads();
    }
}

// ---------------- gated RMSNorm -> bf16 ----------------
__global__ __launch_bounds__(256) void k_gnorm(const float* __restrict__ o,
                                               const float* __restrict__ mixed,
                                               const float* __restrict__ norm_w,
                                               unsigned short* __restrict__ on) {
    int tok = blockIdx.x, t = threadIdx.x;
    int hh = t >> 3, ln = t & 7;
    const f4_t* op = (const f4_t*)(o + (size_t)tok * 4096 + hh * 128 + ln * 16);
    const f4_t* zp = (const f4_t*)(mixed + (size_t)tok * N1 + 8192 + hh * 128 + ln * 16);
    float og[16];
    float ss = 0.f;
#pragma unroll
    for (int i = 0; i < 4; i++) {
        f4_t ov = op[i], zv = zp[i];
#pragma unroll
        for (int j = 0; j < 4; j++) {
            float z = zv[j];
            float g = ov[j] * (z / (1.f + expf(-z)));
            og[i * 4 + j] = g;
            ss += g * g;
        }
    }
    ss += __shfl_xor(ss, 1); ss += __shfl_xor(ss, 2); ss += __shfl_xor(ss, 4);
    float r = 1.f / sqrtf(ss * (1.f / 128.f) + 1e-6f);
    unsigned short* onp = on + (size_t)tok * 4096 + hh * 128 + ln * 16;
    u16x8 a, bb;
#pragma unroll
    for (int j = 0; j < 8; j++) a[j] = f2bf(og[j] * r * norm_w[ln * 16 + j]);
#pragma unroll
    for (int j = 0; j < 8; j++) bb[j] = f2bf(og[8 + j] * r * norm_w[ln * 16 + 8 + j]);
    ((u16x8*)onp)[0] = a;
    ((u16x8*)onp)[1] = bb;
}

extern "C" void kernel_launch(void* const* d_in, const int* in_sizes, int n_in,
                              void* d_out, int out_size, void* d_ws, size_t ws_size,
                              hipStream_t stream) {
    const float* hs      = (const float*)d_in[0];
    const float* conv_w  = (const float*)d_in[1];
    const float* w_qkv   = (const float*)d_in[2];
    const float* w_z     = (const float*)d_in[3];
    const float* w_b     = (const float*)d_in[4];
    const float* w_a     = (const float*)d_in[5];
    const float* w_out   = (const float*)d_in[6];
    const float* dt_bias = (const float*)d_in[7];
    const float* A_log   = (const float*)d_in[8];
    const float* norm_w  = (const float*)d_in[9];
    float* out = (float*)d_out;

    // Workspace layout is byte-identical to the 574 µs round-8 kernel (~222 MiB).
    char* ws = (char*)d_ws;
    unsigned short* hs_bf = (unsigned short*)ws; ws += (size_t)NTOK * HIDDEN * 2;     // 8 MiB
    unsigned short* w1t   = (unsigned short*)ws; ws += (size_t)N1 * HIDDEN * 2;       // 48 MiB
    unsigned short* wot   = (unsigned short*)ws; ws += (size_t)HIDDEN * VAL_DIM * 2;  // 16 MiB (live to end)
    float* mixed          = (float*)ws;          ws += (size_t)NTOK * N1 * 4;         // 96 MiB
    float* beta           = (float*)ws;          ws += (size_t)NTOK * 32 * 4;
    float* gval           = (float*)ws;          ws += (size_t)NTOK * 32 * 4;
    float* halo           = (float*)ws;          ws += (size_t)2 * (NCHC - 1) * 3 * 8192 * 4; // 5.8 MiB
    float* o_buf          = (float*)ws;          ws += (size_t)NTOK * VAL_DIM * 4;    // 32 MiB (U then O)
    unsigned short* on_bf = (unsigned short*)ws; ws += (size_t)NTOK * VAL_DIM * 2;

    // k_prep/k_state scratch ALIASED over buffers dead by that point:
    //   hs_bf + w1t (56 MiB, dead after first GEMM) holds Wg|Pg|KbTg|Qbg (48 MiB);
    //   halo (dead after k_conv) holds Lamg; U lives pre-O inside o_buf.
    char* al = (char*)hs_bf;
    unsigned short* Wg    = (unsigned short*)al; al += (size_t)1024 * 8192 * 2;  // 16 MiB
    unsigned short* Pg    = (unsigned short*)al; al += (size_t)1024 * 4096 * 2;  //  8 MiB
    unsigned short* KbTg  = (unsigned short*)al; al += (size_t)1024 * 8192 * 2;  // 16 MiB
    unsigned short* Qbg   = (unsigned short*)al; al += (size_t)512 * 8192 * 2;   //  8 MiB
    float* Lamg           = (float*)halo;

    k_cast_hs<<<dim3(NTOK * HIDDEN / 4 / 256), 256, 0, stream>>>(hs, hs_bf);
    k_trans_w1<<<dim3(N1 / 32, HIDDEN / 32), 256, 0, stream>>>(w_qkv, w_z, w1t);
    k_trans<<<dim3(HIDDEN / 32, VAL_DIM / 32), 256, 0, stream>>>(w_out, wot, VAL_DIM, HIDDEN);
    k_gemm_bt<<<dim3(NTOK / 128, N1 / 128), 256, 0, stream>>>(hs_bf, w1t, mixed, HIDDEN, N1);
    k_beta_g<<<dim3(NTOK / BG_TOK), 256, 0, stream>>>(hs, w_b, w_a, dt_bias, A_log, beta, gval);
    k_halo<<<dim3(2 * (NCHC - 1) * 3 * 8192 / 256), 256, 0, stream>>>(mixed, halo);
    k_conv<<<dim3(2 * NCHC * 8192 / 256), 256, 0, stream>>>(mixed, conv_w, halo);
    k_l2norm<<<dim3(NTOK), 256, 0, stream>>>(mixed);
    k_prep<<<dim3(1024), 256, 0, stream>>>(mixed, beta, gval, Pg, KbTg, Qbg, Wg, o_buf, Lamg);
    k_state<<<dim3(256), 256, 0, stream>>>(Wg, Pg, KbTg, Qbg, Lamg, o_buf);
    k_gnorm<<<dim3(NTOK), 256, 0, stream>>>(o_buf, mixed, norm_w, on_bf);
    k_gemm_bt<<<dim3(NTOK / 128, HIDDEN / 128), 256, 0, stream>>>(on_bf, wot, out, VAL_DIM, HIDDEN);
}

// Round 10
// 552.932 us; speedup vs baseline: 1.6569x; 1.0359x over previous
//
#include <hip/hip_runtime.h>
#include <hip/hip_bf16.h>
#include <cstdint>
#include <type_traits>

#define HIDDEN   2048
#define HV       32
#define HK       16
#define DK       128
#define DV       128
#define KEY_DIM  2048
#define VAL_DIM  4096
#define CONV_DIM 8192
#define NTOK     2048   // B*S
#define SEQ      1024
#define N1       12288  // 2*KEY_DIM + VAL_DIM (qkv ++ z fused GEMM)
#define C_CH     64     // delta-rule chunk length
#define NCHK     (SEQ / C_CH)

typedef __attribute__((ext_vector_type(4))) float f4_t;
typedef __attribute__((ext_vector_type(2))) float f2_t;
typedef __attribute__((ext_vector_type(8))) short bf8_t;
typedef __attribute__((ext_vector_type(16))) float f16acc;
typedef __attribute__((ext_vector_type(4))) unsigned short u16x4;
typedef __attribute__((ext_vector_type(8))) unsigned short u16x8;
typedef __attribute__((ext_vector_type(2))) uint32_t u32x2;
typedef __attribute__((ext_vector_type(4))) uint32_t u32x4;

__device__ __forceinline__ unsigned short f2bf(float f) {
    union { float f; uint32_t u; } a; a.f = f;
    uint32_t u = a.u;
    return (unsigned short)((u + 0x7fff + ((u >> 16) & 1)) >> 16);
}
__device__ __forceinline__ float bf2f(unsigned short h) {
    uint32_t u = ((uint32_t)h) << 16;
    union { uint32_t u; float f; } a; a.u = u;
    return a.f;
}
// 16B LDS fragment via two 8B loads (rows are 8B-aligned, strides chosen 2-way-max banks)
__device__ __forceinline__ bf8_t lds_frag(const unsigned short* p) {
    u32x2 a = *(const u32x2*)p;
    u32x2 b = *(const u32x2*)(p + 4);
    u32x4 w = {a[0], a[1], b[0], b[1]};
    return __builtin_bit_cast(bf8_t, w);
}

// ---------------- cast hs -> bf16 ----------------
__global__ __launch_bounds__(256) void k_cast_hs(const float* __restrict__ hs,
                                                 unsigned short* __restrict__ out) {
    int i = blockIdx.x * 256 + threadIdx.x;
    f4_t v = ((const f4_t*)hs)[i];
    u16x4 o;
    o[0] = f2bf(v[0]); o[1] = f2bf(v[1]); o[2] = f2bf(v[2]); o[3] = f2bf(v[3]);
    ((u16x4*)out)[i] = o;
}

// ---------------- transpose+cast: W1t[n][k] = {w_qkv|w_z}[k][n] ----------------
__global__ __launch_bounds__(256) void k_trans_w1(const float* __restrict__ w_qkv,
                                                  const float* __restrict__ w_z,
                                                  unsigned short* __restrict__ w1t) {
    __shared__ float tile[32][33];
    int tx = threadIdx.x & 31, ty = threadIdx.x >> 5;
    int n0 = blockIdx.x * 32, k0 = blockIdx.y * 32;
    int n = n0 + tx;
#pragma unroll
    for (int i = 0; i < 4; i++) {
        int k = k0 + ty + i * 8;
        float v = (n < CONV_DIM) ? w_qkv[(size_t)k * CONV_DIM + n]
                                 : w_z[(size_t)k * VAL_DIM + (n - CONV_DIM)];
        tile[ty + i * 8][tx] = v;
    }
    __syncthreads();
#pragma unroll
    for (int i = 0; i < 4; i++)
        w1t[(size_t)(n0 + ty + i * 8) * HIDDEN + k0 + tx] = f2bf(tile[tx][ty + i * 8]);
}

__global__ __launch_bounds__(256) void k_trans(const float* __restrict__ src,
                                               unsigned short* __restrict__ dst,
                                               int K, int N) {
    __shared__ float tile[32][33];
    int tx = threadIdx.x & 31, ty = threadIdx.x >> 5;
    int n0 = blockIdx.x * 32, k0 = blockIdx.y * 32;
#pragma unroll
    for (int i = 0; i < 4; i++)
        tile[ty + i * 8][tx] = src[(size_t)(k0 + ty + i * 8) * N + n0 + tx];
    __syncthreads();
#pragma unroll
    for (int i = 0; i < 4; i++)
        dst[(size_t)(n0 + ty + i * 8) * K + k0 + tx] = f2bf(tile[tx][ty + i * 8]);
}

// ---------------- bf16 MFMA GEMM:  C[M,N] = A[M,K] * B[N,K]^T ----------------
// 128x128 tile, double-buffered LDS, stage-early single-barrier loop; T2 swizzle
// (bank-conflict-free, r8: SQ_LDS_BANK_CONFLICT==0); T1 XCD chunk swizzle.
// Output type templated: fp32 (out-proj) or bf16 (qkv -> mixed, halves C-write traffic).
template <typename OT>
__global__ __launch_bounds__(256, 4) void k_gemm_bt(const unsigned short* __restrict__ A,
                                                    const unsigned short* __restrict__ B,
                                                    OT* __restrict__ C, int K, int N) {
    __shared__ unsigned short lA[2][128 * 32];
    __shared__ unsigned short lB[2][128 * 32];
    int tid = threadIdx.x;
    int wave = tid >> 6, lane = tid & 63;
    int nwg = gridDim.x * gridDim.y;
    int lid = blockIdx.y * gridDim.x + blockIdx.x;
    int swz = (lid & 7) * (nwg >> 3) + (lid >> 3);
    int m0 = (swz & 15) * 128, n0 = (swz >> 4) * 128;
    int wm = wave & 1, wn = wave >> 1;
    f4_t acc[4][4];
#pragma unroll
    for (int i = 0; i < 4; i++)
#pragma unroll
        for (int j = 0; j < 4; j++) acc[i][j] = (f4_t){0.f, 0.f, 0.f, 0.f};
    int srow = wave * 16 + (lane >> 2);
    int scol = ((lane & 3) ^ ((lane >> 3) & 3)) * 8;   // pre-swizzled source chunk
    int quad = lane >> 4, lrow = lane & 15;
    int rswz = (lrow >> 1) & 3;                        // read-side swizzle (row bits 1-2)

    const unsigned short* gA0 = A + (size_t)(m0 + srow) * K + scol;
    const unsigned short* gA1 = A + (size_t)(m0 + 64 + srow) * K + scol;
    const unsigned short* gB0 = B + (size_t)(n0 + srow) * K + scol;
    const unsigned short* gB1 = B + (size_t)(n0 + 64 + srow) * K + scol;

#define GEMM_STAGE(buf, k0)                                                                        \
    do {                                                                                           \
        __builtin_amdgcn_global_load_lds((const __attribute__((address_space(1))) void*)(gA0 + (k0)), \
            (__attribute__((address_space(3))) void*)(&lA[buf][wave * 512]), 16, 0, 0);            \
        __builtin_amdgcn_global_load_lds((const __attribute__((address_space(1))) void*)(gA1 + (k0)), \
            (__attribute__((address_space(3))) void*)(&lA[buf][2048 + wave * 512]), 16, 0, 0);     \
        __builtin_amdgcn_global_load_lds((const __attribute__((address_space(1))) void*)(gB0 + (k0)), \
            (__attribute__((address_space(3))) void*)(&lB[buf][wave * 512]), 16, 0, 0);            \
        __builtin_amdgcn_global_load_lds((const __attribute__((address_space(1))) void*)(gB1 + (k0)), \
            (__attribute__((address_space(3))) void*)(&lB[buf][2048 + wave * 512]), 16, 0, 0);     \
    } while (0)

    GEMM_STAGE(0, 0);
    __syncthreads();

    int cur = 0;
    for (int k0 = 0; k0 < K; k0 += 32) {
        if (k0 + 32 < K) GEMM_STAGE(cur ^ 1, k0 + 32);   // issue next-tile loads FIRST
        bf8_t af[4], bfv[4];
#pragma unroll
        for (int i = 0; i < 4; i++) {
            int sa = (quad ^ rswz) * 8;
            af[i]  = *(const bf8_t*)&lA[cur][(wm * 64 + i * 16 + lrow) * 32 + sa];
            bfv[i] = *(const bf8_t*)&lB[cur][(wn * 64 + i * 16 + lrow) * 32 + sa];
        }
#pragma unroll
        for (int i = 0; i < 4; i++)
#pragma unroll
            for (int j = 0; j < 4; j++)
                acc[i][j] = __builtin_amdgcn_mfma_f32_16x16x32_bf16(af[i], bfv[j], acc[i][j], 0, 0, 0);
        __syncthreads();   // drains vmcnt(0)+lgkmcnt(0): next buffer landed, cur fully read
        cur ^= 1;
    }
#undef GEMM_STAGE
#pragma unroll
    for (int i = 0; i < 4; i++) {
        int row_b = m0 + wm * 64 + i * 16 + quad * 4;
#pragma unroll
        for (int j = 0; j < 4; j++) {
            int col = n0 + wn * 64 + j * 16 + lrow;
#pragma unroll
            for (int r = 0; r < 4; r++) {
                if constexpr (std::is_same<OT, float>::value)
                    C[(size_t)(row_b + r) * N + col] = acc[i][j][r];
                else
                    C[(size_t)(row_b + r) * N + col] = f2bf(acc[i][j][r]);
            }
        }
    }
}

// ---------------- beta / raw log-decay g (reads hs fp32, unchanged) ----------------
#define BG_TOK 4
__global__ __launch_bounds__(256) void k_beta_g(const float* __restrict__ hs,
                                                const float* __restrict__ w_b,
                                                const float* __restrict__ w_a,
                                                const float* __restrict__ dt_bias,
                                                const float* __restrict__ A_log,
                                                float* __restrict__ beta,
                                                float* __restrict__ gval) {
    __shared__ float rows[BG_TOK * HIDDEN];   // 32 KB
    __shared__ float part[BG_TOK][64][17];    // 17.4 KB, padded stride
    int t = threadIdx.x;
    int tok0 = blockIdx.x * BG_TOK;
    {
        const f4_t* src = (const f4_t*)(hs + (size_t)tok0 * HIDDEN);
        f4_t* dst = (f4_t*)rows;
#pragma unroll
        for (int u = 0; u < BG_TOK * HIDDEN / 4 / 256; u++)
            dst[t + u * 256] = src[t + u * 256];
    }
    __syncthreads();
    int hq = t & 15, kp = t >> 4;
    int h0 = hq * 4;
    const float* wsrc = (h0 < 32) ? (w_b + h0) : (w_a + (h0 - 32));
    f4_t acc[BG_TOK];
#pragma unroll
    for (int x = 0; x < BG_TOK; x++) acc[x] = (f4_t){0.f, 0.f, 0.f, 0.f};
    int kbase = kp * 128;
#pragma unroll 4
    for (int i = 0; i < 128; i++) {
        int k = kbase + i;
        f4_t wv = *(const f4_t*)(wsrc + (size_t)k * 32);
#pragma unroll
        for (int x = 0; x < BG_TOK; x++) {
            float r = rows[x * HIDDEN + k];
            acc[x][0] += wv[0] * r;
            acc[x][1] += wv[1] * r;
            acc[x][2] += wv[2] * r;
            acc[x][3] += wv[3] * r;
        }
    }
#pragma unroll
    for (int x = 0; x < BG_TOK; x++)
#pragma unroll
        for (int e = 0; e < 4; e++)
            part[x][h0 + e][kp] = acc[x][e];
    __syncthreads();
    int x = t >> 6, h = t & 63;
    float s = 0.f;
#pragma unroll
    for (int k2 = 0; k2 < 16; k2++) s += part[x][h][k2];
    int tok = tok0 + x;
    if (h < 32) {
        beta[tok * 32 + h] = 1.f / (1.f + expf(-s));
    } else {
        int hh = h - 32;
        float xx = s + dt_bias[hh];
        float sp = (xx > 20.f) ? xx : log1pf(expf(xx));
        gval[tok * 32 + hh] = -expf(A_log[hh]) * sp;   // log-decay (<= 0)
    }
}

// ---------------- conv halo + chunked in-place conv (bf16 mixed) ----------------
#define CCH 32
#define NCHC (SEQ / CCH)
__global__ __launch_bounds__(256) void k_halo(const unsigned short* __restrict__ mixed,
                                              unsigned short* __restrict__ halo) {
    int id = blockIdx.x * 256 + threadIdx.x;
    int c = id & 8191;
    int r = id >> 13;
    int tap = r % 3;
    int ck = (r / 3) % (NCHC - 1);
    int b = r / (3 * (NCHC - 1));
    int s = (ck + 1) * CCH - 1 - tap;
    halo[id] = mixed[(size_t)(b * SEQ + s) * N1 + c];
}

// q/k channels (c<4096): write silu(conv) back to mixed as bf16.
// v channels (c>=4096): write silu(conv) fp32 to vbuf (V path keeps fp32 into UT solve).
__global__ __launch_bounds__(256) void k_conv(unsigned short* __restrict__ mixed,
                                              const float* __restrict__ cw,
                                              const unsigned short* __restrict__ halo,
                                              float* __restrict__ vbuf) {
    int id = blockIdx.x * 256 + threadIdx.x;
    int c = id & 8191;
    int r = id >> 13;
    int chunk = r & (NCHC - 1), b = r >> 5;
    int s0 = chunk * CCH;
    float w0 = cw[c * 4 + 0], w1 = cw[c * 4 + 1], w2 = cw[c * 4 + 2], w3 = cw[c * 4 + 3];
    float xm1, xm2, xm3;
    if (chunk == 0) {
        xm1 = xm2 = xm3 = 0.f;
    } else {
        const unsigned short* hp = halo + (size_t)(b * (NCHC - 1) + chunk - 1) * 3 * 8192;
        xm1 = bf2f(hp[0 * 8192 + c]); xm2 = bf2f(hp[1 * 8192 + c]); xm3 = bf2f(hp[2 * 8192 + c]);
    }
    unsigned short* col = mixed + (size_t)(b * SEQ + s0) * N1 + c;
    float* vcol = vbuf + (size_t)(b * SEQ + s0) * 4096 + (c - 4096);
#pragma unroll
    for (int s = 0; s < CCH; s++) {
        float x = bf2f(col[(size_t)s * N1]);
        float y = w3 * x + w2 * xm1 + w1 * xm2 + w0 * xm3;
        y = y / (1.f + expf(-y));
        if (c < 4096) col[(size_t)s * N1] = f2bf(y);
        else          vcol[(size_t)s * 4096] = y;
        xm3 = xm2; xm2 = xm1; xm1 = x;
    }
}

// ---------------- chunk-local precompute + fused l2norm + UT transform ----------------
// l2norm of q (with 1/sqrt(DK)) and k now fused into the staging: each block stages
// full 128-dim q/k rows; quad-level shfl_xor gives the row sum-of-squares (eps 1e-6,
// same as the deleted k_l2norm). Scaled values round to bf16 exactly where they did before.
__global__ __launch_bounds__(256, 2) void k_prep(const unsigned short* __restrict__ mixed,
                                                 const float* __restrict__ vbuf,
                                                 const float* __restrict__ beta,
                                                 const float* __restrict__ gval,
                                                 unsigned short* __restrict__ Pg,
                                                 unsigned short* __restrict__ KbTg,
                                                 unsigned short* __restrict__ Qbg,
                                                 unsigned short* __restrict__ Wg,
                                                 float* __restrict__ Ug,
                                                 float* __restrict__ Lamg) {
    __shared__ unsigned short lK[64 * 132];
    __shared__ unsigned short lQ[64 * 132];
    __shared__ float lM[64 * 66];
    __shared__ float lG[64], lLam[64], lBeta[64], lKsc[64];

    int blk = blockIdx.x;
    int c = blk & 15, h = (blk >> 4) & 31, b = blk >> 9;
    int hk = h >> 1;
    int t = threadIdx.x;
    int wave = t >> 6, lane = t & 63, half = lane >> 5, lm = lane & 31;
    int s0 = c * C_CH;

    const unsigned short* qptr = mixed + (size_t)(b * SEQ) * N1 + hk * 128;
    const unsigned short* kptr = qptr + 2048;

    // ---- stage K,Q (bf16 in) + fused l2norm + g/beta scan ----
    {
        int i = t >> 2, c0 = (t & 3) * 32;
        // K first (halve live registers), then Q
        {
            const unsigned short* kr = kptr + (size_t)(s0 + i) * N1 + c0;
            float kv[32];
            float ssk = 0.f;
#pragma unroll
            for (int u = 0; u < 4; u++) {
                u16x8 w = *(const u16x8*)(kr + u * 8);
#pragma unroll
                for (int e = 0; e < 8; e++) { float f = bf2f(w[e]); kv[u * 8 + e] = f; ssk += f * f; }
            }
            ssk += __shfl_xor(ssk, 1); ssk += __shfl_xor(ssk, 2);
            float sck = 1.f / sqrtf(ssk + 1e-6f);
            unsigned short* dK = &lK[i * 132 + c0];
#pragma unroll
            for (int u = 0; u < 8; u++) {
                u16x4 s4;
#pragma unroll
                for (int e = 0; e < 4; e++) s4[e] = f2bf(kv[u * 4 + e] * sck);
                *(u16x4*)(dK + u * 4) = s4;
            }
        }
        {
            const unsigned short* qr = qptr + (size_t)(s0 + i) * N1 + c0;
            float qv[32];
            float ssq = 0.f;
#pragma unroll
            for (int u = 0; u < 4; u++) {
                u16x8 w = *(const u16x8*)(qr + u * 8);
#pragma unroll
                for (int e = 0; e < 8; e++) { float f = bf2f(w[e]); qv[u * 8 + e] = f; ssq += f * f; }
            }
            ssq += __shfl_xor(ssq, 1); ssq += __shfl_xor(ssq, 2);
            float scq = (1.f / sqrtf(ssq + 1e-6f)) * 0.08838834764831845f;
            unsigned short* dQ = &lQ[i * 132 + c0];
#pragma unroll
            for (int u = 0; u < 8; u++) {
                u16x4 s4;
#pragma unroll
                for (int e = 0; e < 4; e++) s4[e] = f2bf(qv[u * 4 + e] * scq);
                *(u16x4*)(dQ + u * 4) = s4;
            }
        }
        if (t < 64) {
            float gv = gval[(size_t)(b * SEQ + s0 + t) * 32 + h];
            float bv = beta[(size_t)(b * SEQ + s0 + t) * 32 + h];
            float x = gv;
#pragma unroll
            for (int d = 1; d < 64; d <<= 1) {
                float y = __shfl_up(x, d);
                if (t >= d) x += y;
            }
            float Gc = __shfl(x, 63);
            lG[t] = x; lLam[t] = expf(x); lBeta[t] = bv; lKsc[t] = expf(Gc - x);
        }
    }
    __syncthreads();

    size_t bhc = (size_t)(b * 32 + h) * 16 + c;
    size_t bkc = (size_t)(b * 16 + hk) * 16 + c;

    // ---- MFMA: M (3 tiles, ->LDS) + P (3 tiles, ->global) ----
    for (int job = wave; job < 6; job += 4) {
        int isP = job >= 3 ? 1 : 0;
        int jj = job - (isP ? 3 : 0);
        int ib = (jj == 0) ? 0 : 1;
        int jb = (jj == 2) ? 1 : 0;
        const unsigned short* Ab = isP ? lQ : lK;
        f16acc acc;
#pragma unroll
        for (int r = 0; r < 16; r++) acc[r] = 0.f;
        int arow = ib * 32 + lm, brow = jb * 32 + lm;
#pragma unroll
        for (int k0 = 0; k0 < 128; k0 += 16) {
            bf8_t a = lds_frag(&Ab[arow * 132 + k0 + half * 8]);
            bf8_t bb = lds_frag(&lK[brow * 132 + k0 + half * 8]);
            acc = __builtin_amdgcn_mfma_f32_32x32x16_bf16(a, bb, acc, 0, 0, 0);
        }
        int j = jb * 32 + lm;
        float Gj = lG[j];
#pragma unroll
        for (int r = 0; r < 16; r++) {
            int ml = (r & 3) + 8 * (r >> 2) + 4 * half;
            int i = ib * 32 + ml;
            float f = expf(lG[i] - Gj);
            if (isP) {
                Pg[bhc * 4096 + i * 64 + j] = f2bf((j <= i) ? acc[r] * f : 0.f);
            } else {
                if (j < i) lM[i * 66 + j] = acc[r] * lBeta[i] * f;
            }
        }
    }
    // zero P upper-right tile (rows 0..31, cols 32..63)
#pragma unroll
    for (int u = 0; u < 4; u++) {
        int e = t * 4 + u;
        Pg[bhc * 4096 + (e >> 5) * 64 + 32 + (e & 31)] = 0;
    }

    // ---- Q dump (shared per hk, only even-h blocks write) ----
    if ((h & 1) == 0) {
        int i = t >> 2, c0 = (t & 3) * 32;
#pragma unroll
        for (int u = 0; u < 8; u++)
            *(u16x4*)&Qbg[bkc * 8192 + i * 128 + c0 + u * 4] = *(const u16x4*)&lQ[i * 132 + c0 + u * 4];
    }

    // ---- KbarT[dk][i] ----
    {
        int dk = t >> 1, i0 = (t & 1) * 32;
        unsigned short tmp[32];
#pragma unroll
        for (int ii = 0; ii < 32; ii++) {
            int i = i0 + ii;
            tmp[ii] = f2bf(bf2f(lK[i * 132 + dk]) * lKsc[i]);
        }
#pragma unroll
        for (int u = 0; u < 4; u++) {
            u16x8 w;
#pragma unroll
            for (int j = 0; j < 8; j++) w[j] = tmp[u * 8 + j];
            *(u16x8*)&KbTg[bhc * 8192 + dk * 64 + i0 + u * 8] = w;
        }
    }
    if (t < 64) Lamg[bhc * 64 + t] = lLam[t];

    __syncthreads();   // lM fully populated

    // ---- UT transform: (I+M) X = [beta.*V | beta.*Lam.*K], one column/thread ----
    {
        float x[64];
        if (t < 128) {
            const float* vcol = vbuf + (size_t)(b * SEQ + s0) * 4096 + h * 128 + t;
#pragma unroll
            for (int il = 0; il < 64; il++) x[il] = lBeta[il] * vcol[(size_t)il * 4096];
        } else {
            int dk = t - 128;
#pragma unroll
            for (int il = 0; il < 64; il++) x[il] = lBeta[il] * lLam[il] * bf2f(lK[il * 132 + dk]);
        }
#pragma unroll
        for (int il = 1; il < 64; il++)
#pragma unroll
            for (int j = 0; j < il; j++)
                x[il] -= lM[il * 66 + j] * x[j];
        if (t < 128) {
            float* up = Ug + (size_t)(b * SEQ + s0) * 4096 + h * 128 + t;
#pragma unroll
            for (int il = 0; il < 64; il++) up[(size_t)il * 4096] = x[il];
        } else {
            unsigned short* wp = Wg + bhc * 8192 + (t - 128);
#pragma unroll
            for (int il = 0; il < 64; il++) wp[il * 128] = f2bf(-x[il]);
        }
    }
}

// ---------------- sequential state recurrence (pure MFMA, unchanged) ----------------
__global__ __launch_bounds__(256, 1) void k_state(const unsigned short* __restrict__ Wg,
                                                  const unsigned short* __restrict__ Pg,
                                                  const unsigned short* __restrict__ KbTg,
                                                  const unsigned short* __restrict__ Qbg,
                                                  const float* __restrict__ Lamg,
                                                  float* __restrict__ o) {
    __shared__ unsigned short lSt[32 * 132];  // S^T bf16 [v][dk]
    __shared__ unsigned short lDt[32 * 68];   // Delta^T bf16 [v][i]

    int blk = blockIdx.x;
    int vs = blk & 3, h = (blk >> 2) & 31, b = blk >> 7;
    int hk = h >> 1;
    int t = threadIdx.x;
    int wave = t >> 6, lane = t & 63, half = lane >> 5, lm = lane & 31;
    int ib = wave & 1;

    for (int i = t; i < 32 * 132; i += 256) lSt[i] = 0;
    f16acc sacc;
#pragma unroll
    for (int r = 0; r < 16; r++) sacc[r] = 0.f;
    __syncthreads();

    for (int c = 0; c < NCHK; c++) {
        int s0 = c * C_CH;
        size_t bhc = (size_t)(b * 32 + h) * 16 + c;
        size_t bkc = (size_t)(b * 16 + hk) * 16 + c;

        // ---- fragment loads (L2-resident from k_prep) ----
        const unsigned short* Ag = (wave < 2) ? (Wg + bhc * 8192) : (Qbg + bkc * 8192);
        bf8_t afr[8];
#pragma unroll
        for (int kk = 0; kk < 8; kk++)
            afr[kk] = *(const bf8_t*)&Ag[(ib * 32 + lm) * 128 + kk * 16 + half * 8];
        bf8_t ktfr[4];
#pragma unroll
        for (int u = 0; u < 4; u++)
            ktfr[u] = *(const bf8_t*)&KbTg[bhc * 8192 + (wave * 32 + lm) * 64 + u * 16 + half * 8];
        bf8_t pfr[4];
        f4_t lamv[4];
        if (wave >= 2) {
#pragma unroll
            for (int u = 0; u < 4; u++)
                pfr[u] = *(const bf8_t*)&Pg[bhc * 4096 + (ib * 32 + lm) * 64 + u * 16 + half * 8];
#pragma unroll
            for (int q = 0; q < 4; q++)
                lamv[q] = *(const f4_t*)&Lamg[bhc * 64 + ib * 32 + q * 8 + half * 4];
        }
        float lamC = Lamg[bhc * 64 + 63];

        // ---- phase 1: Delta (waves 0,1, C-init = U) / Qacc (waves 2,3) ----
        f16acc wacc;
        if (wave < 2) {
            const float* up = o + (size_t)(b * SEQ + s0 + ib * 32) * 4096 + h * 128 + vs * 32 + lm;
#pragma unroll
            for (int r = 0; r < 16; r++) {
                int ml = (r & 3) + 8 * (r >> 2) + 4 * half;
                wacc[r] = up[(size_t)ml * 4096];
            }
        } else {
#pragma unroll
            for (int r = 0; r < 16; r++) wacc[r] = 0.f;
        }
#pragma unroll
        for (int kk = 0; kk < 8; kk++) {
            bf8_t bb = lds_frag(&lSt[lm * 132 + kk * 16 + half * 8]);
            wacc = __builtin_amdgcn_mfma_f32_32x32x16_bf16(afr[kk], bb, wacc, 0, 0, 0);
        }
        if (wave < 2) {
#pragma unroll
            for (int r = 0; r < 16; r++) {
                int ml = (r & 3) + 8 * (r >> 2) + 4 * half;
                lDt[lm * 68 + ib * 32 + ml] = f2bf(wacc[r]);
            }
        }
        __syncthreads();   // lDt ready; U reads + lSt reads done

        // ---- tail: O (waves 2,3); S update (all) ----
        if (wave >= 2) {
#pragma unroll
            for (int r = 0; r < 16; r++) wacc[r] *= lamv[r >> 2][r & 3];
#pragma unroll
            for (int u = 0; u < 4; u++) {
                bf8_t bb = lds_frag(&lDt[lm * 68 + u * 16 + half * 8]);
                wacc = __builtin_amdgcn_mfma_f32_32x32x16_bf16(pfr[u], bb, wacc, 0, 0, 0);
            }
#pragma unroll
            for (int r = 0; r < 16; r++) {
                int ml = (r & 3) + 8 * (r >> 2) + 4 * half;
                o[(size_t)(b * SEQ + s0 + ib * 32 + ml) * 4096 + h * 128 + vs * 32 + lm] = wacc[r];
            }
        }
#pragma unroll
        for (int r = 0; r < 16; r++) sacc[r] *= lamC;
#pragma unroll
        for (int u = 0; u < 4; u++) {
            bf8_t bb = lds_frag(&lDt[lm * 68 + u * 16 + half * 8]);
            sacc = __builtin_amdgcn_mfma_f32_32x32x16_bf16(ktfr[u], bb, sacc, 0, 0, 0);
        }
#pragma unroll
        for (int r = 0; r < 16; r++) {
            int ml = (r & 3) + 8 * (r >> 2) + 4 * half;
            lSt[lm * 132 + 32 * wave + ml] = f2bf(sacc[r]);
        }
        __syncthreads();
    }
}

// ---------------- gated RMSNorm -> bf16 (z from bf16 mixed) ----------------
__global__ __launch_bounds__(256) void k_gnorm(const float* __restrict__ o,
                                               const unsigned short* __restrict__ mixed,
                                               const float* __restrict__ norm_w,
                                               unsigned short* __restrict__ on) {
    int tok = blockIdx.x, t = threadIdx.x;
    int hh = t >> 3, ln = t & 7;
    const f4_t* op = (const f4_t*)(o + (size_t)tok * 4096 + hh * 128 + ln * 16);
    const unsigned short* zp = mixed + (size_t)tok * N1 + 8192 + hh * 128 + ln * 16;
    u16x8 zr0 = *(const u16x8*)zp;
    u16x8 zr1 = *(const u16x8*)(zp + 8);
    float og[16];
    float ss = 0.f;
#pragma unroll
    for (int i = 0; i < 4; i++) {
        f4_t ov = op[i];
#pragma unroll
        for (int j = 0; j < 4; j++) {
            int e = i * 4 + j;
            float z = (e < 8) ? bf2f(zr0[e]) : bf2f(zr1[e - 8]);
            float g = ov[j] * (z / (1.f + expf(-z)));
            og[e] = g;
            ss += g * g;
        }
    }
    ss += __shfl_xor(ss, 1); ss += __shfl_xor(ss, 2); ss += __shfl_xor(ss, 4);
    float r = 1.f / sqrtf(ss * (1.f / 128.f) + 1e-6f);
    unsigned short* onp = on + (size_t)tok * 4096 + hh * 128 + ln * 16;
    u16x8 a, bb;
#pragma unroll
    for (int j = 0; j < 8; j++) a[j] = f2bf(og[j] * r * norm_w[ln * 16 + j]);
#pragma unroll
    for (int j = 0; j < 8; j++) bb[j] = f2bf(og[8 + j] * r * norm_w[ln * 16 + 8 + j]);
    ((u16x8*)onp)[0] = a;
    ((u16x8*)onp)[1] = bb;
}

extern "C" void kernel_launch(void* const* d_in, const int* in_sizes, int n_in,
                              void* d_out, int out_size, void* d_ws, size_t ws_size,
                              hipStream_t stream) {
    const float* hs      = (const float*)d_in[0];
    const float* conv_w  = (const float*)d_in[1];
    const float* w_qkv   = (const float*)d_in[2];
    const float* w_z     = (const float*)d_in[3];
    const float* w_b     = (const float*)d_in[4];
    const float* w_a     = (const float*)d_in[5];
    const float* w_out   = (const float*)d_in[6];
    const float* dt_bias = (const float*)d_in[7];
    const float* A_log   = (const float*)d_in[8];
    const float* norm_w  = (const float*)d_in[9];
    float* out = (float*)d_out;

    // Workspace (~203 MiB total, under the 222 MiB baseline that passed).
    char* ws = (char*)d_ws;
    unsigned short* hs_bf = (unsigned short*)ws; ws += (size_t)NTOK * HIDDEN * 2;     // 8 MiB
    unsigned short* w1t   = (unsigned short*)ws; ws += (size_t)N1 * HIDDEN * 2;       // 48 MiB
    unsigned short* wot   = (unsigned short*)ws; ws += (size_t)HIDDEN * VAL_DIM * 2;  // 16 MiB (live to end)
    unsigned short* mixed = (unsigned short*)ws; ws += (size_t)NTOK * N1 * 2;         // 48 MiB (bf16 now)
    float* vbuf           = (float*)ws;          ws += (size_t)NTOK * 4096 * 4;       // 32 MiB (V fp32)
    float* beta           = (float*)ws;          ws += (size_t)NTOK * 32 * 4;
    float* gval           = (float*)ws;          ws += (size_t)NTOK * 32 * 4;
    unsigned short* halo  = (unsigned short*)ws; ws += (size_t)2 * (NCHC - 1) * 3 * 8192 * 2; // 2.9 MiB
    float* o_buf          = (float*)ws;          ws += (size_t)NTOK * VAL_DIM * 4;    // 32 MiB (U then O)
    unsigned short* on_bf = (unsigned short*)ws; ws += (size_t)NTOK * VAL_DIM * 2;

    // k_prep/k_state scratch ALIASED over buffers dead by that point:
    //   hs_bf + w1t (56 MiB, dead after first GEMM) holds Wg|Pg|KbTg|Qbg (48 MiB);
    //   halo (dead after k_conv) holds Lamg (256 KiB <= 2.9 MiB); U lives pre-O inside o_buf.
    char* al = (char*)hs_bf;
    unsigned short* Wg    = (unsigned short*)al; al += (size_t)1024 * 8192 * 2;  // 16 MiB
    unsigned short* Pg    = (unsigned short*)al; al += (size_t)1024 * 4096 * 2;  //  8 MiB
    unsigned short* KbTg  = (unsigned short*)al; al += (size_t)1024 * 8192 * 2;  // 16 MiB
    unsigned short* Qbg   = (unsigned short*)al; al += (size_t)512 * 8192 * 2;   //  8 MiB
    float* Lamg           = (float*)halo;

    k_cast_hs<<<dim3(NTOK * HIDDEN / 4 / 256), 256, 0, stream>>>(hs, hs_bf);
    k_trans_w1<<<dim3(N1 / 32, HIDDEN / 32), 256, 0, stream>>>(w_qkv, w_z, w1t);
    k_trans<<<dim3(HIDDEN / 32, VAL_DIM / 32), 256, 0, stream>>>(w_out, wot, VAL_DIM, HIDDEN);
    k_gemm_bt<unsigned short><<<dim3(NTOK / 128, N1 / 128), 256, 0, stream>>>(hs_bf, w1t, mixed, HIDDEN, N1);
    k_beta_g<<<dim3(NTOK / BG_TOK), 256, 0, stream>>>(hs, w_b, w_a, dt_bias, A_log, beta, gval);
    k_halo<<<dim3(2 * (NCHC - 1) * 3 * 8192 / 256), 256, 0, stream>>>(mixed, halo);
    k_conv<<<dim3(2 * NCHC * 8192 / 256), 256, 0, stream>>>(mixed, conv_w, halo, vbuf);
    k_prep<<<dim3(1024), 256, 0, stream>>>(mixed, vbuf, beta, gval, Pg, KbTg, Qbg, Wg, o_buf, Lamg);
    k_state<<<dim3(256), 256, 0, stream>>>(Wg, Pg, KbTg, Qbg, Lamg, o_buf);
    k_gnorm<<<dim3(NTOK), 256, 0, stream>>>(o_buf, mixed, norm_w, on_bf);
    k_gemm_bt<float><<<dim3(NTOK / 128, HIDDEN / 128), 256, 0, stream>>>(on_bf, wot, out, VAL_DIM, HIDDEN);
}